// Round 4
// baseline (18770.284 us; speedup 1.0000x reference)
//
#include <hip/hip_runtime.h>
#include <hip/hip_bf16.h>
#include <math.h>

typedef __hip_bfloat16 bf16;

__device__ __forceinline__ float us2f(unsigned short u) {
  union { unsigned u; float f; } c; c.u = ((unsigned)u) << 16; return c.f;
}
__device__ __forceinline__ unsigned short f2us(float f) {
  return __bfloat16_as_ushort(__float2bfloat16(f));
}
__device__ __forceinline__ void unpack2(unsigned u, float& a, float& b) {
  union { unsigned u; float f; } lo, hi;
  lo.u = u << 16; hi.u = u & 0xffff0000u;
  a = lo.f; b = hi.f;
}

// fp32 x (LDS, 16B-aligned) . fp32 w (global, 16B-aligned), K % 8 == 0
__device__ __forceinline__ float dot_ff(const float* __restrict__ x,
                                        const float* __restrict__ w, int K) {
  const float4* xp = reinterpret_cast<const float4*>(x);
  const float4* wp = reinterpret_cast<const float4*>(w);
  float acc = 0.f;
  const int n = K >> 2;
  for (int i = 0; i < n; ++i) {
    float4 a = xp[i], b = wp[i];
    acc += a.x*b.x + a.y*b.y + a.z*b.z + a.w*b.w;
  }
  return acc;
}

// bf16 x (LDS, 16B-aligned) . fp32 w (global), K % 8 == 0
__device__ __forceinline__ float dot_bf(const unsigned short* __restrict__ x,
                                        const float* __restrict__ w, int K) {
  const uint4* xp = reinterpret_cast<const uint4*>(x);
  const float4* wp = reinterpret_cast<const float4*>(w);
  float acc = 0.f;
  const int n = K >> 3;
  for (int i = 0; i < n; ++i) {
    uint4 ux = xp[i];
    float x0,x1,x2,x3,x4,x5,x6,x7;
    unpack2(ux.x, x0, x1); unpack2(ux.y, x2, x3);
    unpack2(ux.z, x4, x5); unpack2(ux.w, x6, x7);
    float4 wa = wp[2*i], wb = wp[2*i+1];
    acc += x0*wa.x + x1*wa.y + x2*wa.z + x3*wa.w
         + x4*wb.x + x5*wb.y + x6*wb.z + x7*wb.w;
  }
  return acc;
}

__device__ __forceinline__ float sigm(float x) { return 1.f / (1.f + expf(-x)); }

// ---------------------------------------------------------------------------
// Canary: fill d_out with 100.0f. k_final overwrites all of it on success.
//   absmax ~3.86 -> nothing ran (or all-NaN flush); ~96-100 -> k_final skipped
// ---------------------------------------------------------------------------
__global__ void k_canary(float* __restrict__ out) {
  out[blockIdx.x * 256 + threadIdx.x] = 100.0f;
}

// ---------------------------------------------------------------------------
// Stage 1: embed + per-order MHA (L=32, D=128, NH=4, hd=32) + token-mean +
// out-proj folded after the mean. One block per (b,o).
// LDS = 16384 + 16384 + 16512 + 8192 + 128 = 57,600 B
// ---------------------------------------------------------------------------
#define KB_STRIDE 129

__global__ __launch_bounds__(256) void k_order_attn(
    const int* __restrict__ oh, const float* __restrict__ emb,
    const float* __restrict__ in_w, const float* __restrict__ in_b,
    const float* __restrict__ out_w, const float* __restrict__ out_b,
    float* __restrict__ order_emb)
{
  const int bo = blockIdx.x;            // 0..8191
  const int tid = threadIdx.x;
  __shared__ float xb[32 * 128];        // x; reused as scores[4][32][32]
  __shared__ float qb[32 * 128];        // q (broadcast reads); reused as o
  __shared__ float kb[32 * KB_STRIDE];  // k padded; first 128 floats reused as om
  __shared__ unsigned short vb[32 * 128]; // v bf16 (storage-rounding only)
  __shared__ int   ids[32];

  if (tid < 32) ids[tid] = oh[bo * 32 + tid];
  __syncthreads();
  for (int i = tid; i < 32 * 128; i += 256) {
    int t = i >> 7, d = i & 127;
    xb[i] = emb[(size_t)ids[t] * 128 + d];
  }
  __syncthreads();
  // qkv: 32 tokens x 384 outputs, K=128
  for (int i = tid; i < 32 * 384; i += 256) {
    int t = i / 384, j = i % 384;
    float acc = dot_ff(&xb[t * 128], in_w + (size_t)j * 128, 128) + in_b[j];
    int jj = j & 127;
    if (j < 128)      qb[t * 128 + jj] = acc;
    else if (j < 256) kb[t * KB_STRIDE + jj] = acc;
    else              vb[t * 128 + jj] = f2us(acc);
  }
  __syncthreads();
  float* sc = xb;  // scores overlay (x dead)
  const float scale1 = 0.17677669529663687f; // 1/sqrt(32)
  for (int i = tid; i < 4096; i += 256) {
    int h = i >> 10, rem = i & 1023, qi = rem >> 5, ki = rem & 31;
    const float* qp = &qb[qi * 128 + h * 32];
    const float* kp = &kb[ki * KB_STRIDE + h * 32];
    float acc = 0.f;
#pragma unroll
    for (int c = 0; c < 32; ++c) acc += qp[c] * kp[c];
    sc[i] = acc * scale1;
  }
  __syncthreads();
  if (tid < 128) {  // softmax rows (h*32+qi)
    float* row = &sc[tid * 32];
    float m = row[0];
#pragma unroll
    for (int c = 1; c < 32; ++c) m = fmaxf(m, row[c]);
    float s = 0.f;
#pragma unroll
    for (int c = 0; c < 32; ++c) { float e = expf(row[c] - m); row[c] = e; s += e; }
    float inv = 1.f / s;
#pragma unroll
    for (int c = 0; c < 32; ++c) row[c] *= inv;
  }
  __syncthreads();
  // o = p @ v  (into qb; q dead)
  for (int i = tid; i < 32 * 128; i += 256) {
    int t = i >> 7, d = i & 127, h = d >> 5;
    const float* prow = &sc[(h * 32 + t) * 32];
    float acc = 0.f;
#pragma unroll
    for (int k = 0; k < 32; ++k) acc += prow[k] * us2f(vb[k * 128 + d]);
    qb[t * 128 + d] = acc;
  }
  __syncthreads();
  float* om = kb;  // mean overlay (k dead)
  if (tid < 128) {
    float acc = 0.f;
#pragma unroll
    for (int t = 0; t < 32; ++t) acc += qb[t * 128 + tid];
    om[tid] = acc * (1.f / 32.f);
  }
  __syncthreads();
  if (tid < 128) {
    float acc = dot_ff(om, out_w + (size_t)tid * 128, 128) + out_b[tid];
    order_emb[(size_t)bo * 128 + tid] = acc;
  }
}

// ---------------------------------------------------------------------------
// Stage 2: bidirectional GRU. One block per (batch, dir). H=256, 32 steps.
// g layout: [b][t][dir*256 + j], fp32 [256,32,512]
// ---------------------------------------------------------------------------
__global__ __launch_bounds__(256) void k_gru(
    const float* __restrict__ oe,
    const float* __restrict__ wih_f, const float* __restrict__ whh_f,
    const float* __restrict__ bih_f, const float* __restrict__ bhh_f,
    const float* __restrict__ wih_b, const float* __restrict__ whh_b,
    const float* __restrict__ bih_b, const float* __restrict__ bhh_b,
    float* __restrict__ g)
{
  const int b = blockIdx.x, dir = blockIdx.y, j = threadIdx.x;
  const float* wih = dir ? wih_b : wih_f;
  const float* whh = dir ? whh_b : whh_f;
  const float* bih = dir ? bih_b : bih_f;
  const float* bhh = dir ? bhh_b : bhh_f;
  __shared__ float h[256];
  __shared__ float xr[128];
  const float bir = bih[j], biz = bih[256 + j], bin_ = bih[512 + j];
  const float bhr = bhh[j], bhz = bhh[256 + j], bhn  = bhh[512 + j];
  h[j] = 0.f;
  __syncthreads();
  for (int s = 0; s < 32; ++s) {
    const int t = dir ? (31 - s) : s;
    if (j < 128) xr[j] = oe[((size_t)b * 32 + t) * 128 + j];
    __syncthreads();
    float gir = dot_ff(xr, wih + (size_t)j * 128, 128) + bir;
    float giz = dot_ff(xr, wih + (size_t)(256 + j) * 128, 128) + biz;
    float gin = dot_ff(xr, wih + (size_t)(512 + j) * 128, 128) + bin_;
    float ghr = dot_ff(h, whh + (size_t)j * 256, 256) + bhr;
    float ghz = dot_ff(h, whh + (size_t)(256 + j) * 256, 256) + bhz;
    float ghn = dot_ff(h, whh + (size_t)(512 + j) * 256, 256) + bhn;
    float r = sigm(gir + ghr);
    float z = sigm(giz + ghz);
    float n = tanhf(gin + r * ghn);
    float hn = (1.f - z) * n + z * h[j];
    __syncthreads();
    h[j] = hn;
    g[((size_t)b * 32 + t) * 512 + dir * 256 + j] = hn;
    __syncthreads();
  }
}

// ---------------------------------------------------------------------------
// Stage 3 fused attention: one block per (b, head). Computes q/k/v for its
// head directly from g (QKV GEMM fused; weights stay L2-resident).
// LDS: 32768 + 3*8320 + 4096 = 61,824 B
// ---------------------------------------------------------------------------
__global__ __launch_bounds__(256) void k_mha2f(
    const float* __restrict__ g, const float* __restrict__ W,
    const float* __restrict__ Bv, float* __restrict__ attn)
{
  const int b = blockIdx.x, h = blockIdx.y, tid = threadIdx.x;
  __shared__ unsigned short xs[32 * 512];   // x tile (bf16 storage)
  __shared__ unsigned short qs[32 * 130];   // stride 130 shorts = 65 dwords (odd)
  __shared__ unsigned short ks[32 * 130];
  __shared__ unsigned short vs[32 * 130];
  __shared__ float sc[32 * 32];
  for (int i = tid; i < 32 * 512; i += 256)
    xs[i] = f2us(g[(size_t)b * 16384 + i]);
  __syncthreads();
  // q/k/v for this head: 3 * 32 * 128 dots of K=512
  for (int idx = tid; idx < 3 * 4096; idx += 256) {
    int m = idx >> 12, r = idx & 4095, t = r >> 7, d = r & 127;
    int wrow = m * 512 + h * 128 + d;
    float acc = dot_bf(&xs[t * 512], W + (size_t)wrow * 512, 512) + Bv[wrow];
    unsigned short* dst = (m == 0) ? qs : (m == 1) ? ks : vs;
    dst[t * 130 + d] = f2us(acc);
  }
  __syncthreads();
  const float scale2 = 0.08838834764831845f; // 1/sqrt(128)
  for (int i = tid; i < 1024; i += 256) {
    int qi = i >> 5, ki = i & 31;
    const unsigned short* qp = &qs[qi * 130];
    const unsigned short* kp = &ks[ki * 130];
    float acc = 0.f;
#pragma unroll
    for (int c = 0; c < 128; ++c) acc += us2f(qp[c]) * us2f(kp[c]);
    sc[i] = acc * scale2;
  }
  __syncthreads();
  if (tid < 32) {
    float* row = &sc[tid * 32];
    float m = row[0];
#pragma unroll
    for (int c = 1; c < 32; ++c) m = fmaxf(m, row[c]);
    float s = 0.f;
#pragma unroll
    for (int c = 0; c < 32; ++c) { float e = expf(row[c] - m); row[c] = e; s += e; }
    float inv = 1.f / s;
#pragma unroll
    for (int c = 0; c < 32; ++c) row[c] *= inv;
  }
  __syncthreads();
  for (int i = tid; i < 4096; i += 256) {
    int t = i >> 7, d = i & 127;
    const float* prow = &sc[t * 32];
    float acc = 0.f;
#pragma unroll
    for (int k = 0; k < 32; ++k) acc += prow[k] * us2f(vs[k * 130 + d]);
    attn[((size_t)b * 32 + t) * 512 + h * 128 + d] = acc;
  }
}

// ---------------------------------------------------------------------------
// proj GEMM (K=512, N=512) + residual + LN, 8 rows/block. Y may alias X
// (rows staged in LDS before any global write; block owns its rows).
// LDS: 16384 + 16384 + 1024 = 33,792 B
// ---------------------------------------------------------------------------
__global__ __launch_bounds__(256) void k_proj_ln(
    const float* __restrict__ X, const float* __restrict__ W,
    const float* __restrict__ bias, const float* __restrict__ res,
    const float* __restrict__ gam, const float* __restrict__ bet,
    float* __restrict__ Y)
{
  const int tid = threadIdx.x;
  const int row0 = blockIdx.x * 8;
  __shared__ float xs[8 * 512];
  __shared__ float ys[8 * 512];
  __shared__ float red[256];
  for (int i = tid; i < 8 * 512; i += 256) xs[i] = X[(size_t)row0 * 512 + i];
  __syncthreads();
  for (int j = tid; j < 512; j += 256) {
    const float4* wp = reinterpret_cast<const float4*>(W + (size_t)j * 512);
    float acc[8];
#pragma unroll
    for (int r = 0; r < 8; ++r) acc[r] = 0.f;
    for (int i = 0; i < 64; ++i) {
      float4 wa = wp[2*i], wb = wp[2*i+1];
#pragma unroll
      for (int r = 0; r < 8; ++r) {
        const float* xi = &xs[r * 512 + (i << 3)];
        acc[r] += xi[0]*wa.x + xi[1]*wa.y + xi[2]*wa.z + xi[3]*wa.w
                + xi[4]*wb.x + xi[5]*wb.y + xi[6]*wb.z + xi[7]*wb.w;
      }
    }
    const float bj = bias[j];
#pragma unroll
    for (int r = 0; r < 8; ++r) ys[r * 512 + j] = acc[r] + bj;
  }
  __syncthreads();
  for (int i = tid; i < 8 * 512; i += 256) ys[i] += res[(size_t)row0 * 512 + i];
  __syncthreads();
  for (int r = 0; r < 8; ++r) {
    float part = 0.f;
    for (int i = tid; i < 512; i += 256) part += ys[r * 512 + i];
    red[tid] = part; __syncthreads();
    for (int s = 128; s > 0; s >>= 1) { if (tid < s) red[tid] += red[tid + s]; __syncthreads(); }
    const float mean = red[0] * (1.f / 512.f);
    __syncthreads();
    part = 0.f;
    for (int i = tid; i < 512; i += 256) { float d = ys[r * 512 + i] - mean; part += d * d; }
    red[tid] = part; __syncthreads();
    for (int s = 128; s > 0; s >>= 1) { if (tid < s) red[tid] += red[tid + s]; __syncthreads(); }
    const float rs = rsqrtf(red[0] * (1.f / 512.f) + 1e-5f);
    __syncthreads();
    for (int i = tid; i < 512; i += 256)
      Y[((size_t)row0 + r) * 512 + i] = (ys[r * 512 + i] - mean) * rs * gam[i] + bet[i];
    __syncthreads();
  }
}

// ---------------------------------------------------------------------------
// ff1 GEMM (K=512, N=1024) + relu, 16 rows/block, bf16 output. LDS 32 KB.
// ---------------------------------------------------------------------------
__global__ __launch_bounds__(256) void k_ff1(
    const float* __restrict__ X, const float* __restrict__ W,
    const float* __restrict__ bias, unsigned short* __restrict__ Y)
{
  const int tid = threadIdx.x;
  const int row0 = blockIdx.x * 16;
  __shared__ float xs[16 * 512];
  for (int i = tid; i < 16 * 512; i += 256) xs[i] = X[(size_t)row0 * 512 + i];
  __syncthreads();
  for (int j = tid; j < 1024; j += 256) {
    const float4* wp = reinterpret_cast<const float4*>(W + (size_t)j * 512);
    float acc[16];
#pragma unroll
    for (int r = 0; r < 16; ++r) acc[r] = 0.f;
    for (int i = 0; i < 64; ++i) {
      float4 wa = wp[2*i], wb = wp[2*i+1];
#pragma unroll
      for (int r = 0; r < 16; ++r) {
        const float* xi = &xs[r * 512 + (i << 3)];
        acc[r] += xi[0]*wa.x + xi[1]*wa.y + xi[2]*wa.z + xi[3]*wa.w
                + xi[4]*wb.x + xi[5]*wb.y + xi[6]*wb.z + xi[7]*wb.w;
      }
    }
    const float bj = bias[j];
#pragma unroll
    for (int r = 0; r < 16; ++r)
      Y[(size_t)(row0 + r) * 1024 + j] = f2us(fmaxf(acc[r] + bj, 0.f));
  }
}

// ---------------------------------------------------------------------------
// ff2 GEMM (K=1024 bf16 X, N=512) + residual + LN, 8 rows/block.
// Y fp32 (2048 B/row) overlays X bf16 (2048 B/row) in-place; X staged first.
// LDS: 32768 + 16384 + 1024 = 50,176 B
// ---------------------------------------------------------------------------
__global__ __launch_bounds__(256) void k_ff2_ln(
    const unsigned short* __restrict__ X, const float* __restrict__ W,
    const float* __restrict__ bias, const float* __restrict__ res,
    const float* __restrict__ gam, const float* __restrict__ bet,
    float* __restrict__ Y)
{
  const int tid = threadIdx.x;
  const int row0 = blockIdx.x * 8;
  __shared__ float xs[8 * 1024];
  __shared__ float ys[8 * 512];
  __shared__ float red[256];
  for (int i = tid; i < 8 * 1024; i += 256) xs[i] = us2f(X[(size_t)row0 * 1024 + i]);
  __syncthreads();
  for (int j = tid; j < 512; j += 256) {
    const float4* wp = reinterpret_cast<const float4*>(W + (size_t)j * 1024);
    float acc[8];
#pragma unroll
    for (int r = 0; r < 8; ++r) acc[r] = 0.f;
    for (int i = 0; i < 128; ++i) {
      float4 wa = wp[2*i], wb = wp[2*i+1];
#pragma unroll
      for (int r = 0; r < 8; ++r) {
        const float* xi = &xs[r * 1024 + (i << 3)];
        acc[r] += xi[0]*wa.x + xi[1]*wa.y + xi[2]*wa.z + xi[3]*wa.w
                + xi[4]*wb.x + xi[5]*wb.y + xi[6]*wb.z + xi[7]*wb.w;
      }
    }
    const float bj = bias[j];
#pragma unroll
    for (int r = 0; r < 8; ++r) ys[r * 512 + j] = acc[r] + bj;
  }
  __syncthreads();
  for (int i = tid; i < 8 * 512; i += 256) ys[i] += res[(size_t)row0 * 512 + i];
  __syncthreads();
  for (int r = 0; r < 8; ++r) {
    float part = 0.f;
    for (int i = tid; i < 512; i += 256) part += ys[r * 512 + i];
    red[tid] = part; __syncthreads();
    for (int s = 128; s > 0; s >>= 1) { if (tid < s) red[tid] += red[tid + s]; __syncthreads(); }
    const float mean = red[0] * (1.f / 512.f);
    __syncthreads();
    part = 0.f;
    for (int i = tid; i < 512; i += 256) { float d = ys[r * 512 + i] - mean; part += d * d; }
    red[tid] = part; __syncthreads();
    for (int s = 128; s > 0; s >>= 1) { if (tid < s) red[tid] += red[tid + s]; __syncthreads(); }
    const float rs = rsqrtf(red[0] * (1.f / 512.f) + 1e-5f);
    __syncthreads();
    for (int i = tid; i < 512; i += 256)
      Y[((size_t)row0 + r) * 512 + i] = (ys[r * 512 + i] - mean) * rs * gam[i] + bet[i];
    __syncthreads();
  }
}

// ---------------------------------------------------------------------------
// Final: mean-pool, temporal MLP, concat, classifier, LN, relu -> fp32
// ---------------------------------------------------------------------------
__global__ __launch_bounds__(256) void k_final(
    const float* __restrict__ g2,
    const float* __restrict__ db, const float* __restrict__ dsl,
    const float* __restrict__ te1_w, const float* __restrict__ te1_b,
    const float* __restrict__ l1g, const float* __restrict__ l1b,
    const float* __restrict__ te2_w, const float* __restrict__ te2_b,
    const float* __restrict__ l2g, const float* __restrict__ l2b,
    const float* __restrict__ c_w, const float* __restrict__ c_b,
    const float* __restrict__ clg, const float* __restrict__ clb,
    float* __restrict__ out)
{
  const int b = blockIdx.x, tid = threadIdx.x;
  __shared__ float cat[640];
  __shared__ float t1[64];
  __shared__ float t2[128];
  __shared__ float pre[256];
  __shared__ float red[256];
  __shared__ float st[2];
  for (int i = tid; i < 512; i += 256) {
    float acc = 0.f;
#pragma unroll
    for (int t = 0; t < 32; ++t) acc += g2[((size_t)b * 32 + t) * 512 + i];
    cat[i] = acc * (1.f / 32.f);
  }
  if (tid == 0) {
    float s = 0.f;
    for (int i = 0; i < 31; ++i) s += db[b * 31 + i];
    st[0] = s / 31.f;
    st[1] = dsl[b];
  }
  __syncthreads();
  const float f0 = st[0], f1v = st[1];
  if (tid < 64)
    t1[tid] = f0 * te1_w[tid * 2] + f1v * te1_w[tid * 2 + 1] + te1_b[tid];
  __syncthreads();
  if (tid == 0) {
    float m = 0.f; for (int i = 0; i < 64; ++i) m += t1[i]; m *= (1.f / 64.f);
    float v = 0.f; for (int i = 0; i < 64; ++i) { float d = t1[i] - m; v += d * d; }
    st[0] = m; st[1] = rsqrtf(v * (1.f / 64.f) + 1e-5f);
  }
  __syncthreads();
  if (tid < 64) {
    float v = (t1[tid] - st[0]) * st[1] * l1g[tid] + l1b[tid];
    t1[tid] = fmaxf(v, 0.f);
  }
  __syncthreads();
  if (tid < 128)
    t2[tid] = dot_ff(t1, te2_w + (size_t)tid * 64, 64) + te2_b[tid];
  __syncthreads();
  if (tid == 0) {
    float m = 0.f; for (int i = 0; i < 128; ++i) m += t2[i]; m *= (1.f / 128.f);
    float v = 0.f; for (int i = 0; i < 128; ++i) { float d = t2[i] - m; v += d * d; }
    st[0] = m; st[1] = rsqrtf(v * (1.f / 128.f) + 1e-5f);
  }
  __syncthreads();
  if (tid < 128) {
    float v = (t2[tid] - st[0]) * st[1] * l2g[tid] + l2b[tid];
    cat[512 + tid] = fmaxf(v, 0.f);
  }
  __syncthreads();
  pre[tid] = dot_ff(cat, c_w + (size_t)tid * 640, 640) + c_b[tid];
  red[tid] = pre[tid];
  __syncthreads();
  for (int s = 128; s > 0; s >>= 1) { if (tid < s) red[tid] += red[tid + s]; __syncthreads(); }
  const float m = red[0] * (1.f / 256.f);
  __syncthreads();
  const float d = pre[tid] - m;
  red[tid] = d * d;
  __syncthreads();
  for (int s = 128; s > 0; s >>= 1) { if (tid < s) red[tid] += red[tid + s]; __syncthreads(); }
  const float rs = rsqrtf(red[0] * (1.f / 256.f) + 1e-5f);
  float v = d * rs * clg[tid] + clb[tid];
  out[(size_t)b * 256 + tid] = fmaxf(v, 0.f);
}

// ---------------------------------------------------------------------------
extern "C" void kernel_launch(void* const* d_in, const int* in_sizes, int n_in,
                              void* d_out, int out_size, void* d_ws, size_t ws_size,
                              hipStream_t stream) {
  (void)in_sizes; (void)n_in; (void)out_size; (void)ws_size;
  const int*   oh     = (const int*)  d_in[0];
  const float* db     = (const float*)d_in[1];
  const float* dsl    = (const float*)d_in[2];
  const float* emb    = (const float*)d_in[3];
  const float* a_in_w = (const float*)d_in[4];
  const float* a_in_b = (const float*)d_in[5];
  const float* a_out_w= (const float*)d_in[6];
  const float* a_out_b= (const float*)d_in[7];
  const float* wih_f  = (const float*)d_in[8];
  const float* whh_f  = (const float*)d_in[9];
  const float* bih_f  = (const float*)d_in[10];
  const float* bhh_f  = (const float*)d_in[11];
  const float* wih_b  = (const float*)d_in[12];
  const float* whh_b  = (const float*)d_in[13];
  const float* bih_b  = (const float*)d_in[14];
  const float* bhh_b  = (const float*)d_in[15];
  const float* t_in_w = (const float*)d_in[16];
  const float* t_in_b = (const float*)d_in[17];
  const float* t_out_w= (const float*)d_in[18];
  const float* t_out_b= (const float*)d_in[19];
  const float* t_ln1g = (const float*)d_in[20];
  const float* t_ln1b = (const float*)d_in[21];
  const float* t_ff1w = (const float*)d_in[22];
  const float* t_ff1b = (const float*)d_in[23];
  const float* t_ff2w = (const float*)d_in[24];
  const float* t_ff2b = (const float*)d_in[25];
  const float* t_ln2g = (const float*)d_in[26];
  const float* t_ln2b = (const float*)d_in[27];
  const float* te1_w  = (const float*)d_in[28];
  const float* te1_b  = (const float*)d_in[29];
  const float* tl1g   = (const float*)d_in[30];
  const float* tl1b   = (const float*)d_in[31];
  const float* te2_w  = (const float*)d_in[32];
  const float* te2_b  = (const float*)d_in[33];
  const float* tl2g   = (const float*)d_in[34];
  const float* tl2b   = (const float*)d_in[35];
  const float* c_w    = (const float*)d_in[36];
  const float* c_b    = (const float*)d_in[37];
  const float* clng   = (const float*)d_in[38];
  const float* clnb   = (const float*)d_in[39];

  float* ws = (float*)d_ws;
  // Workspace (floats), 36 MB total:
  //   A [0,        1048576): oe  [8192,128] fp32
  //   B [1048576,  5242880): g   [8192,512] fp32 -> f1 bf16 [8192,1024]
  //                          (over dead g) -> g2 fp32 [8192,512] (in-place
  //                          over f1: identical 2048 B/row spans)
  //   C [5242880,  9437184): attn [8192,512] fp32; g1 = LN out in-place
  float* oe   = ws;
  float* g    = ws + 1048576;
  float* attn = ws + 5242880;
  float* g1   = attn;                                   // in-place
  unsigned short* f1 = (unsigned short*)(ws + 1048576); // over dead g
  float* g2   = ws + 1048576;                           // in-place over f1

  k_canary<<<256, 256, 0, stream>>>((float*)d_out);
  k_order_attn<<<8192, 256, 0, stream>>>(oh, emb, a_in_w, a_in_b, a_out_w, a_out_b, oe);
  k_gru<<<dim3(256, 2), 256, 0, stream>>>(oe, wih_f, whh_f, bih_f, bhh_f,
                                          wih_b, whh_b, bih_b, bhh_b, g);
  k_mha2f<<<dim3(256, 4), 256, 0, stream>>>(g, t_in_w, t_in_b, attn);
  k_proj_ln<<<1024, 256, 0, stream>>>(attn, t_out_w, t_out_b, g, t_ln1g, t_ln1b, g1);
  k_ff1<<<512, 256, 0, stream>>>(g1, t_ff1w, t_ff1b, f1);
  k_ff2_ln<<<1024, 256, 0, stream>>>(f1, t_ff2w, t_ff2b, g1, t_ln2g, t_ln2b, g2);
  k_final<<<256, 256, 0, stream>>>(g2, db, dsl, te1_w, te1_b, tl1g, tl1b,
                                   te2_w, te2_b, tl2g, tl2b, c_w, c_b, clng, clnb,
                                   (float*)d_out);
}

// Round 5
// 4057.935 us; speedup vs baseline: 4.6256x; 4.6256x over previous
//
#include <hip/hip_runtime.h>
#include <hip/hip_bf16.h>
#include <math.h>

typedef __hip_bfloat16 bf16;

__device__ __forceinline__ float us2f(unsigned short u) {
  union { unsigned u; float f; } c; c.u = ((unsigned)u) << 16; return c.f;
}
__device__ __forceinline__ unsigned short f2us(float f) {
  return __bfloat16_as_ushort(__float2bfloat16(f));
}

// fp32 x (LDS/generic, 16B-aligned) . fp32 w (global, 16B-aligned), K % 8 == 0
__device__ __forceinline__ float dot_ff(const float* __restrict__ x,
                                        const float* __restrict__ w, int K) {
  const float4* xp = reinterpret_cast<const float4*>(x);
  const float4* wp = reinterpret_cast<const float4*>(w);
  float acc = 0.f;
  const int n = K >> 2;
  for (int i = 0; i < n; ++i) {
    float4 a = xp[i], b = wp[i];
    acc += a.x*b.x + a.y*b.y + a.z*b.z + a.w*b.w;
  }
  return acc;
}

__device__ __forceinline__ float sigm(float x) { return 1.f / (1.f + expf(-x)); }

// ---------------------------------------------------------------------------
// Canary (cheap insurance): k_final overwrites everything on success.
// ---------------------------------------------------------------------------
__global__ void k_canary(float* __restrict__ out) {
  out[blockIdx.x * 256 + threadIdx.x] = 100.0f;
}

// ---------------------------------------------------------------------------
// Stage 1: embed + per-order MHA (L=32, D=128, NH=4, hd=32) + token-mean +
// out-proj folded after mean. One block per (b,o).
// QKV loop: 32 lanes share one weight row (broadcast); x-tile stride 130
// floats -> lane-varying-t LDS reads are 2-way (free).
// LDS: 16640 + 16640 + 16512 + 8192 + 128 = 58,112 B
// ---------------------------------------------------------------------------
#define XB_STR 130
#define KB_STR 129

__global__ __launch_bounds__(256) void k_order_attn(
    const int* __restrict__ oh, const float* __restrict__ emb,
    const float* __restrict__ in_w, const float* __restrict__ in_b,
    const float* __restrict__ out_w, const float* __restrict__ out_b,
    float* __restrict__ order_emb)
{
  const int bo = blockIdx.x;            // 0..8191
  const int tid = threadIdx.x;
  __shared__ float xb[32 * XB_STR];     // x; overlaid by scores[4096] (<=4160)
  __shared__ float qb[32 * XB_STR];     // q; reused as o
  __shared__ float kb[32 * KB_STR];     // k; first 128 floats reused as om
  __shared__ unsigned short vb[32 * 128]; // v bf16 (storage-rounding only)
  __shared__ int   ids[32];

  if (tid < 32) ids[tid] = oh[bo * 32 + tid];
  __syncthreads();
  for (int i = tid; i < 32 * 128; i += 256) {
    int t = i >> 7, d = i & 127;
    xb[t * XB_STR + d] = emb[(size_t)ids[t] * 128 + d];
  }
  __syncthreads();
  // qkv: idx -> (j = idx>>5 in [0,384), t = idx&31); 32 lanes share j.
  for (int idx = tid; idx < 32 * 384; idx += 256) {
    int j = idx >> 5, t = idx & 31;
    const float4* wp = reinterpret_cast<const float4*>(in_w + (size_t)j * 128);
    const float2* xp = reinterpret_cast<const float2*>(xb + t * XB_STR);
    float acc = 0.f;
#pragma unroll
    for (int i = 0; i < 16; ++i) {
      float4 wa = wp[2*i], wb = wp[2*i+1];
      float2 x0 = xp[4*i], x1 = xp[4*i+1], x2 = xp[4*i+2], x3 = xp[4*i+3];
      acc += x0.x*wa.x + x0.y*wa.y + x1.x*wa.z + x1.y*wa.w
           + x2.x*wb.x + x2.y*wb.y + x3.x*wb.z + x3.y*wb.w;
    }
    acc += in_b[j];
    int jj = j & 127;
    if (j < 128)      qb[t * XB_STR + jj] = acc;
    else if (j < 256) kb[t * KB_STR + jj] = acc;
    else              vb[t * 128 + jj] = f2us(acc);
  }
  __syncthreads();
  float* sc = xb;  // scores overlay (x dead)
  const float scale1 = 0.17677669529663687f; // 1/sqrt(32)
  for (int i = tid; i < 4096; i += 256) {
    int h = i >> 10, rem = i & 1023, qi = rem >> 5, ki = rem & 31;
    const float* qp = &qb[qi * XB_STR + h * 32];  // broadcast (qi shared/32 lanes)
    const float* kp = &kb[ki * KB_STR + h * 32];  // lane-varying, stride-129 ok
    float acc = 0.f;
#pragma unroll
    for (int c = 0; c < 32; ++c) acc += qp[c] * kp[c];
    sc[i] = acc * scale1;
  }
  __syncthreads();
  if (tid < 128) {  // softmax rows (h*32+qi)
    float* row = &sc[tid * 32];
    float m = row[0];
#pragma unroll
    for (int c = 1; c < 32; ++c) m = fmaxf(m, row[c]);
    float s = 0.f;
#pragma unroll
    for (int c = 0; c < 32; ++c) { float e = expf(row[c] - m); row[c] = e; s += e; }
    float inv = 1.f / s;
#pragma unroll
    for (int c = 0; c < 32; ++c) row[c] *= inv;
  }
  __syncthreads();
  // o = p @ v  (into qb; q dead)
  for (int i = tid; i < 32 * 128; i += 256) {
    int t = i >> 7, d = i & 127, h = d >> 5;
    const float* prow = &sc[(h * 32 + t) * 32];
    float acc = 0.f;
#pragma unroll
    for (int k = 0; k < 32; ++k) acc += prow[k] * us2f(vb[k * 128 + d]);
    qb[t * XB_STR + d] = acc;
  }
  __syncthreads();
  float* om = kb;  // mean overlay (k dead)
  if (tid < 128) {
    float acc = 0.f;
#pragma unroll
    for (int t = 0; t < 32; ++t) acc += qb[t * XB_STR + tid];
    om[tid] = acc * (1.f / 32.f);
  }
  __syncthreads();
  if (tid < 128) {
    float acc = dot_ff(om, out_w + (size_t)tid * 128, 128) + out_b[tid];
    order_emb[(size_t)bo * 128 + tid] = acc;
  }
}

// ---------------------------------------------------------------------------
// GRU weight transpose (one-shot): wT[dir][k][gate*256+j].
// wihT: k in [0,128) at offset 0; whhT: k in [0,256) at offset 98304.
// Per dir 294,912 floats; total 589,824 (2.36 MB).
// ---------------------------------------------------------------------------
__global__ __launch_bounds__(256) void k_gru_wt(
    const float* __restrict__ wih_f, const float* __restrict__ whh_f,
    const float* __restrict__ wih_b, const float* __restrict__ whh_b,
    float* __restrict__ wT)
{
  int i = blockIdx.x * 256 + threadIdx.x;   // < 589824
  int dir = i / 294912, r = i % 294912;
  const float* wih = dir ? wih_b : wih_f;
  const float* whh = dir ? whh_b : whh_f;
  float v;
  if (r < 98304) { int k = r / 768, c = r % 768; v = wih[(size_t)c * 128 + k]; }
  else { int r2 = r - 98304; int k = r2 / 768, c = r2 % 768; v = whh[(size_t)c * 256 + k]; }
  wT[i] = v;
}

// ---------------------------------------------------------------------------
// GRU recurrence: 4 batches per block, grid (64, 2). h & x in LDS (broadcast
// reads); transposed weights -> fully coalesced lane-j loads, L2-resident.
// Weight traffic: 128 blocks x 32 steps x 1.18 MB = 4.8 GB (L2).
// ---------------------------------------------------------------------------
#define GB 4

__global__ __launch_bounds__(256) void k_gru_rec(
    const float* __restrict__ oe, const float* __restrict__ wT,
    const float* __restrict__ bih_f, const float* __restrict__ bhh_f,
    const float* __restrict__ bih_b, const float* __restrict__ bhh_b,
    float* __restrict__ g)
{
  const int b0 = blockIdx.x * GB, dir = blockIdx.y, j = threadIdx.x;
  const float* wihT = wT + (size_t)dir * 294912;   // [128][768]
  const float* whhT = wihT + 98304;                // [256][768]
  const float* bih = dir ? bih_b : bih_f;
  const float* bhh = dir ? bhh_b : bhh_f;
  __shared__ float hs[GB][256];
  __shared__ float xr[GB][128];
  const float brz = bih[j] + bhh[j];          // r-gate biases sum
  const float bzz = bih[256 + j] + bhh[256 + j];
  const float bin_ = bih[512 + j];            // n-gate: keep separate (r * (..+bhn))
  const float bhn  = bhh[512 + j];
#pragma unroll
  for (int b = 0; b < GB; ++b) hs[b][j] = 0.f;
  __syncthreads();
  for (int s = 0; s < 32; ++s) {
    const int t = dir ? (31 - s) : s;
    for (int i = j; i < GB * 128; i += 256) {
      int b = i >> 7, d = i & 127;
      xr[b][d] = oe[((size_t)(b0 + b) * 32 + t) * 128 + d];
    }
    __syncthreads();
    float ar[GB], az[GB], an[GB], hr[GB], hz[GB], hn_[GB];
#pragma unroll
    for (int b = 0; b < GB; ++b) {
      ar[b] = brz; az[b] = bzz; an[b] = bin_;
      hr[b] = 0.f; hz[b] = 0.f; hn_[b] = bhn;
    }
#pragma unroll 4
    for (int k = 0; k < 128; ++k) {
      float w0 = wihT[k * 768 + j];
      float w1 = wihT[k * 768 + 256 + j];
      float w2 = wihT[k * 768 + 512 + j];
#pragma unroll
      for (int b = 0; b < GB; ++b) {
        float x = xr[b][k];
        ar[b] += x * w0; az[b] += x * w1; an[b] += x * w2;
      }
    }
#pragma unroll 4
    for (int k = 0; k < 256; ++k) {
      float w0 = whhT[k * 768 + j];
      float w1 = whhT[k * 768 + 256 + j];
      float w2 = whhT[k * 768 + 512 + j];
#pragma unroll
      for (int b = 0; b < GB; ++b) {
        float hh = hs[b][k];
        hr[b] += hh * w0; hz[b] += hh * w1; hn_[b] += hh * w2;
      }
    }
    float newh[GB];
#pragma unroll
    for (int b = 0; b < GB; ++b) {
      float r = sigm(ar[b] + hr[b]);
      float z = sigm(az[b] + hz[b]);
      float n = tanhf(an[b] + r * hn_[b]);
      newh[b] = (1.f - z) * n + z * hs[b][j];
    }
    __syncthreads();
#pragma unroll
    for (int b = 0; b < GB; ++b) {
      hs[b][j] = newh[b];
      g[((size_t)(b0 + b) * 32 + t) * 512 + dir * 256 + j] = newh[b];
    }
    __syncthreads();
  }
}

// ---------------------------------------------------------------------------
// Stage 3 fused attention: one block per (b, head); QKV for its head computed
// from g with 32-lane-shared weight rows (broadcast). x tile bf16, stride 520
// shorts (uniform 4-way on b128 reads = data floor). LDS = 62,336 B.
// ---------------------------------------------------------------------------
#define XS_STR 520

__global__ __launch_bounds__(256) void k_mha2f(
    const float* __restrict__ g, const float* __restrict__ W,
    const float* __restrict__ Bv, float* __restrict__ attn)
{
  const int b = blockIdx.x, h = blockIdx.y, tid = threadIdx.x;
  __shared__ unsigned short xs[32 * XS_STR];
  __shared__ unsigned short qs[32 * 130];
  __shared__ unsigned short ks[32 * 130];
  __shared__ unsigned short vs[32 * 130];
  __shared__ float sc[32 * 32];
  for (int i = tid; i < 32 * 512; i += 256) {
    int t = i >> 9, c = i & 511;
    xs[t * XS_STR + c] = f2us(g[(size_t)b * 16384 + i]);
  }
  __syncthreads();
  // q/k/v: idx -> (m, d = (idx>>5)&127, t = idx&31); 32 lanes share (m,d).
  for (int idx = tid; idx < 3 * 4096; idx += 256) {
    int m = idx >> 12, r = idx & 4095, d = r >> 5, t = r & 31;
    int wrow = m * 512 + h * 128 + d;
    const float4* wp = reinterpret_cast<const float4*>(W + (size_t)wrow * 512);
    const uint4* xp = reinterpret_cast<const uint4*>(xs + t * XS_STR);
    float acc = 0.f;
#pragma unroll 4
    for (int i = 0; i < 64; ++i) {
      uint4 ux = xp[i];
      float4 wa = wp[2*i], wb = wp[2*i+1];
      float x0 = us2f((unsigned short)(ux.x)), x1 = us2f((unsigned short)(ux.x >> 16));
      float x2 = us2f((unsigned short)(ux.y)), x3 = us2f((unsigned short)(ux.y >> 16));
      float x4 = us2f((unsigned short)(ux.z)), x5 = us2f((unsigned short)(ux.z >> 16));
      float x6 = us2f((unsigned short)(ux.w)), x7 = us2f((unsigned short)(ux.w >> 16));
      acc += x0*wa.x + x1*wa.y + x2*wa.z + x3*wa.w
           + x4*wb.x + x5*wb.y + x6*wb.z + x7*wb.w;
    }
    acc += Bv[wrow];
    unsigned short* dst = (m == 0) ? qs : (m == 1) ? ks : vs;
    dst[t * 130 + d] = f2us(acc);
  }
  __syncthreads();
  const float scale2 = 0.08838834764831845f; // 1/sqrt(128)
  for (int i = tid; i < 1024; i += 256) {
    int qi = i >> 5, ki = i & 31;
    const unsigned short* qp = &qs[qi * 130];  // broadcast
    const unsigned short* kp = &ks[ki * 130];  // stride 65 dwords: distinct banks
    float acc = 0.f;
#pragma unroll
    for (int c = 0; c < 128; ++c) acc += us2f(qp[c]) * us2f(kp[c]);
    sc[i] = acc * scale2;
  }
  __syncthreads();
  if (tid < 32) {
    float* row = &sc[tid * 32];
    float m = row[0];
#pragma unroll
    for (int c = 1; c < 32; ++c) m = fmaxf(m, row[c]);
    float s = 0.f;
#pragma unroll
    for (int c = 0; c < 32; ++c) { float e = expf(row[c] - m); row[c] = e; s += e; }
    float inv = 1.f / s;
#pragma unroll
    for (int c = 0; c < 32; ++c) row[c] *= inv;
  }
  __syncthreads();
  for (int i = tid; i < 4096; i += 256) {
    int t = i >> 7, d = i & 127;
    const float* prow = &sc[t * 32];
    float acc = 0.f;
#pragma unroll
    for (int k = 0; k < 32; ++k) acc += prow[k] * us2f(vs[k * 130 + d]);
    attn[((size_t)b * 32 + t) * 512 + h * 128 + d] = acc;
  }
}

// ---------------------------------------------------------------------------
// proj GEMM (K=512, N=512) + residual + LN, 8 rows/block. Y may alias X.
// ---------------------------------------------------------------------------
__global__ __launch_bounds__(256) void k_proj_ln(
    const float* __restrict__ X, const float* __restrict__ W,
    const float* __restrict__ bias, const float* __restrict__ res,
    const float* __restrict__ gam, const float* __restrict__ bet,
    float* __restrict__ Y)
{
  const int tid = threadIdx.x;
  const int row0 = blockIdx.x * 8;
  __shared__ float xs[8 * 512];
  __shared__ float ys[8 * 512];
  __shared__ float red[256];
  for (int i = tid; i < 8 * 512; i += 256) xs[i] = X[(size_t)row0 * 512 + i];
  __syncthreads();
  for (int j = tid; j < 512; j += 256) {
    const float4* wp = reinterpret_cast<const float4*>(W + (size_t)j * 512);
    float acc[8];
#pragma unroll
    for (int r = 0; r < 8; ++r) acc[r] = 0.f;
    for (int i = 0; i < 64; ++i) {
      float4 wa = wp[2*i], wb = wp[2*i+1];
#pragma unroll
      for (int r = 0; r < 8; ++r) {
        const float* xi = &xs[r * 512 + (i << 3)];
        acc[r] += xi[0]*wa.x + xi[1]*wa.y + xi[2]*wa.z + xi[3]*wa.w
                + xi[4]*wb.x + xi[5]*wb.y + xi[6]*wb.z + xi[7]*wb.w;
      }
    }
    const float bj = bias[j];
#pragma unroll
    for (int r = 0; r < 8; ++r) ys[r * 512 + j] = acc[r] + bj;
  }
  __syncthreads();
  for (int i = tid; i < 8 * 512; i += 256) ys[i] += res[(size_t)row0 * 512 + i];
  __syncthreads();
  for (int r = 0; r < 8; ++r) {
    float part = 0.f;
    for (int i = tid; i < 512; i += 256) part += ys[r * 512 + i];
    red[tid] = part; __syncthreads();
    for (int s = 128; s > 0; s >>= 1) { if (tid < s) red[tid] += red[tid + s]; __syncthreads(); }
    const float mean = red[0] * (1.f / 512.f);
    __syncthreads();
    part = 0.f;
    for (int i = tid; i < 512; i += 256) { float d = ys[r * 512 + i] - mean; part += d * d; }
    red[tid] = part; __syncthreads();
    for (int s = 128; s > 0; s >>= 1) { if (tid < s) red[tid] += red[tid + s]; __syncthreads(); }
    const float rs = rsqrtf(red[0] * (1.f / 512.f) + 1e-5f);
    __syncthreads();
    for (int i = tid; i < 512; i += 256)
      Y[((size_t)row0 + r) * 512 + i] = (ys[r * 512 + i] - mean) * rs * gam[i] + bet[i];
    __syncthreads();
  }
}

// ---------------------------------------------------------------------------
// ff1 GEMM (K=512, N=1024) + relu, 16 rows/block, bf16 output.
// ---------------------------------------------------------------------------
__global__ __launch_bounds__(256) void k_ff1(
    const float* __restrict__ X, const float* __restrict__ W,
    const float* __restrict__ bias, unsigned short* __restrict__ Y)
{
  const int tid = threadIdx.x;
  const int row0 = blockIdx.x * 16;
  __shared__ float xs[16 * 512];
  for (int i = tid; i < 16 * 512; i += 256) xs[i] = X[(size_t)row0 * 512 + i];
  __syncthreads();
  for (int j = tid; j < 1024; j += 256) {
    const float4* wp = reinterpret_cast<const float4*>(W + (size_t)j * 512);
    float acc[16];
#pragma unroll
    for (int r = 0; r < 16; ++r) acc[r] = 0.f;
    for (int i = 0; i < 64; ++i) {
      float4 wa = wp[2*i], wb = wp[2*i+1];
#pragma unroll
      for (int r = 0; r < 16; ++r) {
        const float* xi = &xs[r * 512 + (i << 3)];
        acc[r] += xi[0]*wa.x + xi[1]*wa.y + xi[2]*wa.z + xi[3]*wa.w
                + xi[4]*wb.x + xi[5]*wb.y + xi[6]*wb.z + xi[7]*wb.w;
      }
    }
    const float bj = bias[j];
#pragma unroll
    for (int r = 0; r < 16; ++r)
      Y[(size_t)(row0 + r) * 1024 + j] = f2us(fmaxf(acc[r] + bj, 0.f));
  }
}

// ---------------------------------------------------------------------------
// ff2 GEMM (K=1024 bf16 X, N=512) + residual + LN, 8 rows/block.
// Y fp32 overlays X bf16 in-place (identical 2048 B/row spans); X staged first.
// ---------------------------------------------------------------------------
__global__ __launch_bounds__(256) void k_ff2_ln(
    const unsigned short* __restrict__ X, const float* __restrict__ W,
    const float* __restrict__ bias, const float* __restrict__ res,
    const float* __restrict__ gam, const float* __restrict__ bet,
    float* __restrict__ Y)
{
  const int tid = threadIdx.x;
  const int row0 = blockIdx.x * 8;
  __shared__ float xs[8 * 1024];
  __shared__ float ys[8 * 512];
  __shared__ float red[256];
  for (int i = tid; i < 8 * 1024; i += 256) xs[i] = us2f(X[(size_t)row0 * 1024 + i]);
  __syncthreads();
  for (int j = tid; j < 512; j += 256) {
    const float4* wp = reinterpret_cast<const float4*>(W + (size_t)j * 1024);
    float acc[8];
#pragma unroll
    for (int r = 0; r < 8; ++r) acc[r] = 0.f;
    for (int i = 0; i < 128; ++i) {
      float4 wa = wp[2*i], wb = wp[2*i+1];
#pragma unroll
      for (int r = 0; r < 8; ++r) {
        const float* xi = &xs[r * 1024 + (i << 3)];
        acc[r] += xi[0]*wa.x + xi[1]*wa.y + xi[2]*wa.z + xi[3]*wa.w
                + xi[4]*wb.x + xi[5]*wb.y + xi[6]*wb.z + xi[7]*wb.w;
      }
    }
    const float bj = bias[j];
#pragma unroll
    for (int r = 0; r < 8; ++r) ys[r * 512 + j] = acc[r] + bj;
  }
  __syncthreads();
  for (int i = tid; i < 8 * 512; i += 256) ys[i] += res[(size_t)row0 * 512 + i];
  __syncthreads();
  for (int r = 0; r < 8; ++r) {
    float part = 0.f;
    for (int i = tid; i < 512; i += 256) part += ys[r * 512 + i];
    red[tid] = part; __syncthreads();
    for (int s = 128; s > 0; s >>= 1) { if (tid < s) red[tid] += red[tid + s]; __syncthreads(); }
    const float mean = red[0] * (1.f / 512.f);
    __syncthreads();
    part = 0.f;
    for (int i = tid; i < 512; i += 256) { float d = ys[r * 512 + i] - mean; part += d * d; }
    red[tid] = part; __syncthreads();
    for (int s = 128; s > 0; s >>= 1) { if (tid < s) red[tid] += red[tid + s]; __syncthreads(); }
    const float rs = rsqrtf(red[0] * (1.f / 512.f) + 1e-5f);
    __syncthreads();
    for (int i = tid; i < 512; i += 256)
      Y[((size_t)row0 + r) * 512 + i] = (ys[r * 512 + i] - mean) * rs * gam[i] + bet[i];
    __syncthreads();
  }
}

// ---------------------------------------------------------------------------
// Final: mean-pool, temporal MLP, concat, classifier, LN, relu -> fp32
// ---------------------------------------------------------------------------
__global__ __launch_bounds__(256) void k_final(
    const float* __restrict__ g2,
    const float* __restrict__ db, const float* __restrict__ dsl,
    const float* __restrict__ te1_w, const float* __restrict__ te1_b,
    const float* __restrict__ l1g, const float* __restrict__ l1b,
    const float* __restrict__ te2_w, const float* __restrict__ te2_b,
    const float* __restrict__ l2g, const float* __restrict__ l2b,
    const float* __restrict__ c_w, const float* __restrict__ c_b,
    const float* __restrict__ clg, const float* __restrict__ clb,
    float* __restrict__ out)
{
  const int b = blockIdx.x, tid = threadIdx.x;
  __shared__ float cat[640];
  __shared__ float t1[64];
  __shared__ float t2[128];
  __shared__ float pre[256];
  __shared__ float red[256];
  __shared__ float st[2];
  for (int i = tid; i < 512; i += 256) {
    float acc = 0.f;
#pragma unroll
    for (int t = 0; t < 32; ++t) acc += g2[((size_t)b * 32 + t) * 512 + i];
    cat[i] = acc * (1.f / 32.f);
  }
  if (tid == 0) {
    float s = 0.f;
    for (int i = 0; i < 31; ++i) s += db[b * 31 + i];
    st[0] = s / 31.f;
    st[1] = dsl[b];
  }
  __syncthreads();
  const float f0 = st[0], f1v = st[1];
  if (tid < 64)
    t1[tid] = f0 * te1_w[tid * 2] + f1v * te1_w[tid * 2 + 1] + te1_b[tid];
  __syncthreads();
  if (tid == 0) {
    float m = 0.f; for (int i = 0; i < 64; ++i) m += t1[i]; m *= (1.f / 64.f);
    float v = 0.f; for (int i = 0; i < 64; ++i) { float d = t1[i] - m; v += d * d; }
    st[0] = m; st[1] = rsqrtf(v * (1.f / 64.f) + 1e-5f);
  }
  __syncthreads();
  if (tid < 64) {
    float v = (t1[tid] - st[0]) * st[1] * l1g[tid] + l1b[tid];
    t1[tid] = fmaxf(v, 0.f);
  }
  __syncthreads();
  if (tid < 128)
    t2[tid] = dot_ff(t1, te2_w + (size_t)tid * 64, 64) + te2_b[tid];
  __syncthreads();
  if (tid == 0) {
    float m = 0.f; for (int i = 0; i < 128; ++i) m += t2[i]; m *= (1.f / 128.f);
    float v = 0.f; for (int i = 0; i < 128; ++i) { float d = t2[i] - m; v += d * d; }
    st[0] = m; st[1] = rsqrtf(v * (1.f / 128.f) + 1e-5f);
  }
  __syncthreads();
  if (tid < 128) {
    float v = (t2[tid] - st[0]) * st[1] * l2g[tid] + l2b[tid];
    cat[512 + tid] = fmaxf(v, 0.f);
  }
  __syncthreads();
  pre[tid] = dot_ff(cat, c_w + (size_t)tid * 640, 640) + c_b[tid];
  red[tid] = pre[tid];
  __syncthreads();
  for (int s = 128; s > 0; s >>= 1) { if (tid < s) red[tid] += red[tid + s]; __syncthreads(); }
  const float m = red[0] * (1.f / 256.f);
  __syncthreads();
  const float d = pre[tid] - m;
  red[tid] = d * d;
  __syncthreads();
  for (int s = 128; s > 0; s >>= 1) { if (tid < s) red[tid] += red[tid + s]; __syncthreads(); }
  const float rs = rsqrtf(red[0] * (1.f / 256.f) + 1e-5f);
  float v = d * rs * clg[tid] + clb[tid];
  out[(size_t)b * 256 + tid] = fmaxf(v, 0.f);
}

// ---------------------------------------------------------------------------
extern "C" void kernel_launch(void* const* d_in, const int* in_sizes, int n_in,
                              void* d_out, int out_size, void* d_ws, size_t ws_size,
                              hipStream_t stream) {
  (void)in_sizes; (void)n_in; (void)out_size; (void)ws_size;
  const int*   oh     = (const int*)  d_in[0];
  const float* db     = (const float*)d_in[1];
  const float* dsl    = (const float*)d_in[2];
  const float* emb    = (const float*)d_in[3];
  const float* a_in_w = (const float*)d_in[4];
  const float* a_in_b = (const float*)d_in[5];
  const float* a_out_w= (const float*)d_in[6];
  const float* a_out_b= (const float*)d_in[7];
  const float* wih_f  = (const float*)d_in[8];
  const float* whh_f  = (const float*)d_in[9];
  const float* bih_f  = (const float*)d_in[10];
  const float* bhh_f  = (const float*)d_in[11];
  const float* wih_b  = (const float*)d_in[12];
  const float* whh_b  = (const float*)d_in[13];
  const float* bih_b  = (const float*)d_in[14];
  const float* bhh_b  = (const float*)d_in[15];
  const float* t_in_w = (const float*)d_in[16];
  const float* t_in_b = (const float*)d_in[17];
  const float* t_out_w= (const float*)d_in[18];
  const float* t_out_b= (const float*)d_in[19];
  const float* t_ln1g = (const float*)d_in[20];
  const float* t_ln1b = (const float*)d_in[21];
  const float* t_ff1w = (const float*)d_in[22];
  const float* t_ff1b = (const float*)d_in[23];
  const float* t_ff2w = (const float*)d_in[24];
  const float* t_ff2b = (const float*)d_in[25];
  const float* t_ln2g = (const float*)d_in[26];
  const float* t_ln2b = (const float*)d_in[27];
  const float* te1_w  = (const float*)d_in[28];
  const float* te1_b  = (const float*)d_in[29];
  const float* tl1g   = (const float*)d_in[30];
  const float* tl1b   = (const float*)d_in[31];
  const float* te2_w  = (const float*)d_in[32];
  const float* te2_b  = (const float*)d_in[33];
  const float* tl2g   = (const float*)d_in[34];
  const float* tl2b   = (const float*)d_in[35];
  const float* c_w    = (const float*)d_in[36];
  const float* c_b    = (const float*)d_in[37];
  const float* clng   = (const float*)d_in[38];
  const float* clnb   = (const float*)d_in[39];

  float* ws = (float*)d_ws;
  // Workspace (floats), ~40 MB:
  //   A [0,        1048576): oe  [8192,128] fp32
  //   B [1048576,  5242880): g   [8192,512] fp32 -> f1 bf16 [8192,1024]
  //                          (over dead g) -> g2 fp32 (in-place over f1)
  //   C [5242880,  9437184): attn [8192,512] fp32; g1 = LN out in-place
  //   D [9437184, 10027008): wT transposed GRU weights [2][294912]
  float* oe   = ws;
  float* g    = ws + 1048576;
  float* attn = ws + 5242880;
  float* g1   = attn;                                   // in-place
  unsigned short* f1 = (unsigned short*)(ws + 1048576); // over dead g
  float* g2   = ws + 1048576;                           // in-place over f1
  float* wT   = ws + 9437184;

  k_canary<<<256, 256, 0, stream>>>((float*)d_out);
  k_gru_wt<<<2304, 256, 0, stream>>>(wih_f, whh_f, wih_b, whh_b, wT);
  k_order_attn<<<8192, 256, 0, stream>>>(oh, emb, a_in_w, a_in_b, a_out_w, a_out_b, oe);
  k_gru_rec<<<dim3(64, 2), 256, 0, stream>>>(oe, wT, bih_f, bhh_f, bih_b, bhh_b, g);
  k_mha2f<<<dim3(256, 4), 256, 0, stream>>>(g, t_in_w, t_in_b, attn);
  k_proj_ln<<<1024, 256, 0, stream>>>(attn, t_out_w, t_out_b, g, t_ln1g, t_ln1b, g1);
  k_ff1<<<512, 256, 0, stream>>>(g1, t_ff1w, t_ff1b, f1);
  k_ff2_ln<<<1024, 256, 0, stream>>>(f1, t_ff2w, t_ff2b, g1, t_ln2g, t_ln2b, g2);
  k_final<<<256, 256, 0, stream>>>(g2, db, dsl, te1_w, te1_b, tl1g, tl1b,
                                   te2_w, te2_b, tl2g, tl2b, c_w, c_b, clng, clnb,
                                   (float*)d_out);
}

// Round 6
// 4017.917 us; speedup vs baseline: 4.6716x; 1.0100x over previous
//
#include <hip/hip_runtime.h>
#include <hip/hip_bf16.h>
#include <math.h>

typedef __hip_bfloat16 bf16;

__device__ __forceinline__ float us2f(unsigned short u) {
  union { unsigned u; float f; } c; c.u = ((unsigned)u) << 16; return c.f;
}
__device__ __forceinline__ unsigned short f2us(float f) {
  return __bfloat16_as_ushort(__float2bfloat16(f));
}

// fp32 x (LDS/generic, 16B-aligned) . fp32 w (global, 16B-aligned), K % 8 == 0
__device__ __forceinline__ float dot_ff(const float* __restrict__ x,
                                        const float* __restrict__ w, int K) {
  const float4* xp = reinterpret_cast<const float4*>(x);
  const float4* wp = reinterpret_cast<const float4*>(w);
  float acc = 0.f;
  const int n = K >> 2;
  for (int i = 0; i < n; ++i) {
    float4 a = xp[i], b = wp[i];
    acc += a.x*b.x + a.y*b.y + a.z*b.z + a.w*b.w;
  }
  return acc;
}

__device__ __forceinline__ float sigm(float x) { return 1.f / (1.f + expf(-x)); }

// ---------------------------------------------------------------------------
__global__ void k_canary(float* __restrict__ out) {
  out[blockIdx.x * 256 + threadIdx.x] = 100.0f;
}

// ---------------------------------------------------------------------------
// Stage 1: embed + per-order MHA (L=32, D=128, NH=4, hd=32) + token-mean +
// out-proj folded after mean. One block per (b,o).
// R6: transposed score layout sc[ki*128+r] (kills the 64-way softmax bank
// conflicts of R5); qi is the fast lane index in the score loop; q stored
// bf16 -> LDS 50,560 B = 3 blocks/CU (was 2); o written into dead fp32 kb;
// 2 accumulators per dot (break serial FMA chains).
// ---------------------------------------------------------------------------
#define QB_STR 130   // shorts  (65 dwords, odd -> lane-qi reads conflict-free)
#define KB_STR 129   // floats
#define VB_STR 132   // shorts  (66 dwords -> 2-way, free; 128 was 32-way!)

__global__ __launch_bounds__(256) void k_order_attn(
    const int* __restrict__ oh, const float* __restrict__ emb,
    const float* __restrict__ in_w, const float* __restrict__ in_b,
    const float* __restrict__ out_w, const float* __restrict__ out_b,
    float* __restrict__ order_emb)
{
  const int bo = blockIdx.x;            // 0..8191
  const int tid = threadIdx.x;
  __shared__ float xb[32 * 130];          // x fp32; sc[4096] overlays after QKV
  __shared__ unsigned short qb[32 * QB_STR]; // q bf16
  __shared__ float kb[32 * KB_STR];       // k fp32; reused for o after softmax
  __shared__ unsigned short vb[32 * VB_STR]; // v bf16
  __shared__ float om[128];
  __shared__ int   ids[32];

  if (tid < 32) ids[tid] = oh[bo * 32 + tid];
  __syncthreads();
  for (int i = tid; i < 32 * 128; i += 256) {
    int t = i >> 7, d = i & 127;
    xb[t * 130 + d] = emb[(size_t)ids[t] * 128 + d];
  }
  __syncthreads();
  // qkv: idx -> (j = idx>>5 in [0,384), t = idx&31); 32 lanes share j (weight
  // row broadcast); xb reads stride-130 lane-varying-t float2 = 2-way (free).
  for (int idx = tid; idx < 32 * 384; idx += 256) {
    int j = idx >> 5, t = idx & 31;
    const float4* wp = reinterpret_cast<const float4*>(in_w + (size_t)j * 128);
    const float2* xp = reinterpret_cast<const float2*>(xb + t * 130);
    float a0 = 0.f, a1 = 0.f;
#pragma unroll
    for (int i = 0; i < 8; ++i) {
      float4 wa = wp[2*i], wb = wp[2*i+1];
      float2 x0 = xp[4*i], x1 = xp[4*i+1], x2 = xp[4*i+2], x3 = xp[4*i+3];
      a0 += x0.x*wa.x + x0.y*wa.y + x1.x*wa.z + x1.y*wa.w
          + x2.x*wb.x + x2.y*wb.y + x3.x*wb.z + x3.y*wb.w;
    }
#pragma unroll
    for (int i = 8; i < 16; ++i) {
      float4 wa = wp[2*i], wb = wp[2*i+1];
      float2 x0 = xp[4*i], x1 = xp[4*i+1], x2 = xp[4*i+2], x3 = xp[4*i+3];
      a1 += x0.x*wa.x + x0.y*wa.y + x1.x*wa.z + x1.y*wa.w
          + x2.x*wb.x + x2.y*wb.y + x3.x*wb.z + x3.y*wb.w;
    }
    float acc = a0 + a1 + in_b[j];
    int jj = j & 127;
    if (j < 128)      qb[t * QB_STR + jj] = f2us(acc);
    else if (j < 256) kb[t * KB_STR + jj] = acc;
    else              vb[t * VB_STR + jj] = f2us(acc);
  }
  __syncthreads();
  float* sc = xb;  // transposed scores sc[ki*128 + h*32 + qi] (x dead)
  const float scale1 = 0.17677669529663687f; // 1/sqrt(32)
  for (int i = tid; i < 4096; i += 256) {
    int qi = i & 31, kh = i >> 5, ki = kh & 31, h = kh >> 5;
    const unsigned short* qp = &qb[qi * QB_STR + h * 32]; // lane-qi, stride 65dw
    const float* kp = &kb[ki * KB_STR + h * 32];          // broadcast
    float a0 = 0.f, a1 = 0.f;
#pragma unroll
    for (int c = 0; c < 16; ++c) a0 += us2f(qp[c]) * kp[c];
#pragma unroll
    for (int c = 16; c < 32; ++c) a1 += us2f(qp[c]) * kp[c];
    sc[ki * 128 + h * 32 + qi] = (a0 + a1) * scale1;
  }
  __syncthreads();
  if (tid < 128) {  // softmax: lane r walks sc[c*128 + r] -> 2-way (free)
    const int r = tid;
    float m = sc[r];
#pragma unroll
    for (int c = 1; c < 32; ++c) m = fmaxf(m, sc[c * 128 + r]);
    float s = 0.f;
#pragma unroll
    for (int c = 0; c < 32; ++c) { float e = expf(sc[c * 128 + r] - m); sc[c * 128 + r] = e; s += e; }
    float inv = 1.f / s;
#pragma unroll
    for (int c = 0; c < 32; ++c) sc[c * 128 + r] *= inv;
  }
  __syncthreads();
  // o = p @ v  (into kb; k dead). sc reads: 2 distinct addrs/wave (free).
  for (int i = tid; i < 32 * 128; i += 256) {
    int t = i >> 7, d = i & 127, h = d >> 5;
    float a0 = 0.f, a1 = 0.f;
#pragma unroll
    for (int k = 0; k < 32; k += 2) {
      a0 += sc[k * 128 + h * 32 + t] * us2f(vb[k * VB_STR + d]);
      a1 += sc[(k + 1) * 128 + h * 32 + t] * us2f(vb[(k + 1) * VB_STR + d]);
    }
    kb[t * KB_STR + d] = a0 + a1;
  }
  __syncthreads();
  if (tid < 128) {
    float acc = 0.f;
#pragma unroll
    for (int t = 0; t < 32; ++t) acc += kb[t * KB_STR + tid];
    om[tid] = acc * (1.f / 32.f);
  }
  __syncthreads();
  if (tid < 128) {
    float acc = dot_ff(om, out_w + (size_t)tid * 128, 128) + out_b[tid];
    order_emb[(size_t)bo * 128 + tid] = acc;
  }
}

// ---------------------------------------------------------------------------
// GRU weight transpose (one-shot): wT[dir][k][gate*256+j].
// ---------------------------------------------------------------------------
__global__ __launch_bounds__(256) void k_gru_wt(
    const float* __restrict__ wih_f, const float* __restrict__ whh_f,
    const float* __restrict__ wih_b, const float* __restrict__ whh_b,
    float* __restrict__ wT)
{
  int i = blockIdx.x * 256 + threadIdx.x;   // < 589824
  int dir = i / 294912, r = i % 294912;
  const float* wih = dir ? wih_b : wih_f;
  const float* whh = dir ? whh_b : whh_f;
  float v;
  if (r < 98304) { int k = r / 768, c = r % 768; v = wih[(size_t)c * 128 + k]; }
  else { int r2 = r - 98304; int k = r2 / 768, c = r2 % 768; v = whh[(size_t)c * 256 + k]; }
  wT[i] = v;
}

// ---------------------------------------------------------------------------
// GRU recurrence: 4 batches per block, grid (64, 2).
// ---------------------------------------------------------------------------
#define GB 4

__global__ __launch_bounds__(256) void k_gru_rec(
    const float* __restrict__ oe, const float* __restrict__ wT,
    const float* __restrict__ bih_f, const float* __restrict__ bhh_f,
    const float* __restrict__ bih_b, const float* __restrict__ bhh_b,
    float* __restrict__ g)
{
  const int b0 = blockIdx.x * GB, dir = blockIdx.y, j = threadIdx.x;
  const float* wihT = wT + (size_t)dir * 294912;   // [128][768]
  const float* whhT = wihT + 98304;                // [256][768]
  const float* bih = dir ? bih_b : bih_f;
  const float* bhh = dir ? bhh_b : bhh_f;
  __shared__ float hs[GB][256];
  __shared__ float xr[GB][128];
  const float brz = bih[j] + bhh[j];
  const float bzz = bih[256 + j] + bhh[256 + j];
  const float bin_ = bih[512 + j];
  const float bhn  = bhh[512 + j];
#pragma unroll
  for (int b = 0; b < GB; ++b) hs[b][j] = 0.f;
  __syncthreads();
  for (int s = 0; s < 32; ++s) {
    const int t = dir ? (31 - s) : s;
    for (int i = j; i < GB * 128; i += 256) {
      int b = i >> 7, d = i & 127;
      xr[b][d] = oe[((size_t)(b0 + b) * 32 + t) * 128 + d];
    }
    __syncthreads();
    float ar[GB], az[GB], an[GB], hr[GB], hz[GB], hn_[GB];
#pragma unroll
    for (int b = 0; b < GB; ++b) {
      ar[b] = brz; az[b] = bzz; an[b] = bin_;
      hr[b] = 0.f; hz[b] = 0.f; hn_[b] = bhn;
    }
#pragma unroll 4
    for (int k = 0; k < 128; ++k) {
      float w0 = wihT[k * 768 + j];
      float w1 = wihT[k * 768 + 256 + j];
      float w2 = wihT[k * 768 + 512 + j];
#pragma unroll
      for (int b = 0; b < GB; ++b) {
        float x = xr[b][k];
        ar[b] += x * w0; az[b] += x * w1; an[b] += x * w2;
      }
    }
#pragma unroll 4
    for (int k = 0; k < 256; ++k) {
      float w0 = whhT[k * 768 + j];
      float w1 = whhT[k * 768 + 256 + j];
      float w2 = whhT[k * 768 + 512 + j];
#pragma unroll
      for (int b = 0; b < GB; ++b) {
        float hh = hs[b][k];
        hr[b] += hh * w0; hz[b] += hh * w1; hn_[b] += hh * w2;
      }
    }
    float newh[GB];
#pragma unroll
    for (int b = 0; b < GB; ++b) {
      float r = sigm(ar[b] + hr[b]);
      float z = sigm(az[b] + hz[b]);
      float n = tanhf(an[b] + r * hn_[b]);
      newh[b] = (1.f - z) * n + z * hs[b][j];
    }
    __syncthreads();
#pragma unroll
    for (int b = 0; b < GB; ++b) {
      hs[b][j] = newh[b];
      g[((size_t)(b0 + b) * 32 + t) * 512 + dir * 256 + j] = newh[b];
    }
    __syncthreads();
  }
}

// ---------------------------------------------------------------------------
// Stage 3 fused attention: one block per (b, head). R6: 4 accumulators in the
// K=512 QKV dots (breaks the 512-FMA serial chain of R5).
// ---------------------------------------------------------------------------
#define XS_STR 520

__global__ __launch_bounds__(256) void k_mha2f(
    const float* __restrict__ g, const float* __restrict__ W,
    const float* __restrict__ Bv, float* __restrict__ attn)
{
  const int b = blockIdx.x, h = blockIdx.y, tid = threadIdx.x;
  __shared__ unsigned short xs[32 * XS_STR];
  __shared__ unsigned short qs[32 * 130];
  __shared__ unsigned short ks[32 * 130];
  __shared__ unsigned short vs[32 * 130];
  __shared__ float sc[32 * 32];
  for (int i = tid; i < 32 * 512; i += 256) {
    int t = i >> 9, c = i & 511;
    xs[t * XS_STR + c] = f2us(g[(size_t)b * 16384 + i]);
  }
  __syncthreads();
  // q/k/v: idx -> (m, d = (idx>>5)&127, t = idx&31); 32 lanes share (m,d).
  for (int idx = tid; idx < 3 * 4096; idx += 256) {
    int m = idx >> 12, r = idx & 4095, d = r >> 5, t = r & 31;
    int wrow = m * 512 + h * 128 + d;
    const float4* wp = reinterpret_cast<const float4*>(W + (size_t)wrow * 512);
    const uint4* xp = reinterpret_cast<const uint4*>(xs + t * XS_STR);
    float a0 = 0.f, a1 = 0.f, a2 = 0.f, a3 = 0.f;
#pragma unroll 4
    for (int i = 0; i < 64; i += 4) {
#pragma unroll
      for (int u = 0; u < 4; ++u) {
        uint4 ux = xp[i + u];
        float4 wa = wp[2*(i+u)], wb = wp[2*(i+u)+1];
        float x0 = us2f((unsigned short)(ux.x)), x1 = us2f((unsigned short)(ux.x >> 16));
        float x2 = us2f((unsigned short)(ux.y)), x3 = us2f((unsigned short)(ux.y >> 16));
        float x4 = us2f((unsigned short)(ux.z)), x5 = us2f((unsigned short)(ux.z >> 16));
        float x6 = us2f((unsigned short)(ux.w)), x7 = us2f((unsigned short)(ux.w >> 16));
        float term = x0*wa.x + x1*wa.y + x2*wa.z + x3*wa.w
                   + x4*wb.x + x5*wb.y + x6*wb.z + x7*wb.w;
        if (u == 0) a0 += term; else if (u == 1) a1 += term;
        else if (u == 2) a2 += term; else a3 += term;
      }
    }
    float acc = (a0 + a1) + (a2 + a3) + Bv[wrow];
    unsigned short* dst = (m == 0) ? qs : (m == 1) ? ks : vs;
    dst[t * 130 + d] = f2us(acc);
  }
  __syncthreads();
  const float scale2 = 0.08838834764831845f; // 1/sqrt(128)
  for (int i = tid; i < 1024; i += 256) {
    int qi = i >> 5, ki = i & 31;
    const unsigned short* qp = &qs[qi * 130];  // broadcast
    const unsigned short* kp = &ks[ki * 130];  // stride 65 dwords: distinct banks
    float a0 = 0.f, a1 = 0.f;
#pragma unroll
    for (int c = 0; c < 64; ++c) a0 += us2f(qp[c]) * us2f(kp[c]);
#pragma unroll
    for (int c = 64; c < 128; ++c) a1 += us2f(qp[c]) * us2f(kp[c]);
    sc[i] = (a0 + a1) * scale2;
  }
  __syncthreads();
  if (tid < 32) {
    float* row = &sc[tid * 32];
    float m = row[0];
#pragma unroll
    for (int c = 1; c < 32; ++c) m = fmaxf(m, row[c]);
    float s = 0.f;
#pragma unroll
    for (int c = 0; c < 32; ++c) { float e = expf(row[c] - m); row[c] = e; s += e; }
    float inv = 1.f / s;
#pragma unroll
    for (int c = 0; c < 32; ++c) row[c] *= inv;
  }
  __syncthreads();
  for (int i = tid; i < 4096; i += 256) {
    int t = i >> 7, d = i & 127;
    const float* prow = &sc[t * 32];
    float a0 = 0.f, a1 = 0.f;
#pragma unroll
    for (int k = 0; k < 32; k += 2) {
      a0 += prow[k] * us2f(vs[k * 130 + d]);
      a1 += prow[k + 1] * us2f(vs[(k + 1) * 130 + d]);
    }
    attn[((size_t)b * 32 + t) * 512 + h * 128 + d] = a0 + a1;
  }
}

// ---------------------------------------------------------------------------
// proj GEMM (K=512, N=512) + residual + LN, 8 rows/block. Y may alias X.
// ---------------------------------------------------------------------------
__global__ __launch_bounds__(256) void k_proj_ln(
    const float* __restrict__ X, const float* __restrict__ W,
    const float* __restrict__ bias, const float* __restrict__ res,
    const float* __restrict__ gam, const float* __restrict__ bet,
    float* __restrict__ Y)
{
  const int tid = threadIdx.x;
  const int row0 = blockIdx.x * 8;
  __shared__ float xs[8 * 512];
  __shared__ float ys[8 * 512];
  __shared__ float red[256];
  for (int i = tid; i < 8 * 512; i += 256) xs[i] = X[(size_t)row0 * 512 + i];
  __syncthreads();
  for (int j = tid; j < 512; j += 256) {
    const float4* wp = reinterpret_cast<const float4*>(W + (size_t)j * 512);
    float acc[8];
#pragma unroll
    for (int r = 0; r < 8; ++r) acc[r] = 0.f;
    for (int i = 0; i < 64; ++i) {
      float4 wa = wp[2*i], wb = wp[2*i+1];
#pragma unroll
      for (int r = 0; r < 8; ++r) {
        const float* xi = &xs[r * 512 + (i << 3)];
        acc[r] += xi[0]*wa.x + xi[1]*wa.y + xi[2]*wa.z + xi[3]*wa.w
                + xi[4]*wb.x + xi[5]*wb.y + xi[6]*wb.z + xi[7]*wb.w;
      }
    }
    const float bj = bias[j];
#pragma unroll
    for (int r = 0; r < 8; ++r) ys[r * 512 + j] = acc[r] + bj;
  }
  __syncthreads();
  for (int i = tid; i < 8 * 512; i += 256) ys[i] += res[(size_t)row0 * 512 + i];
  __syncthreads();
  for (int r = 0; r < 8; ++r) {
    float part = 0.f;
    for (int i = tid; i < 512; i += 256) part += ys[r * 512 + i];
    red[tid] = part; __syncthreads();
    for (int s = 128; s > 0; s >>= 1) { if (tid < s) red[tid] += red[tid + s]; __syncthreads(); }
    const float mean = red[0] * (1.f / 512.f);
    __syncthreads();
    part = 0.f;
    for (int i = tid; i < 512; i += 256) { float d = ys[r * 512 + i] - mean; part += d * d; }
    red[tid] = part; __syncthreads();
    for (int s = 128; s > 0; s >>= 1) { if (tid < s) red[tid] += red[tid + s]; __syncthreads(); }
    const float rs = rsqrtf(red[0] * (1.f / 512.f) + 1e-5f);
    __syncthreads();
    for (int i = tid; i < 512; i += 256)
      Y[((size_t)row0 + r) * 512 + i] = (ys[r * 512 + i] - mean) * rs * gam[i] + bet[i];
    __syncthreads();
  }
}

// ---------------------------------------------------------------------------
// ff1 GEMM (K=512, N=1024) + relu, 16 rows/block, bf16 output.
// ---------------------------------------------------------------------------
__global__ __launch_bounds__(256) void k_ff1(
    const float* __restrict__ X, const float* __restrict__ W,
    const float* __restrict__ bias, unsigned short* __restrict__ Y)
{
  const int tid = threadIdx.x;
  const int row0 = blockIdx.x * 16;
  __shared__ float xs[16 * 512];
  for (int i = tid; i < 16 * 512; i += 256) xs[i] = X[(size_t)row0 * 512 + i];
  __syncthreads();
  for (int j = tid; j < 1024; j += 256) {
    const float4* wp = reinterpret_cast<const float4*>(W + (size_t)j * 512);
    float acc[16];
#pragma unroll
    for (int r = 0; r < 16; ++r) acc[r] = 0.f;
    for (int i = 0; i < 64; ++i) {
      float4 wa = wp[2*i], wb = wp[2*i+1];
#pragma unroll
      for (int r = 0; r < 16; ++r) {
        const float* xi = &xs[r * 512 + (i << 3)];
        acc[r] += xi[0]*wa.x + xi[1]*wa.y + xi[2]*wa.z + xi[3]*wa.w
                + xi[4]*wb.x + xi[5]*wb.y + xi[6]*wb.z + xi[7]*wb.w;
      }
    }
    const float bj = bias[j];
#pragma unroll
    for (int r = 0; r < 16; ++r)
      Y[(size_t)(row0 + r) * 1024 + j] = f2us(fmaxf(acc[r] + bj, 0.f));
  }
}

// ---------------------------------------------------------------------------
// ff2 GEMM (K=1024 bf16 X, N=512) + residual + LN, 8 rows/block.
// Y fp32 overlays X bf16 in-place (identical 2048 B/row spans); X staged first.
// ---------------------------------------------------------------------------
__global__ __launch_bounds__(256) void k_ff2_ln(
    const unsigned short* __restrict__ X, const float* __restrict__ W,
    const float* __restrict__ bias, const float* __restrict__ res,
    const float* __restrict__ gam, const float* __restrict__ bet,
    float* __restrict__ Y)
{
  const int tid = threadIdx.x;
  const int row0 = blockIdx.x * 8;
  __shared__ float xs[8 * 1024];
  __shared__ float ys[8 * 512];
  __shared__ float red[256];
  for (int i = tid; i < 8 * 1024; i += 256) xs[i] = us2f(X[(size_t)row0 * 1024 + i]);
  __syncthreads();
  for (int j = tid; j < 512; j += 256) {
    const float4* wp = reinterpret_cast<const float4*>(W + (size_t)j * 1024);
    float acc[8];
#pragma unroll
    for (int r = 0; r < 8; ++r) acc[r] = 0.f;
    for (int i = 0; i < 128; ++i) {
      float4 wa = wp[2*i], wb = wp[2*i+1];
#pragma unroll
      for (int r = 0; r < 8; ++r) {
        const float* xi = &xs[r * 1024 + (i << 3)];
        acc[r] += xi[0]*wa.x + xi[1]*wa.y + xi[2]*wa.z + xi[3]*wa.w
                + xi[4]*wb.x + xi[5]*wb.y + xi[6]*wb.z + xi[7]*wb.w;
      }
    }
    const float bj = bias[j];
#pragma unroll
    for (int r = 0; r < 8; ++r) ys[r * 512 + j] = acc[r] + bj;
  }
  __syncthreads();
  for (int i = tid; i < 8 * 512; i += 256) ys[i] += res[(size_t)row0 * 512 + i];
  __syncthreads();
  for (int r = 0; r < 8; ++r) {
    float part = 0.f;
    for (int i = tid; i < 512; i += 256) part += ys[r * 512 + i];
    red[tid] = part; __syncthreads();
    for (int s = 128; s > 0; s >>= 1) { if (tid < s) red[tid] += red[tid + s]; __syncthreads(); }
    const float mean = red[0] * (1.f / 512.f);
    __syncthreads();
    part = 0.f;
    for (int i = tid; i < 512; i += 256) { float d = ys[r * 512 + i] - mean; part += d * d; }
    red[tid] = part; __syncthreads();
    for (int s = 128; s > 0; s >>= 1) { if (tid < s) red[tid] += red[tid + s]; __syncthreads(); }
    const float rs = rsqrtf(red[0] * (1.f / 512.f) + 1e-5f);
    __syncthreads();
    for (int i = tid; i < 512; i += 256)
      Y[((size_t)row0 + r) * 512 + i] = (ys[r * 512 + i] - mean) * rs * gam[i] + bet[i];
    __syncthreads();
  }
}

// ---------------------------------------------------------------------------
// Final: mean-pool, temporal MLP, concat, classifier, LN, relu -> fp32
// ---------------------------------------------------------------------------
__global__ __launch_bounds__(256) void k_final(
    const float* __restrict__ g2,
    const float* __restrict__ db, const float* __restrict__ dsl,
    const float* __restrict__ te1_w, const float* __restrict__ te1_b,
    const float* __restrict__ l1g, const float* __restrict__ l1b,
    const float* __restrict__ te2_w, const float* __restrict__ te2_b,
    const float* __restrict__ l2g, const float* __restrict__ l2b,
    const float* __restrict__ c_w, const float* __restrict__ c_b,
    const float* __restrict__ clg, const float* __restrict__ clb,
    float* __restrict__ out)
{
  const int b = blockIdx.x, tid = threadIdx.x;
  __shared__ float cat[640];
  __shared__ float t1[64];
  __shared__ float t2[128];
  __shared__ float pre[256];
  __shared__ float red[256];
  __shared__ float st[2];
  for (int i = tid; i < 512; i += 256) {
    float acc = 0.f;
#pragma unroll
    for (int t = 0; t < 32; ++t) acc += g2[((size_t)b * 32 + t) * 512 + i];
    cat[i] = acc * (1.f / 32.f);
  }
  if (tid == 0) {
    float s = 0.f;
    for (int i = 0; i < 31; ++i) s += db[b * 31 + i];
    st[0] = s / 31.f;
    st[1] = dsl[b];
  }
  __syncthreads();
  const float f0 = st[0], f1v = st[1];
  if (tid < 64)
    t1[tid] = f0 * te1_w[tid * 2] + f1v * te1_w[tid * 2 + 1] + te1_b[tid];
  __syncthreads();
  if (tid == 0) {
    float m = 0.f; for (int i = 0; i < 64; ++i) m += t1[i]; m *= (1.f / 64.f);
    float v = 0.f; for (int i = 0; i < 64; ++i) { float d = t1[i] - m; v += d * d; }
    st[0] = m; st[1] = rsqrtf(v * (1.f / 64.f) + 1e-5f);
  }
  __syncthreads();
  if (tid < 64) {
    float v = (t1[tid] - st[0]) * st[1] * l1g[tid] + l1b[tid];
    t1[tid] = fmaxf(v, 0.f);
  }
  __syncthreads();
  if (tid < 128)
    t2[tid] = dot_ff(t1, te2_w + (size_t)tid * 64, 64) + te2_b[tid];
  __syncthreads();
  if (tid == 0) {
    float m = 0.f; for (int i = 0; i < 128; ++i) m += t2[i]; m *= (1.f / 128.f);
    float v = 0.f; for (int i = 0; i < 128; ++i) { float d = t2[i] - m; v += d * d; }
    st[0] = m; st[1] = rsqrtf(v * (1.f / 128.f) + 1e-5f);
  }
  __syncthreads();
  if (tid < 128) {
    float v = (t2[tid] - st[0]) * st[1] * l2g[tid] + l2b[tid];
    cat[512 + tid] = fmaxf(v, 0.f);
  }
  __syncthreads();
  pre[tid] = dot_ff(cat, c_w + (size_t)tid * 640, 640) + c_b[tid];
  red[tid] = pre[tid];
  __syncthreads();
  for (int s = 128; s > 0; s >>= 1) { if (tid < s) red[tid] += red[tid + s]; __syncthreads(); }
  const float m = red[0] * (1.f / 256.f);
  __syncthreads();
  const float d = pre[tid] - m;
  red[tid] = d * d;
  __syncthreads();
  for (int s = 128; s > 0; s >>= 1) { if (tid < s) red[tid] += red[tid + s]; __syncthreads(); }
  const float rs = rsqrtf(red[0] * (1.f / 256.f) + 1e-5f);
  float v = d * rs * clg[tid] + clb[tid];
  out[(size_t)b * 256 + tid] = fmaxf(v, 0.f);
}

// ---------------------------------------------------------------------------
extern "C" void kernel_launch(void* const* d_in, const int* in_sizes, int n_in,
                              void* d_out, int out_size, void* d_ws, size_t ws_size,
                              hipStream_t stream) {
  (void)in_sizes; (void)n_in; (void)out_size; (void)ws_size;
  const int*   oh     = (const int*)  d_in[0];
  const float* db     = (const float*)d_in[1];
  const float* dsl    = (const float*)d_in[2];
  const float* emb    = (const float*)d_in[3];
  const float* a_in_w = (const float*)d_in[4];
  const float* a_in_b = (const float*)d_in[5];
  const float* a_out_w= (const float*)d_in[6];
  const float* a_out_b= (const float*)d_in[7];
  const float* wih_f  = (const float*)d_in[8];
  const float* whh_f  = (const float*)d_in[9];
  const float* bih_f  = (const float*)d_in[10];
  const float* bhh_f  = (const float*)d_in[11];
  const float* wih_b  = (const float*)d_in[12];
  const float* whh_b  = (const float*)d_in[13];
  const float* bih_b  = (const float*)d_in[14];
  const float* bhh_b  = (const float*)d_in[15];
  const float* t_in_w = (const float*)d_in[16];
  const float* t_in_b = (const float*)d_in[17];
  const float* t_out_w= (const float*)d_in[18];
  const float* t_out_b= (const float*)d_in[19];
  const float* t_ln1g = (const float*)d_in[20];
  const float* t_ln1b = (const float*)d_in[21];
  const float* t_ff1w = (const float*)d_in[22];
  const float* t_ff1b = (const float*)d_in[23];
  const float* t_ff2w = (const float*)d_in[24];
  const float* t_ff2b = (const float*)d_in[25];
  const float* t_ln2g = (const float*)d_in[26];
  const float* t_ln2b = (const float*)d_in[27];
  const float* te1_w  = (const float*)d_in[28];
  const float* te1_b  = (const float*)d_in[29];
  const float* tl1g   = (const float*)d_in[30];
  const float* tl1b   = (const float*)d_in[31];
  const float* te2_w  = (const float*)d_in[32];
  const float* te2_b  = (const float*)d_in[33];
  const float* tl2g   = (const float*)d_in[34];
  const float* tl2b   = (const float*)d_in[35];
  const float* c_w    = (const float*)d_in[36];
  const float* c_b    = (const float*)d_in[37];
  const float* clng   = (const float*)d_in[38];
  const float* clnb   = (const float*)d_in[39];

  float* ws = (float*)d_ws;
  // Workspace (floats), ~40 MB:
  //   A [0,        1048576): oe  [8192,128] fp32
  //   B [1048576,  5242880): g fp32 -> f1 bf16 (over dead g) -> g2 fp32
  //   C [5242880,  9437184): attn fp32; g1 = LN out in-place
  //   D [9437184, 10027008): wT transposed GRU weights [2][294912]
  float* oe   = ws;
  float* g    = ws + 1048576;
  float* attn = ws + 5242880;
  float* g1   = attn;                                   // in-place
  unsigned short* f1 = (unsigned short*)(ws + 1048576); // over dead g
  float* g2   = ws + 1048576;                           // in-place over f1
  float* wT   = ws + 9437184;

  k_canary<<<256, 256, 0, stream>>>((float*)d_out);
  k_gru_wt<<<2304, 256, 0, stream>>>(wih_f, whh_f, wih_b, whh_b, wT);
  k_order_attn<<<8192, 256, 0, stream>>>(oh, emb, a_in_w, a_in_b, a_out_w, a_out_b, oe);
  k_gru_rec<<<dim3(64, 2), 256, 0, stream>>>(oe, wT, bih_f, bhh_f, bih_b, bhh_b, g);
  k_mha2f<<<dim3(256, 4), 256, 0, stream>>>(g, t_in_w, t_in_b, attn);
  k_proj_ln<<<1024, 256, 0, stream>>>(attn, t_out_w, t_out_b, g, t_ln1g, t_ln1b, g1);
  k_ff1<<<512, 256, 0, stream>>>(g1, t_ff1w, t_ff1b, f1);
  k_ff2_ln<<<1024, 256, 0, stream>>>(f1, t_ff2w, t_ff2b, g1, t_ln2g, t_ln2b, g2);
  k_final<<<256, 256, 0, stream>>>(g2, db, dsl, te1_w, te1_b, tl1g, tl1b,
                                   te2_w, te2_b, tl2g, tl2b, c_w, c_b, clng, clnb,
                                   (float*)d_out);
}

// Round 7
// 3822.011 us; speedup vs baseline: 4.9111x; 1.0513x over previous
//
#include <hip/hip_runtime.h>
#include <hip/hip_bf16.h>
#include <math.h>

typedef __hip_bfloat16 bf16;

__device__ __forceinline__ float us2f(unsigned short u) {
  union { unsigned u; float f; } c; c.u = ((unsigned)u) << 16; return c.f;
}
__device__ __forceinline__ unsigned short f2us(float f) {
  return __bfloat16_as_ushort(__float2bfloat16(f));
}
__device__ __forceinline__ void unpack2(unsigned u, float& a, float& b) {
  union { unsigned u; float f; } lo, hi;
  lo.u = u << 16; hi.u = u & 0xffff0000u;
  a = lo.f; b = hi.f;
}

// fp32 x (LDS/generic, 16B-aligned) . fp32 w (global, 16B-aligned), K % 8 == 0
__device__ __forceinline__ float dot_ff(const float* __restrict__ x,
                                        const float* __restrict__ w, int K) {
  const float4* xp = reinterpret_cast<const float4*>(x);
  const float4* wp = reinterpret_cast<const float4*>(w);
  float acc = 0.f;
  const int n = K >> 2;
  for (int i = 0; i < n; ++i) {
    float4 a = xp[i], b = wp[i];
    acc += a.x*b.x + a.y*b.y + a.z*b.z + a.w*b.w;
  }
  return acc;
}

__device__ __forceinline__ float sigm(float x) { return 1.f / (1.f + expf(-x)); }

// ---------------------------------------------------------------------------
__global__ void k_canary(float* __restrict__ out) {
  out[blockIdx.x * 256 + threadIdx.x] = 100.0f;
}

// ---------------------------------------------------------------------------
// Stage 1: embed + per-order MHA (L=32, D=128, NH=4, hd=32) + token-mean +
// out-proj folded after mean. One block per (b,o).
// R7: LDS 42,240 B (3 blocks/CU under the ~128KB schedulable budget; R6's
// 50.7KB got only 2). q/k/v bf16; sc fp32 overlays dead x; o fp32 overlays
// dead q+k. QKV: 8 outputs per thread-iter = 8 independent FMA chains and
// 6x (not 48x) LDS re-reads of the x row.
// ---------------------------------------------------------------------------
__global__ __launch_bounds__(256, 3) void k_order_attn(
    const int* __restrict__ oh, const float* __restrict__ emb,
    const float* __restrict__ in_w, const float* __restrict__ in_b,
    const float* __restrict__ out_w, const float* __restrict__ out_b,
    float* __restrict__ order_emb)
{
  const int bo = blockIdx.x;            // 0..8191
  const int tid = threadIdx.x;
  __shared__ float xb[32 * 130];                 // 16,640 B; sc[4096] fp32 overlays
  __shared__ alignas(16) unsigned short qkb[2 * 32 * 130]; // q,k bf16; o fp32 overlays
  __shared__ unsigned short vb[32 * 130];        // 8,320 B
  __shared__ float om[128];
  __shared__ int ids[32];
  unsigned short* qb = qkb;
  unsigned short* kb = qkb + 32 * 130;

  if (tid < 32) ids[tid] = oh[bo * 32 + tid];
  __syncthreads();
  for (int i = tid; i < 32 * 128; i += 256) {
    int t = i >> 7, d = i & 127;
    xb[t * 130 + d] = emb[(size_t)ids[t] * 128 + d];
  }
  __syncthreads();
  // QKV: lane t = tid&31 (x row, LDS stride 130 dwords -> 2-way, free);
  // group grp = tid>>5 handles j = grp*48 + it*8 + u (weight rows broadcast).
  {
    const int t = tid & 31, grp = tid >> 5;
    const float2* xp = reinterpret_cast<const float2*>(xb + t * 130);
    for (int it = 0; it < 6; ++it) {
      const int jbase = grp * 48 + it * 8;
      const float4* wp0 = reinterpret_cast<const float4*>(in_w + (size_t)(jbase + 0) * 128);
      const float4* wp1 = reinterpret_cast<const float4*>(in_w + (size_t)(jbase + 1) * 128);
      const float4* wp2 = reinterpret_cast<const float4*>(in_w + (size_t)(jbase + 2) * 128);
      const float4* wp3 = reinterpret_cast<const float4*>(in_w + (size_t)(jbase + 3) * 128);
      const float4* wp4 = reinterpret_cast<const float4*>(in_w + (size_t)(jbase + 4) * 128);
      const float4* wp5 = reinterpret_cast<const float4*>(in_w + (size_t)(jbase + 5) * 128);
      const float4* wp6 = reinterpret_cast<const float4*>(in_w + (size_t)(jbase + 6) * 128);
      const float4* wp7 = reinterpret_cast<const float4*>(in_w + (size_t)(jbase + 7) * 128);
      float a0=0.f,a1=0.f,a2=0.f,a3=0.f,a4=0.f,a5=0.f,a6=0.f,a7=0.f;
#pragma unroll 8
      for (int c = 0; c < 32; ++c) {
        float2 xa = xp[2 * c], xc = xp[2 * c + 1];
        float4 w;
        w = wp0[c]; a0 += xa.x*w.x + xa.y*w.y + xc.x*w.z + xc.y*w.w;
        w = wp1[c]; a1 += xa.x*w.x + xa.y*w.y + xc.x*w.z + xc.y*w.w;
        w = wp2[c]; a2 += xa.x*w.x + xa.y*w.y + xc.x*w.z + xc.y*w.w;
        w = wp3[c]; a3 += xa.x*w.x + xa.y*w.y + xc.x*w.z + xc.y*w.w;
        w = wp4[c]; a4 += xa.x*w.x + xa.y*w.y + xc.x*w.z + xc.y*w.w;
        w = wp5[c]; a5 += xa.x*w.x + xa.y*w.y + xc.x*w.z + xc.y*w.w;
        w = wp6[c]; a6 += xa.x*w.x + xa.y*w.y + xc.x*w.z + xc.y*w.w;
        w = wp7[c]; a7 += xa.x*w.x + xa.y*w.y + xc.x*w.z + xc.y*w.w;
      }
      float accs[8] = {a0,a1,a2,a3,a4,a5,a6,a7};
#pragma unroll
      for (int u = 0; u < 8; ++u) {
        int j = jbase + u;
        float v = accs[u] + in_b[j];
        int jj = j & 127;
        if (j < 128)      qb[t * 130 + jj] = f2us(v);
        else if (j < 256) kb[t * 130 + jj] = f2us(v);
        else              vb[t * 130 + jj] = f2us(v);
      }
    }
  }
  __syncthreads();
  float* sc = xb;  // fp32 scores overlay (x dead): sc[ki*128 + h*32 + qi]
  const float scale1 = 0.17677669529663687f; // 1/sqrt(32)
  for (int i = tid; i < 4096; i += 256) {
    int qi = i & 31, kh = i >> 5, ki = kh & 31, h = kh >> 5;
    const unsigned short* qp = qb + qi * 130 + h * 32; // lane-qi, 65-dword stride
    const unsigned short* kp = kb + ki * 130 + h * 32; // broadcast
    float a0 = 0.f, a1 = 0.f;
#pragma unroll
    for (int c = 0; c < 32; c += 2) {
      a0 += us2f(qp[c]) * us2f(kp[c]);
      a1 += us2f(qp[c + 1]) * us2f(kp[c + 1]);
    }
    sc[ki * 128 + h * 32 + qi] = (a0 + a1) * scale1;
  }
  __syncthreads();
  if (tid < 128) {  // softmax: lane r -> consecutive dwords per pass (free)
    const int r = tid;
    float m = sc[r];
#pragma unroll
    for (int c = 1; c < 32; ++c) m = fmaxf(m, sc[c * 128 + r]);
    float s = 0.f;
#pragma unroll
    for (int c = 0; c < 32; ++c) { float e = expf(sc[c * 128 + r] - m); sc[c * 128 + r] = e; s += e; }
    float inv = 1.f / s;
#pragma unroll
    for (int c = 0; c < 32; ++c) sc[c * 128 + r] *= inv;
  }
  __syncthreads();
  float* o = reinterpret_cast<float*>(qkb);  // o[t*129+d] overlays dead q,k
  for (int i = tid; i < 4096; i += 256) {
    int t = i >> 7, d = i & 127, h = d >> 5;
    float a0 = 0.f, a1 = 0.f;
#pragma unroll
    for (int k = 0; k < 32; k += 2) {
      a0 += sc[k * 128 + h * 32 + t] * us2f(vb[k * 130 + d]);
      a1 += sc[(k + 1) * 128 + h * 32 + t] * us2f(vb[(k + 1) * 130 + d]);
    }
    o[t * 129 + d] = a0 + a1;
  }
  __syncthreads();
  if (tid < 128) {
    float acc = 0.f;
#pragma unroll
    for (int t = 0; t < 32; ++t) acc += o[t * 129 + tid];
    om[tid] = acc * (1.f / 32.f);
  }
  __syncthreads();
  if (tid < 128) {
    float acc = dot_ff(om, out_w + (size_t)tid * 128, 128) + out_b[tid];
    order_emb[(size_t)bo * 128 + tid] = acc;
  }
}

// ---------------------------------------------------------------------------
// GRU weight transpose (one-shot): wT[dir][k][gate*256+j].
// ---------------------------------------------------------------------------
__global__ __launch_bounds__(256) void k_gru_wt(
    const float* __restrict__ wih_f, const float* __restrict__ whh_f,
    const float* __restrict__ wih_b, const float* __restrict__ whh_b,
    float* __restrict__ wT)
{
  int i = blockIdx.x * 256 + threadIdx.x;   // < 589824
  int dir = i / 294912, r = i % 294912;
  const float* wih = dir ? wih_b : wih_f;
  const float* whh = dir ? whh_b : whh_f;
  float v;
  if (r < 98304) { int k = r / 768, c = r % 768; v = wih[(size_t)c * 128 + k]; }
  else { int r2 = r - 98304; int k = r2 / 768, c = r2 % 768; v = whh[(size_t)c * 256 + k]; }
  wT[i] = v;
}

// ---------------------------------------------------------------------------
// GRU recurrence: 4 batches per block, grid (64, 2).
// ---------------------------------------------------------------------------
#define GB 4

__global__ __launch_bounds__(256) void k_gru_rec(
    const float* __restrict__ oe, const float* __restrict__ wT,
    const float* __restrict__ bih_f, const float* __restrict__ bhh_f,
    const float* __restrict__ bih_b, const float* __restrict__ bhh_b,
    float* __restrict__ g)
{
  const int b0 = blockIdx.x * GB, dir = blockIdx.y, j = threadIdx.x;
  const float* wihT = wT + (size_t)dir * 294912;   // [128][768]
  const float* whhT = wihT + 98304;                // [256][768]
  const float* bih = dir ? bih_b : bih_f;
  const float* bhh = dir ? bhh_b : bhh_f;
  __shared__ float hs[GB][256];
  __shared__ float xr[GB][128];
  const float brz = bih[j] + bhh[j];
  const float bzz = bih[256 + j] + bhh[256 + j];
  const float bin_ = bih[512 + j];
  const float bhn  = bhh[512 + j];
#pragma unroll
  for (int b = 0; b < GB; ++b) hs[b][j] = 0.f;
  __syncthreads();
  for (int s = 0; s < 32; ++s) {
    const int t = dir ? (31 - s) : s;
    for (int i = j; i < GB * 128; i += 256) {
      int b = i >> 7, d = i & 127;
      xr[b][d] = oe[((size_t)(b0 + b) * 32 + t) * 128 + d];
    }
    __syncthreads();
    float ar[GB], az[GB], an[GB], hr[GB], hz[GB], hn_[GB];
#pragma unroll
    for (int b = 0; b < GB; ++b) {
      ar[b] = brz; az[b] = bzz; an[b] = bin_;
      hr[b] = 0.f; hz[b] = 0.f; hn_[b] = bhn;
    }
#pragma unroll 4
    for (int k = 0; k < 128; ++k) {
      float w0 = wihT[k * 768 + j];
      float w1 = wihT[k * 768 + 256 + j];
      float w2 = wihT[k * 768 + 512 + j];
#pragma unroll
      for (int b = 0; b < GB; ++b) {
        float x = xr[b][k];
        ar[b] += x * w0; az[b] += x * w1; an[b] += x * w2;
      }
    }
#pragma unroll 4
    for (int k = 0; k < 256; ++k) {
      float w0 = whhT[k * 768 + j];
      float w1 = whhT[k * 768 + 256 + j];
      float w2 = whhT[k * 768 + 512 + j];
#pragma unroll
      for (int b = 0; b < GB; ++b) {
        float hh = hs[b][k];
        hr[b] += hh * w0; hz[b] += hh * w1; hn_[b] += hh * w2;
      }
    }
    float newh[GB];
#pragma unroll
    for (int b = 0; b < GB; ++b) {
      float r = sigm(ar[b] + hr[b]);
      float z = sigm(az[b] + hz[b]);
      float n = tanhf(an[b] + r * hn_[b]);
      newh[b] = (1.f - z) * n + z * hs[b][j];
    }
    __syncthreads();
#pragma unroll
    for (int b = 0; b < GB; ++b) {
      hs[b][j] = newh[b];
      g[((size_t)(b0 + b) * 32 + t) * 512 + dir * 256 + j] = newh[b];
    }
    __syncthreads();
  }
}

// ---------------------------------------------------------------------------
// Stage 3 fused attention, one block per (b, head).
// R7: xs stride 516 shorts (258 dwords == 2 mod 32 -> 2-way free; R6's 520
// was 8-way conflicted). sc fp32 (stride 33) overlays dead xs. QKV: 8
// outputs per thread-iter (x unpack amortized over 8 dots, 8 FMA chains).
// LDS = 33,024 + 24,960 = 57,984 B.
// ---------------------------------------------------------------------------
#define XS_STR 516

__global__ __launch_bounds__(256, 2) void k_mha2f(
    const float* __restrict__ g, const float* __restrict__ W,
    const float* __restrict__ Bv, float* __restrict__ attn)
{
  const int b = blockIdx.x, h = blockIdx.y, tid = threadIdx.x;
  __shared__ alignas(16) unsigned short xs[32 * XS_STR];
  __shared__ unsigned short qs[32 * 130];
  __shared__ unsigned short ks[32 * 130];
  __shared__ unsigned short vs[32 * 130];
  for (int i = tid; i < 32 * 512; i += 256) {
    int t = i >> 9, c = i & 511;
    xs[t * XS_STR + c] = f2us(g[(size_t)b * 16384 + i]);
  }
  __syncthreads();
  // QKV: lane t = tid&31 (x row via uint2, 2-way free); grp = tid>>5 handles
  // idx = grp*48 + it*8 + u in [0,384): m = idx>>7, d = idx&127.
  {
    const int t = tid & 31, grp = tid >> 5;
    const uint2* xp = reinterpret_cast<const uint2*>(xs + t * XS_STR);
    for (int it = 0; it < 6; ++it) {
      const int ibase = grp * 48 + it * 8;
      const float4* wp[8];
      int wrow[8];
#pragma unroll
      for (int u = 0; u < 8; ++u) {
        int idx = ibase + u, m = idx >> 7, dd = idx & 127;
        wrow[u] = m * 512 + h * 128 + dd;
        wp[u] = reinterpret_cast<const float4*>(W + (size_t)wrow[u] * 512);
      }
      float acc[8];
#pragma unroll
      for (int u = 0; u < 8; ++u) acc[u] = 0.f;
#pragma unroll 4
      for (int c = 0; c < 64; ++c) {
        uint2 ua = xp[2 * c], ub = xp[2 * c + 1];
        float x0,x1,x2,x3,x4,x5,x6,x7;
        unpack2(ua.x, x0, x1); unpack2(ua.y, x2, x3);
        unpack2(ub.x, x4, x5); unpack2(ub.y, x6, x7);
#pragma unroll
        for (int u = 0; u < 8; ++u) {
          float4 wa = wp[u][2 * c], wb = wp[u][2 * c + 1];
          acc[u] += x0*wa.x + x1*wa.y + x2*wa.z + x3*wa.w
                  + x4*wb.x + x5*wb.y + x6*wb.z + x7*wb.w;
        }
      }
#pragma unroll
      for (int u = 0; u < 8; ++u) {
        int idx = ibase + u, m = idx >> 7, dd = idx & 127;
        float v = acc[u] + Bv[wrow[u]];
        unsigned short* dst = (m == 0) ? qs : (m == 1) ? ks : vs;
        dst[t * 130 + dd] = f2us(v);
      }
    }
  }
  __syncthreads();
  float* sc = reinterpret_cast<float*>(xs);  // sc[qi*33 + ki] overlays dead xs
  const float scale2 = 0.08838834764831845f; // 1/sqrt(128)
  for (int i = tid; i < 1024; i += 256) {
    int qi = i >> 5, ki = i & 31;
    const unsigned short* qp = &qs[qi * 130];  // broadcast
    const unsigned short* kp = &ks[ki * 130];  // lane-ki, 65-dword stride
    float a0 = 0.f, a1 = 0.f;
#pragma unroll
    for (int c = 0; c < 128; c += 2) {
      a0 += us2f(qp[c]) * us2f(kp[c]);
      a1 += us2f(qp[c + 1]) * us2f(kp[c + 1]);
    }
    sc[qi * 33 + ki] = (a0 + a1) * scale2;
  }
  __syncthreads();
  if (tid < 32) {   // row r: sc[r*33 + c], lane-r stride 33 -> conflict-free
    float* row = &sc[tid * 33];
    float m = row[0];
#pragma unroll
    for (int c = 1; c < 32; ++c) m = fmaxf(m, row[c]);
    float s = 0.f;
#pragma unroll
    for (int c = 0; c < 32; ++c) { float e = expf(row[c] - m); row[c] = e; s += e; }
    float inv = 1.f / s;
#pragma unroll
    for (int c = 0; c < 32; ++c) row[c] *= inv;
  }
  __syncthreads();
  for (int i = tid; i < 4096; i += 256) {
    int t = i >> 7, d = i & 127;
    const float* prow = &sc[t * 33];   // broadcast
    float a0 = 0.f, a1 = 0.f;
#pragma unroll
    for (int k = 0; k < 32; k += 2) {
      a0 += prow[k] * us2f(vs[k * 130 + d]);
      a1 += prow[k + 1] * us2f(vs[(k + 1) * 130 + d]);
    }
    attn[((size_t)b * 32 + t) * 512 + h * 128 + d] = a0 + a1;
  }
}

// ---------------------------------------------------------------------------
// proj GEMM (K=512, N=512) + residual + LN, 8 rows/block. Y may alias X.
// ---------------------------------------------------------------------------
__global__ __launch_bounds__(256) void k_proj_ln(
    const float* __restrict__ X, const float* __restrict__ W,
    const float* __restrict__ bias, const float* __restrict__ res,
    const float* __restrict__ gam, const float* __restrict__ bet,
    float* __restrict__ Y)
{
  const int tid = threadIdx.x;
  const int row0 = blockIdx.x * 8;
  __shared__ float xs[8 * 512];
  __shared__ float ys[8 * 512];
  __shared__ float red[256];
  for (int i = tid; i < 8 * 512; i += 256) xs[i] = X[(size_t)row0 * 512 + i];
  __syncthreads();
  for (int j = tid; j < 512; j += 256) {
    const float4* wp = reinterpret_cast<const float4*>(W + (size_t)j * 512);
    float acc[8];
#pragma unroll
    for (int r = 0; r < 8; ++r) acc[r] = 0.f;
    for (int i = 0; i < 64; ++i) {
      float4 wa = wp[2*i], wb = wp[2*i+1];
#pragma unroll
      for (int r = 0; r < 8; ++r) {
        const float* xi = &xs[r * 512 + (i << 3)];
        acc[r] += xi[0]*wa.x + xi[1]*wa.y + xi[2]*wa.z + xi[3]*wa.w
                + xi[4]*wb.x + xi[5]*wb.y + xi[6]*wb.z + xi[7]*wb.w;
      }
    }
    const float bj = bias[j];
#pragma unroll
    for (int r = 0; r < 8; ++r) ys[r * 512 + j] = acc[r] + bj;
  }
  __syncthreads();
  for (int i = tid; i < 8 * 512; i += 256) ys[i] += res[(size_t)row0 * 512 + i];
  __syncthreads();
  for (int r = 0; r < 8; ++r) {
    float part = 0.f;
    for (int i = tid; i < 512; i += 256) part += ys[r * 512 + i];
    red[tid] = part; __syncthreads();
    for (int s = 128; s > 0; s >>= 1) { if (tid < s) red[tid] += red[tid + s]; __syncthreads(); }
    const float mean = red[0] * (1.f / 512.f);
    __syncthreads();
    part = 0.f;
    for (int i = tid; i < 512; i += 256) { float d = ys[r * 512 + i] - mean; part += d * d; }
    red[tid] = part; __syncthreads();
    for (int s = 128; s > 0; s >>= 1) { if (tid < s) red[tid] += red[tid + s]; __syncthreads(); }
    const float rs = rsqrtf(red[0] * (1.f / 512.f) + 1e-5f);
    __syncthreads();
    for (int i = tid; i < 512; i += 256)
      Y[((size_t)row0 + r) * 512 + i] = (ys[r * 512 + i] - mean) * rs * gam[i] + bet[i];
    __syncthreads();
  }
}

// ---------------------------------------------------------------------------
// ff1 GEMM (K=512, N=1024) + relu, 16 rows/block, bf16 output.
// ---------------------------------------------------------------------------
__global__ __launch_bounds__(256) void k_ff1(
    const float* __restrict__ X, const float* __restrict__ W,
    const float* __restrict__ bias, unsigned short* __restrict__ Y)
{
  const int tid = threadIdx.x;
  const int row0 = blockIdx.x * 16;
  __shared__ float xs[16 * 512];
  for (int i = tid; i < 16 * 512; i += 256) xs[i] = X[(size_t)row0 * 512 + i];
  __syncthreads();
  for (int j = tid; j < 1024; j += 256) {
    const float4* wp = reinterpret_cast<const float4*>(W + (size_t)j * 512);
    float acc[16];
#pragma unroll
    for (int r = 0; r < 16; ++r) acc[r] = 0.f;
    for (int i = 0; i < 64; ++i) {
      float4 wa = wp[2*i], wb = wp[2*i+1];
#pragma unroll
      for (int r = 0; r < 16; ++r) {
        const float* xi = &xs[r * 512 + (i << 3)];
        acc[r] += xi[0]*wa.x + xi[1]*wa.y + xi[2]*wa.z + xi[3]*wa.w
                + xi[4]*wb.x + xi[5]*wb.y + xi[6]*wb.z + xi[7]*wb.w;
      }
    }
    const float bj = bias[j];
#pragma unroll
    for (int r = 0; r < 16; ++r)
      Y[(size_t)(row0 + r) * 1024 + j] = f2us(fmaxf(acc[r] + bj, 0.f));
  }
}

// ---------------------------------------------------------------------------
// ff2 GEMM (K=1024 bf16 X, N=512) + residual + LN, 8 rows/block.
// Y fp32 overlays X bf16 in-place (identical 2048 B/row spans); X staged first.
// ---------------------------------------------------------------------------
__global__ __launch_bounds__(256) void k_ff2_ln(
    const unsigned short* __restrict__ X, const float* __restrict__ W,
    const float* __restrict__ bias, const float* __restrict__ res,
    const float* __restrict__ gam, const float* __restrict__ bet,
    float* __restrict__ Y)
{
  const int tid = threadIdx.x;
  const int row0 = blockIdx.x * 8;
  __shared__ float xs[8 * 1024];
  __shared__ float ys[8 * 512];
  __shared__ float red[256];
  for (int i = tid; i < 8 * 1024; i += 256) xs[i] = us2f(X[(size_t)row0 * 1024 + i]);
  __syncthreads();
  for (int j = tid; j < 512; j += 256) {
    const float4* wp = reinterpret_cast<const float4*>(W + (size_t)j * 1024);
    float acc[8];
#pragma unroll
    for (int r = 0; r < 8; ++r) acc[r] = 0.f;
    for (int i = 0; i < 128; ++i) {
      float4 wa = wp[2*i], wb = wp[2*i+1];
#pragma unroll
      for (int r = 0; r < 8; ++r) {
        const float* xi = &xs[r * 1024 + (i << 3)];
        acc[r] += xi[0]*wa.x + xi[1]*wa.y + xi[2]*wa.z + xi[3]*wa.w
                + xi[4]*wb.x + xi[5]*wb.y + xi[6]*wb.z + xi[7]*wb.w;
      }
    }
    const float bj = bias[j];
#pragma unroll
    for (int r = 0; r < 8; ++r) ys[r * 512 + j] = acc[r] + bj;
  }
  __syncthreads();
  for (int i = tid; i < 8 * 512; i += 256) ys[i] += res[(size_t)row0 * 512 + i];
  __syncthreads();
  for (int r = 0; r < 8; ++r) {
    float part = 0.f;
    for (int i = tid; i < 512; i += 256) part += ys[r * 512 + i];
    red[tid] = part; __syncthreads();
    for (int s = 128; s > 0; s >>= 1) { if (tid < s) red[tid] += red[tid + s]; __syncthreads(); }
    const float mean = red[0] * (1.f / 512.f);
    __syncthreads();
    part = 0.f;
    for (int i = tid; i < 512; i += 256) { float d = ys[r * 512 + i] - mean; part += d * d; }
    red[tid] = part; __syncthreads();
    for (int s = 128; s > 0; s >>= 1) { if (tid < s) red[tid] += red[tid + s]; __syncthreads(); }
    const float rs = rsqrtf(red[0] * (1.f / 512.f) + 1e-5f);
    __syncthreads();
    for (int i = tid; i < 512; i += 256)
      Y[((size_t)row0 + r) * 512 + i] = (ys[r * 512 + i] - mean) * rs * gam[i] + bet[i];
    __syncthreads();
  }
}

// ---------------------------------------------------------------------------
// Final: mean-pool, temporal MLP, concat, classifier, LN, relu -> fp32
// ---------------------------------------------------------------------------
__global__ __launch_bounds__(256) void k_final(
    const float* __restrict__ g2,
    const float* __restrict__ db, const float* __restrict__ dsl,
    const float* __restrict__ te1_w, const float* __restrict__ te1_b,
    const float* __restrict__ l1g, const float* __restrict__ l1b,
    const float* __restrict__ te2_w, const float* __restrict__ te2_b,
    const float* __restrict__ l2g, const float* __restrict__ l2b,
    const float* __restrict__ c_w, const float* __restrict__ c_b,
    const float* __restrict__ clg, const float* __restrict__ clb,
    float* __restrict__ out)
{
  const int b = blockIdx.x, tid = threadIdx.x;
  __shared__ float cat[640];
  __shared__ float t1[64];
  __shared__ float t2[128];
  __shared__ float pre[256];
  __shared__ float red[256];
  __shared__ float st[2];
  for (int i = tid; i < 512; i += 256) {
    float acc = 0.f;
#pragma unroll
    for (int t = 0; t < 32; ++t) acc += g2[((size_t)b * 32 + t) * 512 + i];
    cat[i] = acc * (1.f / 32.f);
  }
  if (tid == 0) {
    float s = 0.f;
    for (int i = 0; i < 31; ++i) s += db[b * 31 + i];
    st[0] = s / 31.f;
    st[1] = dsl[b];
  }
  __syncthreads();
  const float f0 = st[0], f1v = st[1];
  if (tid < 64)
    t1[tid] = f0 * te1_w[tid * 2] + f1v * te1_w[tid * 2 + 1] + te1_b[tid];
  __syncthreads();
  if (tid == 0) {
    float m = 0.f; for (int i = 0; i < 64; ++i) m += t1[i]; m *= (1.f / 64.f);
    float v = 0.f; for (int i = 0; i < 64; ++i) { float d = t1[i] - m; v += d * d; }
    st[0] = m; st[1] = rsqrtf(v * (1.f / 64.f) + 1e-5f);
  }
  __syncthreads();
  if (tid < 64) {
    float v = (t1[tid] - st[0]) * st[1] * l1g[tid] + l1b[tid];
    t1[tid] = fmaxf(v, 0.f);
  }
  __syncthreads();
  if (tid < 128)
    t2[tid] = dot_ff(t1, te2_w + (size_t)tid * 64, 64) + te2_b[tid];
  __syncthreads();
  if (tid == 0) {
    float m = 0.f; for (int i = 0; i < 128; ++i) m += t2[i]; m *= (1.f / 128.f);
    float v = 0.f; for (int i = 0; i < 128; ++i) { float d = t2[i] - m; v += d * d; }
    st[0] = m; st[1] = rsqrtf(v * (1.f / 128.f) + 1e-5f);
  }
  __syncthreads();
  if (tid < 128) {
    float v = (t2[tid] - st[0]) * st[1] * l2g[tid] + l2b[tid];
    cat[512 + tid] = fmaxf(v, 0.f);
  }
  __syncthreads();
  pre[tid] = dot_ff(cat, c_w + (size_t)tid * 640, 640) + c_b[tid];
  red[tid] = pre[tid];
  __syncthreads();
  for (int s = 128; s > 0; s >>= 1) { if (tid < s) red[tid] += red[tid + s]; __syncthreads(); }
  const float m = red[0] * (1.f / 256.f);
  __syncthreads();
  const float d = pre[tid] - m;
  red[tid] = d * d;
  __syncthreads();
  for (int s = 128; s > 0; s >>= 1) { if (tid < s) red[tid] += red[tid + s]; __syncthreads(); }
  const float rs = rsqrtf(red[0] * (1.f / 256.f) + 1e-5f);
  float v = d * rs * clg[tid] + clb[tid];
  out[(size_t)b * 256 + tid] = fmaxf(v, 0.f);
}

// ---------------------------------------------------------------------------
extern "C" void kernel_launch(void* const* d_in, const int* in_sizes, int n_in,
                              void* d_out, int out_size, void* d_ws, size_t ws_size,
                              hipStream_t stream) {
  (void)in_sizes; (void)n_in; (void)out_size; (void)ws_size;
  const int*   oh     = (const int*)  d_in[0];
  const float* db     = (const float*)d_in[1];
  const float* dsl    = (const float*)d_in[2];
  const float* emb    = (const float*)d_in[3];
  const float* a_in_w = (const float*)d_in[4];
  const float* a_in_b = (const float*)d_in[5];
  const float* a_out_w= (const float*)d_in[6];
  const float* a_out_b= (const float*)d_in[7];
  const float* wih_f  = (const float*)d_in[8];
  const float* whh_f  = (const float*)d_in[9];
  const float* bih_f  = (const float*)d_in[10];
  const float* bhh_f  = (const float*)d_in[11];
  const float* wih_b  = (const float*)d_in[12];
  const float* whh_b  = (const float*)d_in[13];
  const float* bih_b  = (const float*)d_in[14];
  const float* bhh_b  = (const float*)d_in[15];
  const float* t_in_w = (const float*)d_in[16];
  const float* t_in_b = (const float*)d_in[17];
  const float* t_out_w= (const float*)d_in[18];
  const float* t_out_b= (const float*)d_in[19];
  const float* t_ln1g = (const float*)d_in[20];
  const float* t_ln1b = (const float*)d_in[21];
  const float* t_ff1w = (const float*)d_in[22];
  const float* t_ff1b = (const float*)d_in[23];
  const float* t_ff2w = (const float*)d_in[24];
  const float* t_ff2b = (const float*)d_in[25];
  const float* t_ln2g = (const float*)d_in[26];
  const float* t_ln2b = (const float*)d_in[27];
  const float* te1_w  = (const float*)d_in[28];
  const float* te1_b  = (const float*)d_in[29];
  const float* tl1g   = (const float*)d_in[30];
  const float* tl1b   = (const float*)d_in[31];
  const float* te2_w  = (const float*)d_in[32];
  const float* te2_b  = (const float*)d_in[33];
  const float* tl2g   = (const float*)d_in[34];
  const float* tl2b   = (const float*)d_in[35];
  const float* c_w    = (const float*)d_in[36];
  const float* c_b    = (const float*)d_in[37];
  const float* clng   = (const float*)d_in[38];
  const float* clnb   = (const float*)d_in[39];

  float* ws = (float*)d_ws;
  // Workspace (floats), ~40 MB:
  //   A [0,        1048576): oe  [8192,128] fp32
  //   B [1048576,  5242880): g fp32 -> f1 bf16 (over dead g) -> g2 fp32
  //   C [5242880,  9437184): attn fp32; g1 = LN out in-place
  //   D [9437184, 10027008): wT transposed GRU weights [2][294912]
  float* oe   = ws;
  float* g    = ws + 1048576;
  float* attn = ws + 5242880;
  float* g1   = attn;                                   // in-place
  unsigned short* f1 = (unsigned short*)(ws + 1048576); // over dead g
  float* g2   = ws + 1048576;                           // in-place over f1
  float* wT   = ws + 9437184;

  k_canary<<<256, 256, 0, stream>>>((float*)d_out);
  k_gru_wt<<<2304, 256, 0, stream>>>(wih_f, whh_f, wih_b, whh_b, wT);
  k_order_attn<<<8192, 256, 0, stream>>>(oh, emb, a_in_w, a_in_b, a_out_w, a_out_b, oe);
  k_gru_rec<<<dim3(64, 2), 256, 0, stream>>>(oe, wT, bih_f, bhh_f, bih_b, bhh_b, g);
  k_mha2f<<<dim3(256, 4), 256, 0, stream>>>(g, t_in_w, t_in_b, attn);
  k_proj_ln<<<1024, 256, 0, stream>>>(attn, t_out_w, t_out_b, g, t_ln1g, t_ln1b, g1);
  k_ff1<<<512, 256, 0, stream>>>(g1, t_ff1w, t_ff1b, f1);
  k_ff2_ln<<<1024, 256, 0, stream>>>(f1, t_ff2w, t_ff2b, g1, t_ln2g, t_ln2b, g2);
  k_final<<<256, 256, 0, stream>>>(g2, db, dsl, te1_w, te1_b, tl1g, tl1b,
                                   te2_w, te2_b, tl2g, tl2b, c_w, c_b, clng, clnb,
                                   (float*)d_out);
}

// Round 8
// 1886.902 us; speedup vs baseline: 9.9477x; 2.0255x over previous
//
#include <hip/hip_runtime.h>
#include <hip/hip_bf16.h>
#include <math.h>

typedef __hip_bfloat16 bf16;
typedef __attribute__((ext_vector_type(8))) short short8v;   // 8 bf16 (4 VGPRs)
typedef __attribute__((ext_vector_type(4))) float float4v;   // 4 fp32 acc
#define MFMA16 __builtin_amdgcn_mfma_f32_16x16x32_bf16

__device__ __forceinline__ float us2f(unsigned short u) {
  union { unsigned u; float f; } c; c.u = ((unsigned)u) << 16; return c.f;
}
__device__ __forceinline__ unsigned short f2us(float f) {
  return __bfloat16_as_ushort(__float2bfloat16(f));
}

// fp32 x (LDS/generic, 16B-aligned) . fp32 w (global, 16B-aligned), K % 8 == 0
__device__ __forceinline__ float dot_ff(const float* __restrict__ x,
                                        const float* __restrict__ w, int K) {
  const float4* xp = reinterpret_cast<const float4*>(x);
  const float4* wp = reinterpret_cast<const float4*>(w);
  float acc = 0.f;
  const int n = K >> 2;
  for (int i = 0; i < n; ++i) {
    float4 a = xp[i], b = wp[i];
    acc += a.x*b.x + a.y*b.y + a.z*b.z + a.w*b.w;
  }
  return acc;
}

__device__ __forceinline__ float sigm(float x) { return 1.f / (1.f + expf(-x)); }

// ---------------------------------------------------------------------------
__global__ void k_canary(float* __restrict__ out) {
  out[blockIdx.x * 256 + threadIdx.x] = 100.0f;
}

// ---------------------------------------------------------------------------
// One-shot: convert attention/transformer-QKV weights to bf16 in ws.
// awb = a_in_w [384*128], twb = t_in_w [1536*512]
// ---------------------------------------------------------------------------
__global__ __launch_bounds__(256) void k_cvt(
    const float* __restrict__ a_in_w, const float* __restrict__ t_in_w,
    unsigned short* __restrict__ awb, unsigned short* __restrict__ twb)
{
  int i = blockIdx.x * 256 + threadIdx.x;
  if (i < 49152)  awb[i] = f2us(a_in_w[i]);
  if (i < 786432) twb[i] = f2us(t_in_w[i]);
}

// ---------------------------------------------------------------------------
// Stage 1: embed + per-order MHA + token-mean + folded out-proj.
// R8: QKV projection via MFMA 16x16x32 bf16 (M=32 tokens, N=384, K=128).
// Verified layouts (guide §3): A[m=lane&15][k=quad*8+j]; B-frag = W row
// n=lane&15, elements k=quad*8+j (B^T trick); D[row=quad*4+r][col=lane&15].
// LDS: xs 8704 + qkb 16640 + vb 8320 + sc 16384 + om 512 + ids 128 = 50,688 B
// (3 blocks/CU).
// ---------------------------------------------------------------------------
__global__ __launch_bounds__(256, 3) void k_order_attn(
    const int* __restrict__ oh, const float* __restrict__ emb,
    const unsigned short* __restrict__ awb, const float* __restrict__ in_b,
    const float* __restrict__ out_w, const float* __restrict__ out_b,
    float* __restrict__ order_emb)
{
  const int bo = blockIdx.x;            // 0..8191
  const int tid = threadIdx.x;
  __shared__ alignas(16) unsigned short xs[32 * 136];       // x bf16 (A operand)
  __shared__ alignas(16) unsigned short qkb[2 * 32 * 130];  // q,k bf16; o fp32 overlays
  __shared__ unsigned short vb[32 * 130];                   // v bf16
  __shared__ float scb[4096];                               // scores fp32
  __shared__ float om[128];
  __shared__ int ids[32];
  unsigned short* qb = qkb;
  unsigned short* kb = qkb + 32 * 130;

  if (tid < 32) ids[tid] = oh[bo * 32 + tid];
  __syncthreads();
  for (int i = tid; i < 32 * 128; i += 256) {
    int t = i >> 7, d = i & 127;
    xs[t * 136 + d] = f2us(emb[(size_t)ids[t] * 128 + d]);
  }
  __syncthreads();
  // ---- QKV via MFMA: 2 m-tiles x 24 n-tiles x 4 k-steps; 6 n-tiles/wave ----
  {
    const int lane = tid & 63, wave = tid >> 6;
    const int l15 = lane & 15, quad = lane >> 4;
    short8v af[2][4];
#pragma unroll
    for (int mt = 0; mt < 2; ++mt)
#pragma unroll
      for (int kc = 0; kc < 4; ++kc)
        af[mt][kc] = *reinterpret_cast<const short8v*>(
            xs + (mt * 16 + l15) * 136 + kc * 32 + quad * 8);
    for (int ni = 0; ni < 6; ++ni) {
      const int n0 = (wave + ni * 4) * 16;
      const int j = n0 + l15;
      const unsigned short* wrow = awb + (size_t)j * 128;
      float4v acc0 = {0.f, 0.f, 0.f, 0.f}, acc1 = {0.f, 0.f, 0.f, 0.f};
#pragma unroll
      for (int kc = 0; kc < 4; ++kc) {
        short8v bfr = *reinterpret_cast<const short8v*>(wrow + kc * 32 + quad * 8);
        acc0 = MFMA16(af[0][kc], bfr, acc0, 0, 0, 0);
        acc1 = MFMA16(af[1][kc], bfr, acc1, 0, 0, 0);
      }
      const float bj = in_b[j];
      const int jj = j & 127;
      unsigned short* dst = (j < 128) ? qb : (j < 256) ? kb : vb;
#pragma unroll
      for (int r = 0; r < 4; ++r) {
        int t0 = quad * 4 + r;
        dst[t0 * 130 + jj] = f2us(acc0[r] + bj);
        dst[(t0 + 16) * 130 + jj] = f2us(acc1[r] + bj);
      }
    }
  }
  __syncthreads();
  float* sc = scb;  // sc[ki*128 + h*32 + qi]
  const float scale1 = 0.17677669529663687f; // 1/sqrt(32)
  for (int i = tid; i < 4096; i += 256) {
    int qi = i & 31, kh = i >> 5, ki = kh & 31, h = kh >> 5;
    const unsigned short* qp = qb + qi * 130 + h * 32; // lane-qi, 65-dword stride
    const unsigned short* kp = kb + ki * 130 + h * 32; // broadcast
    float a0 = 0.f, a1 = 0.f;
#pragma unroll
    for (int c = 0; c < 32; c += 2) {
      a0 += us2f(qp[c]) * us2f(kp[c]);
      a1 += us2f(qp[c + 1]) * us2f(kp[c + 1]);
    }
    sc[ki * 128 + h * 32 + qi] = (a0 + a1) * scale1;
  }
  __syncthreads();
  if (tid < 128) {  // softmax: lane r walks sc[c*128 + r]
    const int r = tid;
    float m = sc[r];
#pragma unroll
    for (int c = 1; c < 32; ++c) m = fmaxf(m, sc[c * 128 + r]);
    float s = 0.f;
#pragma unroll
    for (int c = 0; c < 32; ++c) { float e = expf(sc[c * 128 + r] - m); sc[c * 128 + r] = e; s += e; }
    float inv = 1.f / s;
#pragma unroll
    for (int c = 0; c < 32; ++c) sc[c * 128 + r] *= inv;
  }
  __syncthreads();
  float* o = reinterpret_cast<float*>(qkb);  // o[t*129+d] overlays dead q,k
  for (int i = tid; i < 4096; i += 256) {
    int t = i >> 7, d = i & 127, h = d >> 5;
    float a0 = 0.f, a1 = 0.f;
#pragma unroll
    for (int k = 0; k < 32; k += 2) {
      a0 += sc[k * 128 + h * 32 + t] * us2f(vb[k * 130 + d]);
      a1 += sc[(k + 1) * 128 + h * 32 + t] * us2f(vb[(k + 1) * 130 + d]);
    }
    o[t * 129 + d] = a0 + a1;
  }
  __syncthreads();
  if (tid < 128) {
    float acc = 0.f;
#pragma unroll
    for (int t = 0; t < 32; ++t) acc += o[t * 129 + tid];
    om[tid] = acc * (1.f / 32.f);
  }
  __syncthreads();
  if (tid < 128) {
    float acc = dot_ff(om, out_w + (size_t)tid * 128, 128) + out_b[tid];
    order_emb[(size_t)bo * 128 + tid] = acc;
  }
}

// ---------------------------------------------------------------------------
// GRU weight transpose (one-shot): wT[dir][k][gate*256+j].
// ---------------------------------------------------------------------------
__global__ __launch_bounds__(256) void k_gru_wt(
    const float* __restrict__ wih_f, const float* __restrict__ whh_f,
    const float* __restrict__ wih_b, const float* __restrict__ whh_b,
    float* __restrict__ wT)
{
  int i = blockIdx.x * 256 + threadIdx.x;   // < 589824
  int dir = i / 294912, r = i % 294912;
  const float* wih = dir ? wih_b : wih_f;
  const float* whh = dir ? whh_b : whh_f;
  float v;
  if (r < 98304) { int k = r / 768, c = r % 768; v = wih[(size_t)c * 128 + k]; }
  else { int r2 = r - 98304; int k = r2 / 768, c = r2 % 768; v = whh[(size_t)c * 256 + k]; }
  wT[i] = v;
}

// ---------------------------------------------------------------------------
// GRU recurrence: 4 batches per block, grid (64, 2).
// ---------------------------------------------------------------------------
#define GB 4

__global__ __launch_bounds__(256) void k_gru_rec(
    const float* __restrict__ oe, const float* __restrict__ wT,
    const float* __restrict__ bih_f, const float* __restrict__ bhh_f,
    const float* __restrict__ bih_b, const float* __restrict__ bhh_b,
    float* __restrict__ g)
{
  const int b0 = blockIdx.x * GB, dir = blockIdx.y, j = threadIdx.x;
  const float* wihT = wT + (size_t)dir * 294912;   // [128][768]
  const float* whhT = wihT + 98304;                // [256][768]
  const float* bih = dir ? bih_b : bih_f;
  const float* bhh = dir ? bhh_b : bhh_f;
  __shared__ float hs[GB][256];
  __shared__ float xr[GB][128];
  const float brz = bih[j] + bhh[j];
  const float bzz = bih[256 + j] + bhh[256 + j];
  const float bin_ = bih[512 + j];
  const float bhn  = bhh[512 + j];
#pragma unroll
  for (int b = 0; b < GB; ++b) hs[b][j] = 0.f;
  __syncthreads();
  for (int s = 0; s < 32; ++s) {
    const int t = dir ? (31 - s) : s;
    for (int i = j; i < GB * 128; i += 256) {
      int b = i >> 7, d = i & 127;
      xr[b][d] = oe[((size_t)(b0 + b) * 32 + t) * 128 + d];
    }
    __syncthreads();
    float ar[GB], az[GB], an[GB], hr[GB], hz[GB], hn_[GB];
#pragma unroll
    for (int b = 0; b < GB; ++b) {
      ar[b] = brz; az[b] = bzz; an[b] = bin_;
      hr[b] = 0.f; hz[b] = 0.f; hn_[b] = bhn;
    }
#pragma unroll 4
    for (int k = 0; k < 128; ++k) {
      float w0 = wihT[k * 768 + j];
      float w1 = wihT[k * 768 + 256 + j];
      float w2 = wihT[k * 768 + 512 + j];
#pragma unroll
      for (int b = 0; b < GB; ++b) {
        float x = xr[b][k];
        ar[b] += x * w0; az[b] += x * w1; an[b] += x * w2;
      }
    }
#pragma unroll 4
    for (int k = 0; k < 256; ++k) {
      float w0 = whhT[k * 768 + j];
      float w1 = whhT[k * 768 + 256 + j];
      float w2 = whhT[k * 768 + 512 + j];
#pragma unroll
      for (int b = 0; b < GB; ++b) {
        float hh = hs[b][k];
        hr[b] += hh * w0; hz[b] += hh * w1; hn_[b] += hh * w2;
      }
    }
    float newh[GB];
#pragma unroll
    for (int b = 0; b < GB; ++b) {
      float r = sigm(ar[b] + hr[b]);
      float z = sigm(az[b] + hz[b]);
      float n = tanhf(an[b] + r * hn_[b]);
      newh[b] = (1.f - z) * n + z * hs[b][j];
    }
    __syncthreads();
#pragma unroll
    for (int b = 0; b < GB; ++b) {
      hs[b][j] = newh[b];
      g[((size_t)(b0 + b) * 32 + t) * 512 + dir * 256 + j] = newh[b];
    }
    __syncthreads();
  }
}

// ---------------------------------------------------------------------------
// Stage 3 fused attention, one block per (b, head).
// R8: head-slice QKV (M=32, N=384, K=512) via MFMA, bf16 weights from ws.
// xs stride 520 shorts (multiple of 8 -> 16B-aligned A-frags).
// LDS: 33,280 + 24,960 = 58,240 B. sc fp32 overlays dead xs.
// ---------------------------------------------------------------------------
#define XS_STR 520

__global__ __launch_bounds__(256, 2) void k_mha2f(
    const float* __restrict__ g, const unsigned short* __restrict__ twb,
    const float* __restrict__ Bv, float* __restrict__ attn)
{
  const int b = blockIdx.x, h = blockIdx.y, tid = threadIdx.x;
  __shared__ alignas(16) unsigned short xs[32 * XS_STR];
  __shared__ unsigned short qs[32 * 130];
  __shared__ unsigned short ks[32 * 130];
  __shared__ unsigned short vs[32 * 130];
  for (int i = tid; i < 32 * 512; i += 256) {
    int t = i >> 9, c = i & 511;
    xs[t * XS_STR + c] = f2us(g[(size_t)b * 16384 + i]);
  }
  __syncthreads();
  // ---- QKV via MFMA: 2 m x 24 n x 16 k tiles; 6 n-tiles/wave, 4 k-chunks --
  {
    const int lane = tid & 63, wave = tid >> 6;
    const int l15 = lane & 15, quad = lane >> 4;
    int wrowi[6];
#pragma unroll
    for (int ni = 0; ni < 6; ++ni) {
      int idx = (wave + ni * 4) * 16 + l15;
      int m = idx >> 7, dd = idx & 127;
      wrowi[ni] = m * 512 + h * 128 + dd;
    }
    float4v acc[6][2];
#pragma unroll
    for (int ni = 0; ni < 6; ++ni)
#pragma unroll
      for (int mt = 0; mt < 2; ++mt) acc[ni][mt] = (float4v){0.f, 0.f, 0.f, 0.f};
    for (int kc4 = 0; kc4 < 4; ++kc4) {
      short8v af[2][4];
#pragma unroll
      for (int mt = 0; mt < 2; ++mt)
#pragma unroll
        for (int u = 0; u < 4; ++u)
          af[mt][u] = *reinterpret_cast<const short8v*>(
              xs + (mt * 16 + l15) * XS_STR + kc4 * 128 + u * 32 + quad * 8);
#pragma unroll
      for (int ni = 0; ni < 6; ++ni) {
        const unsigned short* wrow = twb + (size_t)wrowi[ni] * 512 + kc4 * 128;
#pragma unroll
        for (int u = 0; u < 4; ++u) {
          short8v bfr = *reinterpret_cast<const short8v*>(wrow + u * 32 + quad * 8);
          acc[ni][0] = MFMA16(af[0][u], bfr, acc[ni][0], 0, 0, 0);
          acc[ni][1] = MFMA16(af[1][u], bfr, acc[ni][1], 0, 0, 0);
        }
      }
    }
#pragma unroll
    for (int ni = 0; ni < 6; ++ni) {
      int idx = (wave + ni * 4) * 16 + l15;
      int m = idx >> 7, dd = idx & 127;
      float bj = Bv[wrowi[ni]];
      unsigned short* dst = (m == 0) ? qs : (m == 1) ? ks : vs;
#pragma unroll
      for (int r = 0; r < 4; ++r) {
        int t0 = quad * 4 + r;
        dst[t0 * 130 + dd] = f2us(acc[ni][0][r] + bj);
        dst[(t0 + 16) * 130 + dd] = f2us(acc[ni][1][r] + bj);
      }
    }
  }
  __syncthreads();
  float* sc = reinterpret_cast<float*>(xs);  // sc[qi*33 + ki] overlays dead xs
  const float scale2 = 0.08838834764831845f; // 1/sqrt(128)
  for (int i = tid; i < 1024; i += 256) {
    int qi = i >> 5, ki = i & 31;
    const unsigned short* qp = &qs[qi * 130];  // broadcast
    const unsigned short* kp = &ks[ki * 130];  // lane-ki, 65-dword stride
    float a0 = 0.f, a1 = 0.f;
#pragma unroll
    for (int c = 0; c < 128; c += 2) {
      a0 += us2f(qp[c]) * us2f(kp[c]);
      a1 += us2f(qp[c + 1]) * us2f(kp[c + 1]);
    }
    sc[qi * 33 + ki] = (a0 + a1) * scale2;
  }
  __syncthreads();
  if (tid < 32) {
    float* row = &sc[tid * 33];
    float m = row[0];
#pragma unroll
    for (int c = 1; c < 32; ++c) m = fmaxf(m, row[c]);
    float s = 0.f;
#pragma unroll
    for (int c = 0; c < 32; ++c) { float e = expf(row[c] - m); row[c] = e; s += e; }
    float inv = 1.f / s;
#pragma unroll
    for (int c = 0; c < 32; ++c) row[c] *= inv;
  }
  __syncthreads();
  for (int i = tid; i < 4096; i += 256) {
    int t = i >> 7, d = i & 127;
    const float* prow = &sc[t * 33];   // broadcast
    float a0 = 0.f, a1 = 0.f;
#pragma unroll
    for (int k = 0; k < 32; k += 2) {
      a0 += prow[k] * us2f(vs[k * 130 + d]);
      a1 += prow[k + 1] * us2f(vs[(k + 1) * 130 + d]);
    }
    attn[((size_t)b * 32 + t) * 512 + h * 128 + d] = a0 + a1;
  }
}

// ---------------------------------------------------------------------------
// proj GEMM (K=512, N=512) + residual + LN, 8 rows/block. Y may alias X.
// ---------------------------------------------------------------------------
__global__ __launch_bounds__(256) void k_proj_ln(
    const float* __restrict__ X, const float* __restrict__ W,
    const float* __restrict__ bias, const float* __restrict__ res,
    const float* __restrict__ gam, const float* __restrict__ bet,
    float* __restrict__ Y)
{
  const int tid = threadIdx.x;
  const int row0 = blockIdx.x * 8;
  __shared__ float xs[8 * 512];
  __shared__ float ys[8 * 512];
  __shared__ float red[256];
  for (int i = tid; i < 8 * 512; i += 256) xs[i] = X[(size_t)row0 * 512 + i];
  __syncthreads();
  for (int j = tid; j < 512; j += 256) {
    const float4* wp = reinterpret_cast<const float4*>(W + (size_t)j * 512);
    float acc[8];
#pragma unroll
    for (int r = 0; r < 8; ++r) acc[r] = 0.f;
    for (int i = 0; i < 64; ++i) {
      float4 wa = wp[2*i], wb = wp[2*i+1];
#pragma unroll
      for (int r = 0; r < 8; ++r) {
        const float* xi = &xs[r * 512 + (i << 3)];
        acc[r] += xi[0]*wa.x + xi[1]*wa.y + xi[2]*wa.z + xi[3]*wa.w
                + xi[4]*wb.x + xi[5]*wb.y + xi[6]*wb.z + xi[7]*wb.w;
      }
    }
    const float bj = bias[j];
#pragma unroll
    for (int r = 0; r < 8; ++r) ys[r * 512 + j] = acc[r] + bj;
  }
  __syncthreads();
  for (int i = tid; i < 8 * 512; i += 256) ys[i] += res[(size_t)row0 * 512 + i];
  __syncthreads();
  for (int r = 0; r < 8; ++r) {
    float part = 0.f;
    for (int i = tid; i < 512; i += 256) part += ys[r * 512 + i];
    red[tid] = part; __syncthreads();
    for (int s = 128; s > 0; s >>= 1) { if (tid < s) red[tid] += red[tid + s]; __syncthreads(); }
    const float mean = red[0] * (1.f / 512.f);
    __syncthreads();
    part = 0.f;
    for (int i = tid; i < 512; i += 256) { float d = ys[r * 512 + i] - mean; part += d * d; }
    red[tid] = part; __syncthreads();
    for (int s = 128; s > 0; s >>= 1) { if (tid < s) red[tid] += red[tid + s]; __syncthreads(); }
    const float rs = rsqrtf(red[0] * (1.f / 512.f) + 1e-5f);
    __syncthreads();
    for (int i = tid; i < 512; i += 256)
      Y[((size_t)row0 + r) * 512 + i] = (ys[r * 512 + i] - mean) * rs * gam[i] + bet[i];
    __syncthreads();
  }
}

// ---------------------------------------------------------------------------
// ff1 GEMM (K=512, N=1024) + relu, 16 rows/block, bf16 output.
// ---------------------------------------------------------------------------
__global__ __launch_bounds__(256) void k_ff1(
    const float* __restrict__ X, const float* __restrict__ W,
    const float* __restrict__ bias, unsigned short* __restrict__ Y)
{
  const int tid = threadIdx.x;
  const int row0 = blockIdx.x * 16;
  __shared__ float xs[16 * 512];
  for (int i = tid; i < 16 * 512; i += 256) xs[i] = X[(size_t)row0 * 512 + i];
  __syncthreads();
  for (int j = tid; j < 1024; j += 256) {
    const float4* wp = reinterpret_cast<const float4*>(W + (size_t)j * 512);
    float acc[16];
#pragma unroll
    for (int r = 0; r < 16; ++r) acc[r] = 0.f;
    for (int i = 0; i < 64; ++i) {
      float4 wa = wp[2*i], wb = wp[2*i+1];
#pragma unroll
      for (int r = 0; r < 16; ++r) {
        const float* xi = &xs[r * 512 + (i << 3)];
        acc[r] += xi[0]*wa.x + xi[1]*wa.y + xi[2]*wa.z + xi[3]*wa.w
                + xi[4]*wb.x + xi[5]*wb.y + xi[6]*wb.z + xi[7]*wb.w;
      }
    }
    const float bj = bias[j];
#pragma unroll
    for (int r = 0; r < 16; ++r)
      Y[(size_t)(row0 + r) * 1024 + j] = f2us(fmaxf(acc[r] + bj, 0.f));
  }
}

// ---------------------------------------------------------------------------
// ff2 GEMM (K=1024 bf16 X, N=512) + residual + LN, 8 rows/block.
// Y fp32 overlays X bf16 in-place (identical 2048 B/row spans); X staged first.
// ---------------------------------------------------------------------------
__global__ __launch_bounds__(256) void k_ff2_ln(
    const unsigned short* __restrict__ X, const float* __restrict__ W,
    const float* __restrict__ bias, const float* __restrict__ res,
    const float* __restrict__ gam, const float* __restrict__ bet,
    float* __restrict__ Y)
{
  const int tid = threadIdx.x;
  const int row0 = blockIdx.x * 8;
  __shared__ float xs[8 * 1024];
  __shared__ float ys[8 * 512];
  __shared__ float red[256];
  for (int i = tid; i < 8 * 1024; i += 256) xs[i] = us2f(X[(size_t)row0 * 1024 + i]);
  __syncthreads();
  for (int j = tid; j < 512; j += 256) {
    const float4* wp = reinterpret_cast<const float4*>(W + (size_t)j * 1024);
    float acc[8];
#pragma unroll
    for (int r = 0; r < 8; ++r) acc[r] = 0.f;
    for (int i = 0; i < 128; ++i) {
      float4 wa = wp[2*i], wb = wp[2*i+1];
#pragma unroll
      for (int r = 0; r < 8; ++r) {
        const float* xi = &xs[r * 1024 + (i << 3)];
        acc[r] += xi[0]*wa.x + xi[1]*wa.y + xi[2]*wa.z + xi[3]*wa.w
                + xi[4]*wb.x + xi[5]*wb.y + xi[6]*wb.z + xi[7]*wb.w;
      }
    }
    const float bj = bias[j];
#pragma unroll
    for (int r = 0; r < 8; ++r) ys[r * 512 + j] = acc[r] + bj;
  }
  __syncthreads();
  for (int i = tid; i < 8 * 512; i += 256) ys[i] += res[(size_t)row0 * 512 + i];
  __syncthreads();
  for (int r = 0; r < 8; ++r) {
    float part = 0.f;
    for (int i = tid; i < 512; i += 256) part += ys[r * 512 + i];
    red[tid] = part; __syncthreads();
    for (int s = 128; s > 0; s >>= 1) { if (tid < s) red[tid] += red[tid + s]; __syncthreads(); }
    const float mean = red[0] * (1.f / 512.f);
    __syncthreads();
    part = 0.f;
    for (int i = tid; i < 512; i += 256) { float d = ys[r * 512 + i] - mean; part += d * d; }
    red[tid] = part; __syncthreads();
    for (int s = 128; s > 0; s >>= 1) { if (tid < s) red[tid] += red[tid + s]; __syncthreads(); }
    const float rs = rsqrtf(red[0] * (1.f / 512.f) + 1e-5f);
    __syncthreads();
    for (int i = tid; i < 512; i += 256)
      Y[((size_t)row0 + r) * 512 + i] = (ys[r * 512 + i] - mean) * rs * gam[i] + bet[i];
    __syncthreads();
  }
}

// ---------------------------------------------------------------------------
// Final: mean-pool, temporal MLP, concat, classifier, LN, relu -> fp32
// ---------------------------------------------------------------------------
__global__ __launch_bounds__(256) void k_final(
    const float* __restrict__ g2,
    const float* __restrict__ db, const float* __restrict__ dsl,
    const float* __restrict__ te1_w, const float* __restrict__ te1_b,
    const float* __restrict__ l1g, const float* __restrict__ l1b,
    const float* __restrict__ te2_w, const float* __restrict__ te2_b,
    const float* __restrict__ l2g, const float* __restrict__ l2b,
    const float* __restrict__ c_w, const float* __restrict__ c_b,
    const float* __restrict__ clg, const float* __restrict__ clb,
    float* __restrict__ out)
{
  const int b = blockIdx.x, tid = threadIdx.x;
  __shared__ float cat[640];
  __shared__ float t1[64];
  __shared__ float t2[128];
  __shared__ float pre[256];
  __shared__ float red[256];
  __shared__ float st[2];
  for (int i = tid; i < 512; i += 256) {
    float acc = 0.f;
#pragma unroll
    for (int t = 0; t < 32; ++t) acc += g2[((size_t)b * 32 + t) * 512 + i];
    cat[i] = acc * (1.f / 32.f);
  }
  if (tid == 0) {
    float s = 0.f;
    for (int i = 0; i < 31; ++i) s += db[b * 31 + i];
    st[0] = s / 31.f;
    st[1] = dsl[b];
  }
  __syncthreads();
  const float f0 = st[0], f1v = st[1];
  if (tid < 64)
    t1[tid] = f0 * te1_w[tid * 2] + f1v * te1_w[tid * 2 + 1] + te1_b[tid];
  __syncthreads();
  if (tid == 0) {
    float m = 0.f; for (int i = 0; i < 64; ++i) m += t1[i]; m *= (1.f / 64.f);
    float v = 0.f; for (int i = 0; i < 64; ++i) { float d = t1[i] - m; v += d * d; }
    st[0] = m; st[1] = rsqrtf(v * (1.f / 64.f) + 1e-5f);
  }
  __syncthreads();
  if (tid < 64) {
    float v = (t1[tid] - st[0]) * st[1] * l1g[tid] + l1b[tid];
    t1[tid] = fmaxf(v, 0.f);
  }
  __syncthreads();
  if (tid < 128)
    t2[tid] = dot_ff(t1, te2_w + (size_t)tid * 64, 64) + te2_b[tid];
  __syncthreads();
  if (tid == 0) {
    float m = 0.f; for (int i = 0; i < 128; ++i) m += t2[i]; m *= (1.f / 128.f);
    float v = 0.f; for (int i = 0; i < 128; ++i) { float d = t2[i] - m; v += d * d; }
    st[0] = m; st[1] = rsqrtf(v * (1.f / 128.f) + 1e-5f);
  }
  __syncthreads();
  if (tid < 128) {
    float v = (t2[tid] - st[0]) * st[1] * l2g[tid] + l2b[tid];
    cat[512 + tid] = fmaxf(v, 0.f);
  }
  __syncthreads();
  pre[tid] = dot_ff(cat, c_w + (size_t)tid * 640, 640) + c_b[tid];
  red[tid] = pre[tid];
  __syncthreads();
  for (int s = 128; s > 0; s >>= 1) { if (tid < s) red[tid] += red[tid + s]; __syncthreads(); }
  const float m = red[0] * (1.f / 256.f);
  __syncthreads();
  const float d = pre[tid] - m;
  red[tid] = d * d;
  __syncthreads();
  for (int s = 128; s > 0; s >>= 1) { if (tid < s) red[tid] += red[tid + s]; __syncthreads(); }
  const float rs = rsqrtf(red[0] * (1.f / 256.f) + 1e-5f);
  float v = d * rs * clg[tid] + clb[tid];
  out[(size_t)b * 256 + tid] = fmaxf(v, 0.f);
}

// ---------------------------------------------------------------------------
extern "C" void kernel_launch(void* const* d_in, const int* in_sizes, int n_in,
                              void* d_out, int out_size, void* d_ws, size_t ws_size,
                              hipStream_t stream) {
  (void)in_sizes; (void)n_in; (void)out_size; (void)ws_size;
  const int*   oh     = (const int*)  d_in[0];
  const float* db     = (const float*)d_in[1];
  const float* dsl    = (const float*)d_in[2];
  const float* emb    = (const float*)d_in[3];
  const float* a_in_w = (const float*)d_in[4];
  const float* a_in_b = (const float*)d_in[5];
  const float* a_out_w= (const float*)d_in[6];
  const float* a_out_b= (const float*)d_in[7];
  const float* wih_f  = (const float*)d_in[8];
  const float* whh_f  = (const float*)d_in[9];
  const float* bih_f  = (const float*)d_in[10];
  const float* bhh_f  = (const float*)d_in[11];
  const float* wih_b  = (const float*)d_in[12];
  const float* whh_b  = (const float*)d_in[13];
  const float* bih_b  = (const float*)d_in[14];
  const float* bhh_b  = (const float*)d_in[15];
  const float* t_in_w = (const float*)d_in[16];
  const float* t_in_b = (const float*)d_in[17];
  const float* t_out_w= (const float*)d_in[18];
  const float* t_out_b= (const float*)d_in[19];
  const float* t_ln1g = (const float*)d_in[20];
  const float* t_ln1b = (const float*)d_in[21];
  const float* t_ff1w = (const float*)d_in[22];
  const float* t_ff1b = (const float*)d_in[23];
  const float* t_ff2w = (const float*)d_in[24];
  const float* t_ff2b = (const float*)d_in[25];
  const float* t_ln2g = (const float*)d_in[26];
  const float* t_ln2b = (const float*)d_in[27];
  const float* te1_w  = (const float*)d_in[28];
  const float* te1_b  = (const float*)d_in[29];
  const float* tl1g   = (const float*)d_in[30];
  const float* tl1b   = (const float*)d_in[31];
  const float* te2_w  = (const float*)d_in[32];
  const float* te2_b  = (const float*)d_in[33];
  const float* tl2g   = (const float*)d_in[34];
  const float* tl2b   = (const float*)d_in[35];
  const float* c_w    = (const float*)d_in[36];
  const float* c_b    = (const float*)d_in[37];
  const float* clng   = (const float*)d_in[38];
  const float* clnb   = (const float*)d_in[39];

  float* ws = (float*)d_ws;
  // Workspace (floats), ~41.8 MB:
  //   A [0,        1048576): oe  [8192,128] fp32
  //   B [1048576,  5242880): g fp32 -> f1 bf16 (over dead g) -> g2 fp32
  //   C [5242880,  9437184): attn fp32; g1 = LN out in-place
  //   D [9437184, 10027008): wT transposed GRU weights [2][294912]
  //   E [10027008,10051584): a_in_w bf16 [384*128]
  //   F [10051584,10444800): t_in_w bf16 [1536*512]
  float* oe   = ws;
  float* g    = ws + 1048576;
  float* attn = ws + 5242880;
  float* g1   = attn;                                   // in-place
  unsigned short* f1 = (unsigned short*)(ws + 1048576); // over dead g
  float* g2   = ws + 1048576;                           // in-place over f1
  float* wT   = ws + 9437184;
  unsigned short* awb = (unsigned short*)(ws + 10027008);
  unsigned short* twb = (unsigned short*)(ws + 10051584);

  k_canary<<<256, 256, 0, stream>>>((float*)d_out);
  k_cvt<<<3072, 256, 0, stream>>>(a_in_w, t_in_w, awb, twb);
  k_gru_wt<<<2304, 256, 0, stream>>>(wih_f, whh_f, wih_b, whh_b, wT);
  k_order_attn<<<8192, 256, 0, stream>>>(oh, emb, awb, a_in_b, a_out_w, a_out_b, oe);
  k_gru_rec<<<dim3(64, 2), 256, 0, stream>>>(oe, wT, bih_f, bhh_f, bih_b, bhh_b, g);
  k_mha2f<<<dim3(256, 4), 256, 0, stream>>>(g, twb, t_in_b, attn);
  k_proj_ln<<<1024, 256, 0, stream>>>(attn, t_out_w, t_out_b, g, t_ln1g, t_ln1b, g1);
  k_ff1<<<512, 256, 0, stream>>>(g1, t_ff1w, t_ff1b, f1);
  k_ff2_ln<<<1024, 256, 0, stream>>>(f1, t_ff2w, t_ff2b, g1, t_ln2g, t_ln2b, g2);
  k_final<<<256, 256, 0, stream>>>(g2, db, dsl, te1_w, te1_b, tl1g, tl1b,
                                   te2_w, te2_b, tl2g, tl2b, c_w, c_b, clng, clnb,
                                   (float*)d_out);
}

// Round 9
// 1599.123 us; speedup vs baseline: 11.7379x; 1.1800x over previous
//
#include <hip/hip_runtime.h>
#include <hip/hip_bf16.h>
#include <math.h>

typedef __hip_bfloat16 bf16;
typedef __attribute__((ext_vector_type(8))) short short8v;   // 8 bf16 (4 VGPRs)
typedef __attribute__((ext_vector_type(4))) float float4v;   // 4 fp32 acc
#define MFMA16 __builtin_amdgcn_mfma_f32_16x16x32_bf16

__device__ __forceinline__ float us2f(unsigned short u) {
  union { unsigned u; float f; } c; c.u = ((unsigned)u) << 16; return c.f;
}
__device__ __forceinline__ unsigned short f2us(float f) {
  return __bfloat16_as_ushort(__float2bfloat16(f));
}
__device__ __forceinline__ void unpack2(unsigned u, float& a, float& b) {
  union { unsigned u; float f; } lo, hi;
  lo.u = u << 16; hi.u = u & 0xffff0000u;
  a = lo.f; b = hi.f;
}

// fp32 x (LDS/generic, 16B-aligned) . fp32 w (global, 16B-aligned), K % 8 == 0
__device__ __forceinline__ float dot_ff(const float* __restrict__ x,
                                        const float* __restrict__ w, int K) {
  const float4* xp = reinterpret_cast<const float4*>(x);
  const float4* wp = reinterpret_cast<const float4*>(w);
  float acc = 0.f;
  const int n = K >> 2;
  for (int i = 0; i < n; ++i) {
    float4 a = xp[i], b = wp[i];
    acc += a.x*b.x + a.y*b.y + a.z*b.z + a.w*b.w;
  }
  return acc;
}

__device__ __forceinline__ float sigm(float x) { return 1.f / (1.f + expf(-x)); }

// ---------------------------------------------------------------------------
__global__ void k_canary(float* __restrict__ out) {
  out[blockIdx.x * 256 + threadIdx.x] = 100.0f;
}

// ---------------------------------------------------------------------------
// One-shot: convert attention/transformer-QKV weights to bf16 in ws.
// ---------------------------------------------------------------------------
__global__ __launch_bounds__(256) void k_cvt(
    const float* __restrict__ a_in_w, const float* __restrict__ t_in_w,
    unsigned short* __restrict__ awb, unsigned short* __restrict__ twb)
{
  int i = blockIdx.x * 256 + threadIdx.x;
  if (i < 49152)  awb[i] = f2us(a_in_w[i]);
  if (i < 786432) twb[i] = f2us(t_in_w[i]);
}

// ---------------------------------------------------------------------------
// Stage 1: embed + per-order MHA + token-mean + folded out-proj (MFMA QKV).
// ---------------------------------------------------------------------------
__global__ __launch_bounds__(256, 3) void k_order_attn(
    const int* __restrict__ oh, const float* __restrict__ emb,
    const unsigned short* __restrict__ awb, const float* __restrict__ in_b,
    const float* __restrict__ out_w, const float* __restrict__ out_b,
    float* __restrict__ order_emb)
{
  const int bo = blockIdx.x;            // 0..8191
  const int tid = threadIdx.x;
  __shared__ alignas(16) unsigned short xs[32 * 136];       // x bf16 (A operand)
  __shared__ alignas(16) unsigned short qkb[2 * 32 * 130];  // q,k bf16; o fp32 overlays
  __shared__ unsigned short vb[32 * 130];                   // v bf16
  __shared__ float scb[4096];                               // scores fp32
  __shared__ float om[128];
  __shared__ int ids[32];
  unsigned short* qb = qkb;
  unsigned short* kb = qkb + 32 * 130;

  if (tid < 32) ids[tid] = oh[bo * 32 + tid];
  __syncthreads();
  for (int i = tid; i < 32 * 128; i += 256) {
    int t = i >> 7, d = i & 127;
    xs[t * 136 + d] = f2us(emb[(size_t)ids[t] * 128 + d]);
  }
  __syncthreads();
  // ---- QKV via MFMA: 2 m-tiles x 24 n-tiles x 4 k-steps; 6 n-tiles/wave ----
  {
    const int lane = tid & 63, wave = tid >> 6;
    const int l15 = lane & 15, quad = lane >> 4;
    short8v af[2][4];
#pragma unroll
    for (int mt = 0; mt < 2; ++mt)
#pragma unroll
      for (int kc = 0; kc < 4; ++kc)
        af[mt][kc] = *reinterpret_cast<const short8v*>(
            xs + (mt * 16 + l15) * 136 + kc * 32 + quad * 8);
    for (int ni = 0; ni < 6; ++ni) {
      const int n0 = (wave + ni * 4) * 16;
      const int j = n0 + l15;
      const unsigned short* wrow = awb + (size_t)j * 128;
      float4v acc0 = {0.f, 0.f, 0.f, 0.f}, acc1 = {0.f, 0.f, 0.f, 0.f};
#pragma unroll
      for (int kc = 0; kc < 4; ++kc) {
        short8v bfr = *reinterpret_cast<const short8v*>(wrow + kc * 32 + quad * 8);
        acc0 = MFMA16(af[0][kc], bfr, acc0, 0, 0, 0);
        acc1 = MFMA16(af[1][kc], bfr, acc1, 0, 0, 0);
      }
      const float bj = in_b[j];
      const int jj = j & 127;
      unsigned short* dst = (j < 128) ? qb : (j < 256) ? kb : vb;
#pragma unroll
      for (int r = 0; r < 4; ++r) {
        int t0 = quad * 4 + r;
        dst[t0 * 130 + jj] = f2us(acc0[r] + bj);
        dst[(t0 + 16) * 130 + jj] = f2us(acc1[r] + bj);
      }
    }
  }
  __syncthreads();
  float* sc = scb;  // sc[ki*128 + h*32 + qi]
  const float scale1 = 0.17677669529663687f; // 1/sqrt(32)
  for (int i = tid; i < 4096; i += 256) {
    int qi = i & 31, kh = i >> 5, ki = kh & 31, h = kh >> 5;
    const unsigned short* qp = qb + qi * 130 + h * 32;
    const unsigned short* kp = kb + ki * 130 + h * 32;
    float a0 = 0.f, a1 = 0.f;
#pragma unroll
    for (int c = 0; c < 32; c += 2) {
      a0 += us2f(qp[c]) * us2f(kp[c]);
      a1 += us2f(qp[c + 1]) * us2f(kp[c + 1]);
    }
    sc[ki * 128 + h * 32 + qi] = (a0 + a1) * scale1;
  }
  __syncthreads();
  if (tid < 128) {
    const int r = tid;
    float m = sc[r];
#pragma unroll
    for (int c = 1; c < 32; ++c) m = fmaxf(m, sc[c * 128 + r]);
    float s = 0.f;
#pragma unroll
    for (int c = 0; c < 32; ++c) { float e = expf(sc[c * 128 + r] - m); sc[c * 128 + r] = e; s += e; }
    float inv = 1.f / s;
#pragma unroll
    for (int c = 0; c < 32; ++c) sc[c * 128 + r] *= inv;
  }
  __syncthreads();
  float* o = reinterpret_cast<float*>(qkb);  // o[t*129+d] overlays dead q,k
  for (int i = tid; i < 4096; i += 256) {
    int t = i >> 7, d = i & 127, h = d >> 5;
    float a0 = 0.f, a1 = 0.f;
#pragma unroll
    for (int k = 0; k < 32; k += 2) {
      a0 += sc[k * 128 + h * 32 + t] * us2f(vb[k * 130 + d]);
      a1 += sc[(k + 1) * 128 + h * 32 + t] * us2f(vb[(k + 1) * 130 + d]);
    }
    o[t * 129 + d] = a0 + a1;
  }
  __syncthreads();
  if (tid < 128) {
    float acc = 0.f;
#pragma unroll
    for (int t = 0; t < 32; ++t) acc += o[t * 129 + tid];
    om[tid] = acc * (1.f / 32.f);
  }
  __syncthreads();
  if (tid < 128) {
    float acc = dot_ff(om, out_w + (size_t)tid * 128, 128) + out_b[tid];
    order_emb[(size_t)bo * 128 + tid] = acc;
  }
}

// ---------------------------------------------------------------------------
// R9 GRU weight pack (one-shot): packed bf16 k-pairs, column-major for
// coalesced per-(gate,j) thread loads. wTb[dir][kp][c], kp<64 = x-part
// (k=2kp,2kp+1 of wih), kp in [64,192) = h-part of whh. 294,912 uints.
// ---------------------------------------------------------------------------
__global__ __launch_bounds__(256) void k_gru_wtb(
    const float* __restrict__ wih_f, const float* __restrict__ whh_f,
    const float* __restrict__ wih_b, const float* __restrict__ whh_b,
    unsigned* __restrict__ wTb)
{
  int i = blockIdx.x * 256 + threadIdx.x;   // < 294912
  int dir = i / 147456, r = i % 147456;
  int kp = r / 768, c = r % 768;
  const float* wih = dir ? wih_b : wih_f;
  const float* whh = dir ? whh_b : whh_f;
  float w0, w1;
  if (kp < 64) { w0 = wih[(size_t)c * 128 + 2 * kp]; w1 = wih[(size_t)c * 128 + 2 * kp + 1]; }
  else { int k2 = kp - 64; w0 = whh[(size_t)c * 256 + 2 * k2]; w1 = whh[(size_t)c * 256 + 2 * k2 + 1]; }
  wTb[i] = (unsigned)f2us(w0) | ((unsigned)f2us(w1) << 16);
}

// ---------------------------------------------------------------------------
// R9 GRU recurrence: gate-parallel. 768 threads = (gate g, output j); GB=2
// batches/block; grid (128,2) = 256 blocks = 1/CU (R8 had 128 blocks, 1
// wave/SIMD, occupancy 5.9% -> latency-bound). Weights bf16-packed (half the
// L2 bytes + half the load instrs). h/x reads are wave-broadcast (free);
// weight loads 256 B/wave coalesced. n-gate keeps gin/ghn partials separate.
// LDS: hs 2K + xr 1K + pg 8K = 11 KB.
// ---------------------------------------------------------------------------
__global__ __launch_bounds__(768) void k_gru_rec(
    const float* __restrict__ oe, const unsigned* __restrict__ wTb,
    const float* __restrict__ bih_f, const float* __restrict__ bhh_f,
    const float* __restrict__ bih_b, const float* __restrict__ bhh_b,
    float* __restrict__ g)
{
  const int b0 = blockIdx.x * 2, dir = blockIdx.y;
  const int tid = threadIdx.x;           // 0..767
  const int gsel = tid >> 8, j = tid & 255;
  const unsigned* wp = wTb + (size_t)dir * 147456;
  const float* bih = dir ? bih_b : bih_f;
  const float* bhh = dir ? bhh_b : bhh_f;
  __shared__ float hs[2][256];
  __shared__ float xr[2][128];
  __shared__ float pg[2][4][256];
  const float bi = bih[gsel * 256 + j];
  const float bh = bhh[gsel * 256 + j];
  if (tid < 512) hs[tid >> 8][tid & 255] = 0.f;
  __syncthreads();
  const unsigned* col = wp + gsel * 256 + j;
  for (int s = 0; s < 32; ++s) {
    const int t = dir ? (31 - s) : s;
    if (tid < 256) {
      int b = tid >> 7, d = tid & 127;
      xr[b][d] = oe[((size_t)(b0 + b) * 32 + t) * 128 + d];
    }
    __syncthreads();
    float a0x = 0.f, a1x = 0.f, a0h = 0.f, a1h = 0.f;
#pragma unroll 8
    for (int kp = 0; kp < 64; ++kp) {       // x-part (K=128 paired)
      unsigned u = col[kp * 768];
      float w0, w1; unpack2(u, w0, w1);
      a0x += xr[0][2 * kp] * w0 + xr[0][2 * kp + 1] * w1;
      a1x += xr[1][2 * kp] * w0 + xr[1][2 * kp + 1] * w1;
    }
#pragma unroll 8
    for (int kp = 0; kp < 128; ++kp) {      // h-part (K=256 paired)
      unsigned u = col[(64 + kp) * 768];
      float w0, w1; unpack2(u, w0, w1);
      a0h += hs[0][2 * kp] * w0 + hs[0][2 * kp + 1] * w1;
      a1h += hs[1][2 * kp] * w0 + hs[1][2 * kp + 1] * w1;
    }
    if (gsel < 2) {
      pg[0][gsel][j] = a0x + a0h + bi + bh;
      pg[1][gsel][j] = a1x + a1h + bi + bh;
    } else {
      pg[0][2][j] = a0x + bi;  pg[0][3][j] = a0h + bh;
      pg[1][2][j] = a1x + bi;  pg[1][3][j] = a1h + bh;
    }
    __syncthreads();
    if (tid < 512) {
      int b = tid >> 8;
      float r = sigm(pg[b][0][j]);
      float z = sigm(pg[b][1][j]);
      float n = tanhf(pg[b][2][j] + r * pg[b][3][j]);
      float nh = (1.f - z) * n + z * hs[b][j];
      hs[b][j] = nh;
      g[((size_t)(b0 + b) * 32 + t) * 512 + dir * 256 + j] = nh;
    }
    __syncthreads();
  }
}

// ---------------------------------------------------------------------------
// Stage 3 fused attention, one block per (b, head). MFMA QKV (R8).
// ---------------------------------------------------------------------------
#define XS_STR 520

__global__ __launch_bounds__(256, 2) void k_mha2f(
    const float* __restrict__ g, const unsigned short* __restrict__ twb,
    const float* __restrict__ Bv, float* __restrict__ attn)
{
  const int b = blockIdx.x, h = blockIdx.y, tid = threadIdx.x;
  __shared__ alignas(16) unsigned short xs[32 * XS_STR];
  __shared__ unsigned short qs[32 * 130];
  __shared__ unsigned short ks[32 * 130];
  __shared__ unsigned short vs[32 * 130];
  for (int i = tid; i < 32 * 512; i += 256) {
    int t = i >> 9, c = i & 511;
    xs[t * XS_STR + c] = f2us(g[(size_t)b * 16384 + i]);
  }
  __syncthreads();
  {
    const int lane = tid & 63, wave = tid >> 6;
    const int l15 = lane & 15, quad = lane >> 4;
    int wrowi[6];
#pragma unroll
    for (int ni = 0; ni < 6; ++ni) {
      int idx = (wave + ni * 4) * 16 + l15;
      int m = idx >> 7, dd = idx & 127;
      wrowi[ni] = m * 512 + h * 128 + dd;
    }
    float4v acc[6][2];
#pragma unroll
    for (int ni = 0; ni < 6; ++ni)
#pragma unroll
      for (int mt = 0; mt < 2; ++mt) acc[ni][mt] = (float4v){0.f, 0.f, 0.f, 0.f};
    for (int kc4 = 0; kc4 < 4; ++kc4) {
      short8v af[2][4];
#pragma unroll
      for (int mt = 0; mt < 2; ++mt)
#pragma unroll
        for (int u = 0; u < 4; ++u)
          af[mt][u] = *reinterpret_cast<const short8v*>(
              xs + (mt * 16 + l15) * XS_STR + kc4 * 128 + u * 32 + quad * 8);
#pragma unroll
      for (int ni = 0; ni < 6; ++ni) {
        const unsigned short* wrow = twb + (size_t)wrowi[ni] * 512 + kc4 * 128;
#pragma unroll
        for (int u = 0; u < 4; ++u) {
          short8v bfr = *reinterpret_cast<const short8v*>(wrow + u * 32 + quad * 8);
          acc[ni][0] = MFMA16(af[0][u], bfr, acc[ni][0], 0, 0, 0);
          acc[ni][1] = MFMA16(af[1][u], bfr, acc[ni][1], 0, 0, 0);
        }
      }
    }
#pragma unroll
    for (int ni = 0; ni < 6; ++ni) {
      int idx = (wave + ni * 4) * 16 + l15;
      int m = idx >> 7, dd = idx & 127;
      float bj = Bv[wrowi[ni]];
      unsigned short* dst = (m == 0) ? qs : (m == 1) ? ks : vs;
#pragma unroll
      for (int r = 0; r < 4; ++r) {
        int t0 = quad * 4 + r;
        dst[t0 * 130 + dd] = f2us(acc[ni][0][r] + bj);
        dst[(t0 + 16) * 130 + dd] = f2us(acc[ni][1][r] + bj);
      }
    }
  }
  __syncthreads();
  float* sc = reinterpret_cast<float*>(xs);  // sc[qi*33 + ki] overlays dead xs
  const float scale2 = 0.08838834764831845f; // 1/sqrt(128)
  for (int i = tid; i < 1024; i += 256) {
    int qi = i >> 5, ki = i & 31;
    const unsigned short* qp = &qs[qi * 130];
    const unsigned short* kp = &ks[ki * 130];
    float a0 = 0.f, a1 = 0.f;
#pragma unroll
    for (int c = 0; c < 128; c += 2) {
      a0 += us2f(qp[c]) * us2f(kp[c]);
      a1 += us2f(qp[c + 1]) * us2f(kp[c + 1]);
    }
    sc[qi * 33 + ki] = (a0 + a1) * scale2;
  }
  __syncthreads();
  if (tid < 32) {
    float* row = &sc[tid * 33];
    float m = row[0];
#pragma unroll
    for (int c = 1; c < 32; ++c) m = fmaxf(m, row[c]);
    float s = 0.f;
#pragma unroll
    for (int c = 0; c < 32; ++c) { float e = expf(row[c] - m); row[c] = e; s += e; }
    float inv = 1.f / s;
#pragma unroll
    for (int c = 0; c < 32; ++c) row[c] *= inv;
  }
  __syncthreads();
  for (int i = tid; i < 4096; i += 256) {
    int t = i >> 7, d = i & 127;
    const float* prow = &sc[t * 33];
    float a0 = 0.f, a1 = 0.f;
#pragma unroll
    for (int k = 0; k < 32; k += 2) {
      a0 += prow[k] * us2f(vs[k * 130 + d]);
      a1 += prow[k + 1] * us2f(vs[(k + 1) * 130 + d]);
    }
    attn[((size_t)b * 32 + t) * 512 + h * 128 + d] = a0 + a1;
  }
}

// ---------------------------------------------------------------------------
// proj GEMM (K=512, N=512) + residual + LN, 8 rows/block. Y may alias X.
// ---------------------------------------------------------------------------
__global__ __launch_bounds__(256) void k_proj_ln(
    const float* __restrict__ X, const float* __restrict__ W,
    const float* __restrict__ bias, const float* __restrict__ res,
    const float* __restrict__ gam, const float* __restrict__ bet,
    float* __restrict__ Y)
{
  const int tid = threadIdx.x;
  const int row0 = blockIdx.x * 8;
  __shared__ float xs[8 * 512];
  __shared__ float ys[8 * 512];
  __shared__ float red[256];
  for (int i = tid; i < 8 * 512; i += 256) xs[i] = X[(size_t)row0 * 512 + i];
  __syncthreads();
  for (int j = tid; j < 512; j += 256) {
    const float4* wp = reinterpret_cast<const float4*>(W + (size_t)j * 512);
    float acc[8];
#pragma unroll
    for (int r = 0; r < 8; ++r) acc[r] = 0.f;
    for (int i = 0; i < 64; ++i) {
      float4 wa = wp[2*i], wb = wp[2*i+1];
#pragma unroll
      for (int r = 0; r < 8; ++r) {
        const float* xi = &xs[r * 512 + (i << 3)];
        acc[r] += xi[0]*wa.x + xi[1]*wa.y + xi[2]*wa.z + xi[3]*wa.w
                + xi[4]*wb.x + xi[5]*wb.y + xi[6]*wb.z + xi[7]*wb.w;
      }
    }
    const float bj = bias[j];
#pragma unroll
    for (int r = 0; r < 8; ++r) ys[r * 512 + j] = acc[r] + bj;
  }
  __syncthreads();
  for (int i = tid; i < 8 * 512; i += 256) ys[i] += res[(size_t)row0 * 512 + i];
  __syncthreads();
  for (int r = 0; r < 8; ++r) {
    float part = 0.f;
    for (int i = tid; i < 512; i += 256) part += ys[r * 512 + i];
    red[tid] = part; __syncthreads();
    for (int s = 128; s > 0; s >>= 1) { if (tid < s) red[tid] += red[tid + s]; __syncthreads(); }
    const float mean = red[0] * (1.f / 512.f);
    __syncthreads();
    part = 0.f;
    for (int i = tid; i < 512; i += 256) { float d = ys[r * 512 + i] - mean; part += d * d; }
    red[tid] = part; __syncthreads();
    for (int s = 128; s > 0; s >>= 1) { if (tid < s) red[tid] += red[tid + s]; __syncthreads(); }
    const float rs = rsqrtf(red[0] * (1.f / 512.f) + 1e-5f);
    __syncthreads();
    for (int i = tid; i < 512; i += 256)
      Y[((size_t)row0 + r) * 512 + i] = (ys[r * 512 + i] - mean) * rs * gam[i] + bet[i];
    __syncthreads();
  }
}

// ---------------------------------------------------------------------------
// ff1 GEMM (K=512, N=1024) + relu, 16 rows/block, bf16 output.
// ---------------------------------------------------------------------------
__global__ __launch_bounds__(256) void k_ff1(
    const float* __restrict__ X, const float* __restrict__ W,
    const float* __restrict__ bias, unsigned short* __restrict__ Y)
{
  const int tid = threadIdx.x;
  const int row0 = blockIdx.x * 16;
  __shared__ float xs[16 * 512];
  for (int i = tid; i < 16 * 512; i += 256) xs[i] = X[(size_t)row0 * 512 + i];
  __syncthreads();
  for (int j = tid; j < 1024; j += 256) {
    const float4* wp = reinterpret_cast<const float4*>(W + (size_t)j * 512);
    float acc[16];
#pragma unroll
    for (int r = 0; r < 16; ++r) acc[r] = 0.f;
    for (int i = 0; i < 64; ++i) {
      float4 wa = wp[2*i], wb = wp[2*i+1];
#pragma unroll
      for (int r = 0; r < 16; ++r) {
        const float* xi = &xs[r * 512 + (i << 3)];
        acc[r] += xi[0]*wa.x + xi[1]*wa.y + xi[2]*wa.z + xi[3]*wa.w
                + xi[4]*wb.x + xi[5]*wb.y + xi[6]*wb.z + xi[7]*wb.w;
      }
    }
    const float bj = bias[j];
#pragma unroll
    for (int r = 0; r < 16; ++r)
      Y[(size_t)(row0 + r) * 1024 + j] = f2us(fmaxf(acc[r] + bj, 0.f));
  }
}

// ---------------------------------------------------------------------------
// ff2 GEMM (K=1024 bf16 X, N=512) + residual + LN, 8 rows/block.
// ---------------------------------------------------------------------------
__global__ __launch_bounds__(256) void k_ff2_ln(
    const unsigned short* __restrict__ X, const float* __restrict__ W,
    const float* __restrict__ bias, const float* __restrict__ res,
    const float* __restrict__ gam, const float* __restrict__ bet,
    float* __restrict__ Y)
{
  const int tid = threadIdx.x;
  const int row0 = blockIdx.x * 8;
  __shared__ float xs[8 * 1024];
  __shared__ float ys[8 * 512];
  __shared__ float red[256];
  for (int i = tid; i < 8 * 1024; i += 256) xs[i] = us2f(X[(size_t)row0 * 1024 + i]);
  __syncthreads();
  for (int j = tid; j < 512; j += 256) {
    const float4* wp = reinterpret_cast<const float4*>(W + (size_t)j * 1024);
    float acc[8];
#pragma unroll
    for (int r = 0; r < 8; ++r) acc[r] = 0.f;
    for (int i = 0; i < 128; ++i) {
      float4 wa = wp[2*i], wb = wp[2*i+1];
#pragma unroll
      for (int r = 0; r < 8; ++r) {
        const float* xi = &xs[r * 1024 + (i << 3)];
        acc[r] += xi[0]*wa.x + xi[1]*wa.y + xi[2]*wa.z + xi[3]*wa.w
                + xi[4]*wb.x + xi[5]*wb.y + xi[6]*wb.z + xi[7]*wb.w;
      }
    }
    const float bj = bias[j];
#pragma unroll
    for (int r = 0; r < 8; ++r) ys[r * 512 + j] = acc[r] + bj;
  }
  __syncthreads();
  for (int i = tid; i < 8 * 512; i += 256) ys[i] += res[(size_t)row0 * 512 + i];
  __syncthreads();
  for (int r = 0; r < 8; ++r) {
    float part = 0.f;
    for (int i = tid; i < 512; i += 256) part += ys[r * 512 + i];
    red[tid] = part; __syncthreads();
    for (int s = 128; s > 0; s >>= 1) { if (tid < s) red[tid] += red[tid + s]; __syncthreads(); }
    const float mean = red[0] * (1.f / 512.f);
    __syncthreads();
    part = 0.f;
    for (int i = tid; i < 512; i += 256) { float d = ys[r * 512 + i] - mean; part += d * d; }
    red[tid] = part; __syncthreads();
    for (int s = 128; s > 0; s >>= 1) { if (tid < s) red[tid] += red[tid + s]; __syncthreads(); }
    const float rs = rsqrtf(red[0] * (1.f / 512.f) + 1e-5f);
    __syncthreads();
    for (int i = tid; i < 512; i += 256)
      Y[((size_t)row0 + r) * 512 + i] = (ys[r * 512 + i] - mean) * rs * gam[i] + bet[i];
    __syncthreads();
  }
}

// ---------------------------------------------------------------------------
// Final: mean-pool, temporal MLP, concat, classifier, LN, relu -> fp32
// ---------------------------------------------------------------------------
__global__ __launch_bounds__(256) void k_final(
    const float* __restrict__ g2,
    const float* __restrict__ db, const float* __restrict__ dsl,
    const float* __restrict__ te1_w, const float* __restrict__ te1_b,
    const float* __restrict__ l1g, const float* __restrict__ l1b,
    const float* __restrict__ te2_w, const float* __restrict__ te2_b,
    const float* __restrict__ l2g, const float* __restrict__ l2b,
    const float* __restrict__ c_w, const float* __restrict__ c_b,
    const float* __restrict__ clg, const float* __restrict__ clb,
    float* __restrict__ out)
{
  const int b = blockIdx.x, tid = threadIdx.x;
  __shared__ float cat[640];
  __shared__ float t1[64];
  __shared__ float t2[128];
  __shared__ float pre[256];
  __shared__ float red[256];
  __shared__ float st[2];
  for (int i = tid; i < 512; i += 256) {
    float acc = 0.f;
#pragma unroll
    for (int t = 0; t < 32; ++t) acc += g2[((size_t)b * 32 + t) * 512 + i];
    cat[i] = acc * (1.f / 32.f);
  }
  if (tid == 0) {
    float s = 0.f;
    for (int i = 0; i < 31; ++i) s += db[b * 31 + i];
    st[0] = s / 31.f;
    st[1] = dsl[b];
  }
  __syncthreads();
  const float f0 = st[0], f1v = st[1];
  if (tid < 64)
    t1[tid] = f0 * te1_w[tid * 2] + f1v * te1_w[tid * 2 + 1] + te1_b[tid];
  __syncthreads();
  if (tid == 0) {
    float m = 0.f; for (int i = 0; i < 64; ++i) m += t1[i]; m *= (1.f / 64.f);
    float v = 0.f; for (int i = 0; i < 64; ++i) { float d = t1[i] - m; v += d * d; }
    st[0] = m; st[1] = rsqrtf(v * (1.f / 64.f) + 1e-5f);
  }
  __syncthreads();
  if (tid < 64) {
    float v = (t1[tid] - st[0]) * st[1] * l1g[tid] + l1b[tid];
    t1[tid] = fmaxf(v, 0.f);
  }
  __syncthreads();
  if (tid < 128)
    t2[tid] = dot_ff(t1, te2_w + (size_t)tid * 64, 64) + te2_b[tid];
  __syncthreads();
  if (tid == 0) {
    float m = 0.f; for (int i = 0; i < 128; ++i) m += t2[i]; m *= (1.f / 128.f);
    float v = 0.f; for (int i = 0; i < 128; ++i) { float d = t2[i] - m; v += d * d; }
    st[0] = m; st[1] = rsqrtf(v * (1.f / 128.f) + 1e-5f);
  }
  __syncthreads();
  if (tid < 128) {
    float v = (t2[tid] - st[0]) * st[1] * l2g[tid] + l2b[tid];
    cat[512 + tid] = fmaxf(v, 0.f);
  }
  __syncthreads();
  pre[tid] = dot_ff(cat, c_w + (size_t)tid * 640, 640) + c_b[tid];
  red[tid] = pre[tid];
  __syncthreads();
  for (int s = 128; s > 0; s >>= 1) { if (tid < s) red[tid] += red[tid + s]; __syncthreads(); }
  const float m = red[0] * (1.f / 256.f);
  __syncthreads();
  const float d = pre[tid] - m;
  red[tid] = d * d;
  __syncthreads();
  for (int s = 128; s > 0; s >>= 1) { if (tid < s) red[tid] += red[tid + s]; __syncthreads(); }
  const float rs = rsqrtf(red[0] * (1.f / 256.f) + 1e-5f);
  float v = d * rs * clg[tid] + clb[tid];
  out[(size_t)b * 256 + tid] = fmaxf(v, 0.f);
}

// ---------------------------------------------------------------------------
extern "C" void kernel_launch(void* const* d_in, const int* in_sizes, int n_in,
                              void* d_out, int out_size, void* d_ws, size_t ws_size,
                              hipStream_t stream) {
  (void)in_sizes; (void)n_in; (void)out_size; (void)ws_size;
  const int*   oh     = (const int*)  d_in[0];
  const float* db     = (const float*)d_in[1];
  const float* dsl    = (const float*)d_in[2];
  const float* emb    = (const float*)d_in[3];
  const float* a_in_w = (const float*)d_in[4];
  const float* a_in_b = (const float*)d_in[5];
  const float* a_out_w= (const float*)d_in[6];
  const float* a_out_b= (const float*)d_in[7];
  const float* wih_f  = (const float*)d_in[8];
  const float* whh_f  = (const float*)d_in[9];
  const float* bih_f  = (const float*)d_in[10];
  const float* bhh_f  = (const float*)d_in[11];
  const float* wih_b  = (const float*)d_in[12];
  const float* whh_b  = (const float*)d_in[13];
  const float* bih_b  = (const float*)d_in[14];
  const float* bhh_b  = (const float*)d_in[15];
  const float* t_in_w = (const float*)d_in[16];
  const float* t_in_b = (const float*)d_in[17];
  const float* t_out_w= (const float*)d_in[18];
  const float* t_out_b= (const float*)d_in[19];
  const float* t_ln1g = (const float*)d_in[20];
  const float* t_ln1b = (const float*)d_in[21];
  const float* t_ff1w = (const float*)d_in[22];
  const float* t_ff1b = (const float*)d_in[23];
  const float* t_ff2w = (const float*)d_in[24];
  const float* t_ff2b = (const float*)d_in[25];
  const float* t_ln2g = (const float*)d_in[26];
  const float* t_ln2b = (const float*)d_in[27];
  const float* te1_w  = (const float*)d_in[28];
  const float* te1_b  = (const float*)d_in[29];
  const float* tl1g   = (const float*)d_in[30];
  const float* tl1b   = (const float*)d_in[31];
  const float* te2_w  = (const float*)d_in[32];
  const float* te2_b  = (const float*)d_in[33];
  const float* tl2g   = (const float*)d_in[34];
  const float* tl2b   = (const float*)d_in[35];
  const float* c_w    = (const float*)d_in[36];
  const float* c_b    = (const float*)d_in[37];
  const float* clng   = (const float*)d_in[38];
  const float* clnb   = (const float*)d_in[39];

  float* ws = (float*)d_ws;
  // Workspace (floats), ~41.8 MB:
  //   A [0,        1048576): oe  [8192,128] fp32
  //   B [1048576,  5242880): g fp32 -> f1 bf16 (over dead g) -> g2 fp32
  //   C [5242880,  9437184): attn fp32; g1 = LN out in-place
  //   D [9437184,  9732096): wTb packed-bf16 GRU weights [2][192][768] uints
  //   E [10027008,10051584): a_in_w bf16 [384*128]
  //   F [10051584,10444800): t_in_w bf16 [1536*512]
  float* oe   = ws;
  float* g    = ws + 1048576;
  float* attn = ws + 5242880;
  float* g1   = attn;                                   // in-place
  unsigned short* f1 = (unsigned short*)(ws + 1048576); // over dead g
  float* g2   = ws + 1048576;                           // in-place over f1
  unsigned* wTb = (unsigned*)(ws + 9437184);
  unsigned short* awb = (unsigned short*)(ws + 10027008);
  unsigned short* twb = (unsigned short*)(ws + 10051584);

  k_canary<<<256, 256, 0, stream>>>((float*)d_out);
  k_cvt<<<3072, 256, 0, stream>>>(a_in_w, t_in_w, awb, twb);
  k_gru_wtb<<<1152, 256, 0, stream>>>(wih_f, whh_f, wih_b, whh_b, wTb);
  k_order_attn<<<8192, 256, 0, stream>>>(oh, emb, awb, a_in_b, a_out_w, a_out_b, oe);
  k_gru_rec<<<dim3(128, 2), 768, 0, stream>>>(oe, wTb, bih_f, bhh_f, bih_b, bhh_b, g);
  k_mha2f<<<dim3(256, 4), 256, 0, stream>>>(g, twb, t_in_b, attn);
  k_proj_ln<<<1024, 256, 0, stream>>>(attn, t_out_w, t_out_b, g, t_ln1g, t_ln1b, g1);
  k_ff1<<<512, 256, 0, stream>>>(g1, t_ff1w, t_ff1b, f1);
  k_ff2_ln<<<1024, 256, 0, stream>>>(f1, t_ff2w, t_ff2b, g1, t_ln2g, t_ln2b, g2);
  k_final<<<256, 256, 0, stream>>>(g2, db, dsl, te1_w, te1_b, tl1g, tl1b,
                                   te2_w, te2_b, tl2g, tl2b, c_w, c_b, clng, clnb,
                                   (float*)d_out);
}

// Round 10
// 978.295 us; speedup vs baseline: 19.1867x; 1.6346x over previous
//
#include <hip/hip_runtime.h>
#include <hip/hip_bf16.h>
#include <math.h>

typedef __hip_bfloat16 bf16;
typedef __attribute__((ext_vector_type(8))) short short8v;   // 8 bf16 (4 VGPRs)
typedef __attribute__((ext_vector_type(4))) float float4v;   // 4 fp32 acc
#define MFMA16 __builtin_amdgcn_mfma_f32_16x16x32_bf16

__device__ __forceinline__ float us2f(unsigned short u) {
  union { unsigned u; float f; } c; c.u = ((unsigned)u) << 16; return c.f;
}
__device__ __forceinline__ unsigned short f2us(float f) {
  return __bfloat16_as_ushort(__float2bfloat16(f));
}
__device__ __forceinline__ void unpack2(unsigned u, float& a, float& b) {
  union { unsigned u; float f; } lo, hi;
  lo.u = u << 16; hi.u = u & 0xffff0000u;
  a = lo.f; b = hi.f;
}

// fp32 x . fp32 w, K % 8 == 0, 16B-aligned
__device__ __forceinline__ float dot_ff(const float* __restrict__ x,
                                        const float* __restrict__ w, int K) {
  const float4* xp = reinterpret_cast<const float4*>(x);
  const float4* wp = reinterpret_cast<const float4*>(w);
  float acc = 0.f;
  const int n = K >> 2;
  for (int i = 0; i < n; ++i) {
    float4 a = xp[i], b = wp[i];
    acc += a.x*b.x + a.y*b.y + a.z*b.z + a.w*b.w;
  }
  return acc;
}

__device__ __forceinline__ float sigm(float x) { return 1.f / (1.f + expf(-x)); }

// ---------------------------------------------------------------------------
__global__ void k_canary(float* __restrict__ out) {
  out[blockIdx.x * 256 + threadIdx.x] = 100.0f;
}

// ---------------------------------------------------------------------------
// One-shot: convert MFMA-consumed weights to bf16 in ws.
// ---------------------------------------------------------------------------
__global__ __launch_bounds__(256) void k_cvt(
    const float* __restrict__ a_in_w, const float* __restrict__ t_in_w,
    const float* __restrict__ t_out_w, const float* __restrict__ t_ff1w,
    const float* __restrict__ t_ff2w,
    unsigned short* __restrict__ awb, unsigned short* __restrict__ twb,
    unsigned short* __restrict__ pwb, unsigned short* __restrict__ f1wb,
    unsigned short* __restrict__ f2wb)
{
  int i = blockIdx.x * 256 + threadIdx.x;
  if (i < 49152)  awb[i] = f2us(a_in_w[i]);
  if (i < 786432) twb[i] = f2us(t_in_w[i]);
  if (i < 262144) pwb[i] = f2us(t_out_w[i]);
  if (i < 524288) f1wb[i] = f2us(t_ff1w[i]);
  if (i < 524288) f2wb[i] = f2us(t_ff2w[i]);
}

// ---------------------------------------------------------------------------
// Stage 1: embed + per-order MHA + token-mean + folded out-proj (MFMA QKV).
// ---------------------------------------------------------------------------
__global__ __launch_bounds__(256, 3) void k_order_attn(
    const int* __restrict__ oh, const float* __restrict__ emb,
    const unsigned short* __restrict__ awb, const float* __restrict__ in_b,
    const float* __restrict__ out_w, const float* __restrict__ out_b,
    float* __restrict__ order_emb)
{
  const int bo = blockIdx.x;            // 0..8191
  const int tid = threadIdx.x;
  __shared__ alignas(16) unsigned short xs[32 * 136];       // x bf16 (A operand)
  __shared__ alignas(16) unsigned short qkb[2 * 32 * 130];  // q,k bf16; o fp32 overlays
  __shared__ unsigned short vb[32 * 130];                   // v bf16
  __shared__ float scb[4096];                               // scores fp32
  __shared__ float om[128];
  __shared__ int ids[32];
  unsigned short* qb = qkb;
  unsigned short* kb = qkb + 32 * 130;

  if (tid < 32) ids[tid] = oh[bo * 32 + tid];
  __syncthreads();
  for (int i = tid; i < 32 * 128; i += 256) {
    int t = i >> 7, d = i & 127;
    xs[t * 136 + d] = f2us(emb[(size_t)ids[t] * 128 + d]);
  }
  __syncthreads();
  {
    const int lane = tid & 63, wave = tid >> 6;
    const int l15 = lane & 15, quad = lane >> 4;
    short8v af[2][4];
#pragma unroll
    for (int mt = 0; mt < 2; ++mt)
#pragma unroll
      for (int kc = 0; kc < 4; ++kc)
        af[mt][kc] = *reinterpret_cast<const short8v*>(
            xs + (mt * 16 + l15) * 136 + kc * 32 + quad * 8);
    for (int ni = 0; ni < 6; ++ni) {
      const int j = (wave + ni * 4) * 16 + l15;
      const unsigned short* wrow = awb + (size_t)j * 128;
      float4v acc0 = {0.f, 0.f, 0.f, 0.f}, acc1 = {0.f, 0.f, 0.f, 0.f};
#pragma unroll
      for (int kc = 0; kc < 4; ++kc) {
        short8v bfr = *reinterpret_cast<const short8v*>(wrow + kc * 32 + quad * 8);
        acc0 = MFMA16(af[0][kc], bfr, acc0, 0, 0, 0);
        acc1 = MFMA16(af[1][kc], bfr, acc1, 0, 0, 0);
      }
      const float bj = in_b[j];
      const int jj = j & 127;
      unsigned short* dst = (j < 128) ? qb : (j < 256) ? kb : vb;
#pragma unroll
      for (int r = 0; r < 4; ++r) {
        int t0 = quad * 4 + r;
        dst[t0 * 130 + jj] = f2us(acc0[r] + bj);
        dst[(t0 + 16) * 130 + jj] = f2us(acc1[r] + bj);
      }
    }
  }
  __syncthreads();
  float* sc = scb;  // sc[ki*128 + h*32 + qi]
  const float scale1 = 0.17677669529663687f; // 1/sqrt(32)
  for (int i = tid; i < 4096; i += 256) {
    int qi = i & 31, kh = i >> 5, ki = kh & 31, h = kh >> 5;
    const unsigned short* qp = qb + qi * 130 + h * 32;
    const unsigned short* kp = kb + ki * 130 + h * 32;
    float a0 = 0.f, a1 = 0.f;
#pragma unroll
    for (int c = 0; c < 32; c += 2) {
      a0 += us2f(qp[c]) * us2f(kp[c]);
      a1 += us2f(qp[c + 1]) * us2f(kp[c + 1]);
    }
    sc[ki * 128 + h * 32 + qi] = (a0 + a1) * scale1;
  }
  __syncthreads();
  if (tid < 128) {
    const int r = tid;
    float m = sc[r];
#pragma unroll
    for (int c = 1; c < 32; ++c) m = fmaxf(m, sc[c * 128 + r]);
    float s = 0.f;
#pragma unroll
    for (int c = 0; c < 32; ++c) { float e = expf(sc[c * 128 + r] - m); sc[c * 128 + r] = e; s += e; }
    float inv = 1.f / s;
#pragma unroll
    for (int c = 0; c < 32; ++c) sc[c * 128 + r] *= inv;
  }
  __syncthreads();
  float* o = reinterpret_cast<float*>(qkb);  // o[t*129+d] overlays dead q,k
  for (int i = tid; i < 4096; i += 256) {
    int t = i >> 7, d = i & 127, h = d >> 5;
    float a0 = 0.f, a1 = 0.f;
#pragma unroll
    for (int k = 0; k < 32; k += 2) {
      a0 += sc[k * 128 + h * 32 + t] * us2f(vb[k * 130 + d]);
      a1 += sc[(k + 1) * 128 + h * 32 + t] * us2f(vb[(k + 1) * 130 + d]);
    }
    o[t * 129 + d] = a0 + a1;
  }
  __syncthreads();
  if (tid < 128) {
    float acc = 0.f;
#pragma unroll
    for (int t = 0; t < 32; ++t) acc += o[t * 129 + tid];
    om[tid] = acc * (1.f / 32.f);
  }
  __syncthreads();
  if (tid < 128) {
    float acc = dot_ff(om, out_w + (size_t)tid * 128, 128) + out_b[tid];
    order_emb[(size_t)bo * 128 + tid] = acc;
  }
}

// ---------------------------------------------------------------------------
// R10 GRU weight prep (one-shot): wTb = packed bf16 k-pairs of whh only
// [dir][kp<128][768] (column-major for the recurrence); wihb = row-major
// bf16 wih for the gi MFMA GEMM, row n = dir*768 + c (c = gate*256+j).
// ---------------------------------------------------------------------------
__global__ __launch_bounds__(256) void k_gru_wtb(
    const float* __restrict__ wih_f, const float* __restrict__ whh_f,
    const float* __restrict__ wih_b, const float* __restrict__ whh_b,
    unsigned* __restrict__ wTb, unsigned short* __restrict__ wihb)
{
  int i = blockIdx.x * 256 + threadIdx.x;   // grid covers 196608
  if (i >= 196608) return;
  int dir = i / 98304, r = i % 98304;
  const float* whh = dir ? whh_b : whh_f;
  int kp = r / 768, c = r % 768;
  float w0 = whh[(size_t)c * 256 + 2 * kp];
  float w1 = whh[(size_t)c * 256 + 2 * kp + 1];
  wTb[i] = (unsigned)f2us(w0) | ((unsigned)f2us(w1) << 16);
  const float* wih = dir ? wih_b : wih_f;
  wihb[i] = f2us(wih[r]);   // r = c2*128 + k, row-major already
}

// ---------------------------------------------------------------------------
// R10 gi GEMM (MFMA): gi[8192][1536] bf16 = oe @ wih^T (both dirs).
// col = dir*768 + gate*256 + j. 32 rows/block, grid 256.
// ---------------------------------------------------------------------------
__global__ __launch_bounds__(256, 2) void k_gru_gi(
    const float* __restrict__ oe, const unsigned short* __restrict__ wihb,
    unsigned short* __restrict__ gi)
{
  const int row0 = blockIdx.x * 32, tid = threadIdx.x;
  __shared__ alignas(16) unsigned short xs[32 * 136];
  for (int i = tid; i < 32 * 128; i += 256) {
    int t = i >> 7, d = i & 127;
    xs[t * 136 + d] = f2us(oe[(size_t)(row0 + t) * 128 + d]);
  }
  __syncthreads();
  const int lane = tid & 63, wave = tid >> 6;
  const int l15 = lane & 15, quad = lane >> 4;
  short8v af[2][4];
#pragma unroll
  for (int mt = 0; mt < 2; ++mt)
#pragma unroll
    for (int kc = 0; kc < 4; ++kc)
      af[mt][kc] = *reinterpret_cast<const short8v*>(
          xs + (mt * 16 + l15) * 136 + kc * 32 + quad * 8);
  for (int ni = 0; ni < 24; ++ni) {
    int col = (wave + ni * 4) * 16 + l15;
    const unsigned short* wrow = wihb + (size_t)col * 128;
    float4v a0 = {0.f,0.f,0.f,0.f}, a1 = {0.f,0.f,0.f,0.f};
#pragma unroll
    for (int kc = 0; kc < 4; ++kc) {
      short8v bfr = *reinterpret_cast<const short8v*>(wrow + kc * 32 + quad * 8);
      a0 = MFMA16(af[0][kc], bfr, a0, 0, 0, 0);
      a1 = MFMA16(af[1][kc], bfr, a1, 0, 0, 0);
    }
#pragma unroll
    for (int r = 0; r < 4; ++r) {
      gi[(size_t)(row0 + quad * 4 + r) * 1536 + col] = f2us(a0[r]);
      gi[(size_t)(row0 + quad * 4 + r + 16) * 1536 + col] = f2us(a1[r]);
    }
  }
}

// ---------------------------------------------------------------------------
// R10 GRU recurrence: h-part only (x-part hoisted to k_gru_gi). 768 threads
// = (gate, j); 2 batches/block; grid (128,2). Inner loop 128 packed-pair
// iterations (was 192) — the VALU was 84% busy, so less work = less time.
// ---------------------------------------------------------------------------
__global__ __launch_bounds__(768) void k_gru_rec(
    const unsigned short* __restrict__ gi, const unsigned* __restrict__ wTb,
    const float* __restrict__ bih_f, const float* __restrict__ bhh_f,
    const float* __restrict__ bih_b, const float* __restrict__ bhh_b,
    float* __restrict__ g)
{
  const int b0 = blockIdx.x * 2, dir = blockIdx.y;
  const int tid = threadIdx.x;           // 0..767
  const int gsel = tid >> 8, j = tid & 255;
  const unsigned* col = wTb + (size_t)dir * 98304 + gsel * 256 + j;
  const float* bih = dir ? bih_b : bih_f;
  const float* bhh = dir ? bhh_b : bhh_f;
  __shared__ float hs[2][256];
  __shared__ float pg[2][4][256];
  const float bi = bih[gsel * 256 + j];
  const float bh = bhh[gsel * 256 + j];
  const int gcol = dir * 768 + gsel * 256 + j;
  if (tid < 512) hs[tid >> 8][tid & 255] = 0.f;
  __syncthreads();
  for (int s = 0; s < 32; ++s) {
    const int t = dir ? (31 - s) : s;
    float gx0 = us2f(gi[((size_t)(b0 + 0) * 32 + t) * 1536 + gcol]);
    float gx1 = us2f(gi[((size_t)(b0 + 1) * 32 + t) * 1536 + gcol]);
    float a0h = 0.f, a1h = 0.f;
#pragma unroll 8
    for (int kp = 0; kp < 128; ++kp) {
      unsigned u = col[kp * 768];
      float w0, w1; unpack2(u, w0, w1);
      a0h += hs[0][2 * kp] * w0 + hs[0][2 * kp + 1] * w1;
      a1h += hs[1][2 * kp] * w0 + hs[1][2 * kp + 1] * w1;
    }
    if (gsel < 2) {
      pg[0][gsel][j] = gx0 + a0h + bi + bh;
      pg[1][gsel][j] = gx1 + a1h + bi + bh;
    } else {
      pg[0][2][j] = gx0 + bi;  pg[0][3][j] = a0h + bh;
      pg[1][2][j] = gx1 + bi;  pg[1][3][j] = a1h + bh;
    }
    __syncthreads();
    if (tid < 512) {
      int b = tid >> 8;
      float r = sigm(pg[b][0][j]);
      float z = sigm(pg[b][1][j]);
      float n = tanhf(pg[b][2][j] + r * pg[b][3][j]);
      float nh = (1.f - z) * n + z * hs[b][j];
      hs[b][j] = nh;
      g[((size_t)(b0 + b) * 32 + t) * 512 + dir * 256 + j] = nh;
    }
    __syncthreads();
  }
}

// ---------------------------------------------------------------------------
// Stage 3 fused attention, one block per (b, head). MFMA QKV (R8).
// ---------------------------------------------------------------------------
#define XS_STR 520

__global__ __launch_bounds__(256, 2) void k_mha2f(
    const float* __restrict__ g, const unsigned short* __restrict__ twb,
    const float* __restrict__ Bv, float* __restrict__ attn)
{
  const int b = blockIdx.x, h = blockIdx.y, tid = threadIdx.x;
  __shared__ alignas(16) unsigned short xs[32 * XS_STR];
  __shared__ unsigned short qs[32 * 130];
  __shared__ unsigned short ks[32 * 130];
  __shared__ unsigned short vs[32 * 130];
  for (int i = tid; i < 32 * 512; i += 256) {
    int t = i >> 9, c = i & 511;
    xs[t * XS_STR + c] = f2us(g[(size_t)b * 16384 + i]);
  }
  __syncthreads();
  {
    const int lane = tid & 63, wave = tid >> 6;
    const int l15 = lane & 15, quad = lane >> 4;
    int wrowi[6];
#pragma unroll
    for (int ni = 0; ni < 6; ++ni) {
      int idx = (wave + ni * 4) * 16 + l15;
      int m = idx >> 7, dd = idx & 127;
      wrowi[ni] = m * 512 + h * 128 + dd;
    }
    float4v acc[6][2];
#pragma unroll
    for (int ni = 0; ni < 6; ++ni)
#pragma unroll
      for (int mt = 0; mt < 2; ++mt) acc[ni][mt] = (float4v){0.f, 0.f, 0.f, 0.f};
    for (int kc4 = 0; kc4 < 4; ++kc4) {
      short8v af[2][4];
#pragma unroll
      for (int mt = 0; mt < 2; ++mt)
#pragma unroll
        for (int u = 0; u < 4; ++u)
          af[mt][u] = *reinterpret_cast<const short8v*>(
              xs + (mt * 16 + l15) * XS_STR + kc4 * 128 + u * 32 + quad * 8);
#pragma unroll
      for (int ni = 0; ni < 6; ++ni) {
        const unsigned short* wrow = twb + (size_t)wrowi[ni] * 512 + kc4 * 128;
#pragma unroll
        for (int u = 0; u < 4; ++u) {
          short8v bfr = *reinterpret_cast<const short8v*>(wrow + u * 32 + quad * 8);
          acc[ni][0] = MFMA16(af[0][u], bfr, acc[ni][0], 0, 0, 0);
          acc[ni][1] = MFMA16(af[1][u], bfr, acc[ni][1], 0, 0, 0);
        }
      }
    }
#pragma unroll
    for (int ni = 0; ni < 6; ++ni) {
      int idx = (wave + ni * 4) * 16 + l15;
      int m = idx >> 7, dd = idx & 127;
      float bj = Bv[wrowi[ni]];
      unsigned short* dst = (m == 0) ? qs : (m == 1) ? ks : vs;
#pragma unroll
      for (int r = 0; r < 4; ++r) {
        int t0 = quad * 4 + r;
        dst[t0 * 130 + dd] = f2us(acc[ni][0][r] + bj);
        dst[(t0 + 16) * 130 + dd] = f2us(acc[ni][1][r] + bj);
      }
    }
  }
  __syncthreads();
  float* sc = reinterpret_cast<float*>(xs);  // sc[qi*33 + ki] overlays dead xs
  const float scale2 = 0.08838834764831845f; // 1/sqrt(128)
  for (int i = tid; i < 1024; i += 256) {
    int qi = i >> 5, ki = i & 31;
    const unsigned short* qp = &qs[qi * 130];
    const unsigned short* kp = &ks[ki * 130];
    float a0 = 0.f, a1 = 0.f;
#pragma unroll
    for (int c = 0; c < 128; c += 2) {
      a0 += us2f(qp[c]) * us2f(kp[c]);
      a1 += us2f(qp[c + 1]) * us2f(kp[c + 1]);
    }
    sc[qi * 33 + ki] = (a0 + a1) * scale2;
  }
  __syncthreads();
  if (tid < 32) {
    float* row = &sc[tid * 33];
    float m = row[0];
#pragma unroll
    for (int c = 1; c < 32; ++c) m = fmaxf(m, row[c]);
    float s = 0.f;
#pragma unroll
    for (int c = 0; c < 32; ++c) { float e = expf(row[c] - m); row[c] = e; s += e; }
    float inv = 1.f / s;
#pragma unroll
    for (int c = 0; c < 32; ++c) row[c] *= inv;
  }
  __syncthreads();
  for (int i = tid; i < 4096; i += 256) {
    int t = i >> 7, d = i & 127;
    const float* prow = &sc[t * 33];
    float a0 = 0.f, a1 = 0.f;
#pragma unroll
    for (int k = 0; k < 32; k += 2) {
      a0 += prow[k] * us2f(vs[k * 130 + d]);
      a1 += prow[k + 1] * us2f(vs[(k + 1) * 130 + d]);
    }
    attn[((size_t)b * 32 + t) * 512 + h * 128 + d] = a0 + a1;
  }
}

// ---------------------------------------------------------------------------
// R10 proj GEMM via MFMA (M=16/block, N=512, K=512) + bias + residual + LN.
// Y may alias X (rows staged to acc before writes). LDS 49,664 B.
// ---------------------------------------------------------------------------
__global__ __launch_bounds__(256, 2) void k_projln_mfma(
    const float* __restrict__ X, const unsigned short* __restrict__ Wb,
    const float* __restrict__ bias, const float* __restrict__ res,
    const float* __restrict__ gam, const float* __restrict__ bet,
    float* __restrict__ Y)
{
  const int row0 = blockIdx.x * 16, tid = threadIdx.x;
  __shared__ alignas(16) unsigned short xs[16 * 520];
  __shared__ float ys[16 * 516];
  for (int i = tid; i < 16 * 512; i += 256) {
    int t = i >> 9, c = i & 511;
    xs[t * 520 + c] = f2us(X[(size_t)(row0 + t) * 512 + c]);
  }
  __syncthreads();
  {
    const int lane = tid & 63, wave = tid >> 6;
    const int l15 = lane & 15, quad = lane >> 4;
    short8v af[16];
#pragma unroll
    for (int kc = 0; kc < 16; ++kc)
      af[kc] = *reinterpret_cast<const short8v*>(xs + l15 * 520 + kc * 32 + quad * 8);
    for (int ni = 0; ni < 8; ++ni) {
      int col = (wave + ni * 4) * 16 + l15;
      const unsigned short* wrow = Wb + (size_t)col * 512;
      float4v acc = {0.f,0.f,0.f,0.f};
#pragma unroll
      for (int kc = 0; kc < 16; ++kc) {
        short8v bfr = *reinterpret_cast<const short8v*>(wrow + kc * 32 + quad * 8);
        acc = MFMA16(af[kc], bfr, acc, 0, 0, 0);
      }
      float bj = bias[col];
#pragma unroll
      for (int r = 0; r < 4; ++r)
        ys[(quad * 4 + r) * 516 + col] = acc[r] + bj;
    }
  }
  __syncthreads();
  for (int i = tid; i < 16 * 512; i += 256) {
    int t = i >> 9, c = i & 511;
    ys[t * 516 + c] += res[(size_t)(row0 + t) * 512 + c];
  }
  __syncthreads();
  {
    int row = tid >> 4, l16 = tid & 15;
    const float* yr = ys + row * 516;
    float part = 0.f;
#pragma unroll
    for (int k = 0; k < 32; ++k) part += yr[l16 + 16 * k];
#pragma unroll
    for (int off = 8; off; off >>= 1) part += __shfl_xor(part, off, 16);
    float mean = part * (1.f / 512.f);
    float var = 0.f;
#pragma unroll
    for (int k = 0; k < 32; ++k) { float d = yr[l16 + 16 * k] - mean; var += d * d; }
#pragma unroll
    for (int off = 8; off; off >>= 1) var += __shfl_xor(var, off, 16);
    float rs = rsqrtf(var * (1.f / 512.f) + 1e-5f);
    for (int k = 0; k < 32; ++k) {
      int c = l16 + 16 * k;
      Y[(size_t)(row0 + row) * 512 + c] = (yr[c] - mean) * rs * gam[c] + bet[c];
    }
  }
}

// ---------------------------------------------------------------------------
// R10 ff1 GEMM via MFMA (M=16/block, N=1024, K=512) + bias + relu -> bf16.
// ---------------------------------------------------------------------------
__global__ __launch_bounds__(256, 2) void k_ff1_mfma(
    const float* __restrict__ X, const unsigned short* __restrict__ Wb,
    const float* __restrict__ bias, unsigned short* __restrict__ Y)
{
  const int row0 = blockIdx.x * 16, tid = threadIdx.x;
  __shared__ alignas(16) unsigned short xs[16 * 520];
  for (int i = tid; i < 16 * 512; i += 256) {
    int t = i >> 9, c = i & 511;
    xs[t * 520 + c] = f2us(X[(size_t)(row0 + t) * 512 + c]);
  }
  __syncthreads();
  const int lane = tid & 63, wave = tid >> 6;
  const int l15 = lane & 15, quad = lane >> 4;
  short8v af[16];
#pragma unroll
  for (int kc = 0; kc < 16; ++kc)
    af[kc] = *reinterpret_cast<const short8v*>(xs + l15 * 520 + kc * 32 + quad * 8);
  for (int ni = 0; ni < 16; ++ni) {
    int col = (wave + ni * 4) * 16 + l15;
    const unsigned short* wrow = Wb + (size_t)col * 512;
    float4v acc = {0.f,0.f,0.f,0.f};
#pragma unroll
    for (int kc = 0; kc < 16; ++kc) {
      short8v bfr = *reinterpret_cast<const short8v*>(wrow + kc * 32 + quad * 8);
      acc = MFMA16(af[kc], bfr, acc, 0, 0, 0);
    }
    float bj = bias[col];
#pragma unroll
    for (int r = 0; r < 4; ++r)
      Y[(size_t)(row0 + quad * 4 + r) * 1024 + col] = f2us(fmaxf(acc[r] + bj, 0.f));
  }
}

// ---------------------------------------------------------------------------
// R10 ff2 GEMM via MFMA (M=16/block, N=512, K=1024 in 2 chunks) + bias +
// residual + LN. Y fp32 overlays X bf16 in-place (rows consumed first).
// ---------------------------------------------------------------------------
__global__ __launch_bounds__(256, 2) void k_ff2ln_mfma(
    const unsigned short* __restrict__ X, const unsigned short* __restrict__ Wb,
    const float* __restrict__ bias, const float* __restrict__ res,
    const float* __restrict__ gam, const float* __restrict__ bet,
    float* __restrict__ Y)
{
  const int row0 = blockIdx.x * 16, tid = threadIdx.x;
  __shared__ alignas(16) unsigned short xs[16 * 520];
  __shared__ float ys[16 * 516];
  const int lane = tid & 63, wave = tid >> 6;
  const int l15 = lane & 15, quad = lane >> 4;
  float4v acc[8];
#pragma unroll
  for (int ni = 0; ni < 8; ++ni) acc[ni] = (float4v){0.f,0.f,0.f,0.f};
  for (int half = 0; half < 2; ++half) {
    __syncthreads();
    for (int i = tid; i < 16 * 512; i += 256) {
      int t = i >> 9, c = i & 511;
      xs[t * 520 + c] = X[(size_t)(row0 + t) * 1024 + half * 512 + c];
    }
    __syncthreads();
    short8v af[16];
#pragma unroll
    for (int kc = 0; kc < 16; ++kc)
      af[kc] = *reinterpret_cast<const short8v*>(xs + l15 * 520 + kc * 32 + quad * 8);
#pragma unroll
    for (int ni = 0; ni < 8; ++ni) {
      int col = (wave + ni * 4) * 16 + l15;
      const unsigned short* wrow = Wb + (size_t)col * 1024 + half * 512;
#pragma unroll
      for (int kc = 0; kc < 16; ++kc) {
        short8v bfr = *reinterpret_cast<const short8v*>(wrow + kc * 32 + quad * 8);
        acc[ni] = MFMA16(af[kc], bfr, acc[ni], 0, 0, 0);
      }
    }
  }
  __syncthreads();
  for (int ni = 0; ni < 8; ++ni) {
    int col = (wave + ni * 4) * 16 + l15;
    float bj = bias[col];
#pragma unroll
    for (int r = 0; r < 4; ++r)
      ys[(quad * 4 + r) * 516 + col] = acc[ni][r] + bj;
  }
  __syncthreads();
  for (int i = tid; i < 16 * 512; i += 256) {
    int t = i >> 9, c = i & 511;
    ys[t * 516 + c] += res[(size_t)(row0 + t) * 512 + c];
  }
  __syncthreads();
  {
    int row = tid >> 4, l16 = tid & 15;
    const float* yr = ys + row * 516;
    float part = 0.f;
#pragma unroll
    for (int k = 0; k < 32; ++k) part += yr[l16 + 16 * k];
#pragma unroll
    for (int off = 8; off; off >>= 1) part += __shfl_xor(part, off, 16);
    float mean = part * (1.f / 512.f);
    float var = 0.f;
#pragma unroll
    for (int k = 0; k < 32; ++k) { float d = yr[l16 + 16 * k] - mean; var += d * d; }
#pragma unroll
    for (int off = 8; off; off >>= 1) var += __shfl_xor(var, off, 16);
    float rs = rsqrtf(var * (1.f / 512.f) + 1e-5f);
    for (int k = 0; k < 32; ++k) {
      int c = l16 + 16 * k;
      Y[(size_t)(row0 + row) * 512 + c] = (yr[c] - mean) * rs * gam[c] + bet[c];
    }
  }
}

// ---------------------------------------------------------------------------
// Final: mean-pool, temporal MLP, concat, classifier, LN, relu -> fp32
// ---------------------------------------------------------------------------
__global__ __launch_bounds__(256) void k_final(
    const float* __restrict__ g2,
    const float* __restrict__ db, const float* __restrict__ dsl,
    const float* __restrict__ te1_w, const float* __restrict__ te1_b,
    const float* __restrict__ l1g, const float* __restrict__ l1b,
    const float* __restrict__ te2_w, const float* __restrict__ te2_b,
    const float* __restrict__ l2g, const float* __restrict__ l2b,
    const float* __restrict__ c_w, const float* __restrict__ c_b,
    const float* __restrict__ clg, const float* __restrict__ clb,
    float* __restrict__ out)
{
  const int b = blockIdx.x, tid = threadIdx.x;
  __shared__ float cat[640];
  __shared__ float t1[64];
  __shared__ float t2[128];
  __shared__ float pre[256];
  __shared__ float red[256];
  __shared__ float st[2];
  for (int i = tid; i < 512; i += 256) {
    float acc = 0.f;
#pragma unroll
    for (int t = 0; t < 32; ++t) acc += g2[((size_t)b * 32 + t) * 512 + i];
    cat[i] = acc * (1.f / 32.f);
  }
  if (tid == 0) {
    float s = 0.f;
    for (int i = 0; i < 31; ++i) s += db[b * 31 + i];
    st[0] = s / 31.f;
    st[1] = dsl[b];
  }
  __syncthreads();
  const float f0 = st[0], f1v = st[1];
  if (tid < 64)
    t1[tid] = f0 * te1_w[tid * 2] + f1v * te1_w[tid * 2 + 1] + te1_b[tid];
  __syncthreads();
  if (tid == 0) {
    float m = 0.f; for (int i = 0; i < 64; ++i) m += t1[i]; m *= (1.f / 64.f);
    float v = 0.f; for (int i = 0; i < 64; ++i) { float d = t1[i] - m; v += d * d; }
    st[0] = m; st[1] = rsqrtf(v * (1.f / 64.f) + 1e-5f);
  }
  __syncthreads();
  if (tid < 64) {
    float v = (t1[tid] - st[0]) * st[1] * l1g[tid] + l1b[tid];
    t1[tid] = fmaxf(v, 0.f);
  }
  __syncthreads();
  if (tid < 128)
    t2[tid] = dot_ff(t1, te2_w + (size_t)tid * 64, 64) + te2_b[tid];
  __syncthreads();
  if (tid == 0) {
    float m = 0.f; for (int i = 0; i < 128; ++i) m += t2[i]; m *= (1.f / 128.f);
    float v = 0.f; for (int i = 0; i < 128; ++i) { float d = t2[i] - m; v += d * d; }
    st[0] = m; st[1] = rsqrtf(v * (1.f / 128.f) + 1e-5f);
  }
  __syncthreads();
  if (tid < 128) {
    float v = (t2[tid] - st[0]) * st[1] * l2g[tid] + l2b[tid];
    cat[512 + tid] = fmaxf(v, 0.f);
  }
  __syncthreads();
  pre[tid] = dot_ff(cat, c_w + (size_t)tid * 640, 640) + c_b[tid];
  red[tid] = pre[tid];
  __syncthreads();
  for (int s = 128; s > 0; s >>= 1) { if (tid < s) red[tid] += red[tid + s]; __syncthreads(); }
  const float m = red[0] * (1.f / 256.f);
  __syncthreads();
  const float d = pre[tid] - m;
  red[tid] = d * d;
  __syncthreads();
  for (int s = 128; s > 0; s >>= 1) { if (tid < s) red[tid] += red[tid + s]; __syncthreads(); }
  const float rs = rsqrtf(red[0] * (1.f / 256.f) + 1e-5f);
  float v = d * rs * clg[tid] + clb[tid];
  out[(size_t)b * 256 + tid] = fmaxf(v, 0.f);
}

// ---------------------------------------------------------------------------
extern "C" void kernel_launch(void* const* d_in, const int* in_sizes, int n_in,
                              void* d_out, int out_size, void* d_ws, size_t ws_size,
                              hipStream_t stream) {
  (void)in_sizes; (void)n_in; (void)out_size; (void)ws_size;
  const int*   oh     = (const int*)  d_in[0];
  const float* db     = (const float*)d_in[1];
  const float* dsl    = (const float*)d_in[2];
  const float* emb    = (const float*)d_in[3];
  const float* a_in_w = (const float*)d_in[4];
  const float* a_in_b = (const float*)d_in[5];
  const float* a_out_w= (const float*)d_in[6];
  const float* a_out_b= (const float*)d_in[7];
  const float* wih_f  = (const float*)d_in[8];
  const float* whh_f  = (const float*)d_in[9];
  const float* bih_f  = (const float*)d_in[10];
  const float* bhh_f  = (const float*)d_in[11];
  const float* wih_b  = (const float*)d_in[12];
  const float* whh_b  = (const float*)d_in[13];
  const float* bih_b  = (const float*)d_in[14];
  const float* bhh_b  = (const float*)d_in[15];
  const float* t_in_w = (const float*)d_in[16];
  const float* t_in_b = (const float*)d_in[17];
  const float* t_out_w= (const float*)d_in[18];
  const float* t_out_b= (const float*)d_in[19];
  const float* t_ln1g = (const float*)d_in[20];
  const float* t_ln1b = (const float*)d_in[21];
  const float* t_ff1w = (const float*)d_in[22];
  const float* t_ff1b = (const float*)d_in[23];
  const float* t_ff2w = (const float*)d_in[24];
  const float* t_ff2b = (const float*)d_in[25];
  const float* t_ln2g = (const float*)d_in[26];
  const float* t_ln2b = (const float*)d_in[27];
  const float* te1_w  = (const float*)d_in[28];
  const float* te1_b  = (const float*)d_in[29];
  const float* tl1g   = (const float*)d_in[30];
  const float* tl1b   = (const float*)d_in[31];
  const float* te2_w  = (const float*)d_in[32];
  const float* te2_b  = (const float*)d_in[33];
  const float* tl2g   = (const float*)d_in[34];
  const float* tl2b   = (const float*)d_in[35];
  const float* c_w    = (const float*)d_in[36];
  const float* c_b    = (const float*)d_in[37];
  const float* clng   = (const float*)d_in[38];
  const float* clnb   = (const float*)d_in[39];

  float* ws = (float*)d_ws;
  // Workspace (float slots), max index 17,391,616 (~69.6 MB; ws >= 88 MB
  // proven in R4):
  //   A [0,        1048576): oe [8192,128] fp32
  //   B [1048576,  5242880): g fp32 -> f1 bf16 (over dead g) -> g2 fp32
  //   C [5242880,  9437184): attn fp32; g1 = LN out in-place
  //   D [9437184,  9633792): wTb packed-bf16 whh [2][128][768] uints
  //   D2[9633792,  9732096): wihb bf16 [2*768][128]
  //   E [10027008,10051584): awb bf16 [384*128]
  //   F [10051584,10444800): twb bf16 [1536*512]
  //   G [10444800,10575872): pwb bf16 [512*512]
  //   G2[10575872,10838016): f1wb bf16 [1024*512]
  //   G3[10838016,11100160): f2wb bf16 [512*1024]
  //   H [11100160,17391616): gi bf16 [8192*1536]
  float* oe   = ws;
  float* g    = ws + 1048576;
  float* attn = ws + 5242880;
  float* g1   = attn;                                   // in-place
  unsigned short* f1 = (unsigned short*)(ws + 1048576); // over dead g
  float* g2   = ws + 1048576;                           // in-place over f1
  unsigned* wTb = (unsigned*)(ws + 9437184);
  unsigned short* wihb = (unsigned short*)(ws + 9633792);
  unsigned short* awb  = (unsigned short*)(ws + 10027008);
  unsigned short* twb  = (unsigned short*)(ws + 10051584);
  unsigned short* pwb  = (unsigned short*)(ws + 10444800);
  unsigned short* f1wb = (unsigned short*)(ws + 10575872);
  unsigned short* f2wb = (unsigned short*)(ws + 10838016);
  unsigned short* gi   = (unsigned short*)(ws + 11100160);

  k_canary<<<256, 256, 0, stream>>>((float*)d_out);
  k_cvt<<<3072, 256, 0, stream>>>(a_in_w, t_in_w, t_out_w, t_ff1w, t_ff2w,
                                  awb, twb, pwb, f1wb, f2wb);
  k_gru_wtb<<<768, 256, 0, stream>>>(wih_f, whh_f, wih_b, whh_b, wTb, wihb);
  k_order_attn<<<8192, 256, 0, stream>>>(oh, emb, awb, a_in_b, a_out_w, a_out_b, oe);
  k_gru_gi<<<256, 256, 0, stream>>>(oe, wihb, gi);
  k_gru_rec<<<dim3(128, 2), 768, 0, stream>>>(gi, wTb, bih_f, bhh_f, bih_b, bhh_b, g);
  k_mha2f<<<dim3(256, 4), 256, 0, stream>>>(g, twb, t_in_b, attn);
  k_projln_mfma<<<512, 256, 0, stream>>>(attn, pwb, t_out_b, g, t_ln1g, t_ln1b, g1);
  k_ff1_mfma<<<512, 256, 0, stream>>>(g1, f1wb, t_ff1b, f1);
  k_ff2ln_mfma<<<512, 256, 0, stream>>>(f1, f2wb, t_ff2b, g1, t_ln2g, t_ln2b, g2);
  k_final<<<256, 256, 0, stream>>>(g2, db, dsl, te1_w, te1_b, tl1g, tl1b,
                                   te2_w, te2_b, tl2g, tl2b, c_w, c_b, clng, clnb,
                                   (float*)d_out);
}

// Round 11
// 893.239 us; speedup vs baseline: 21.0137x; 1.0952x over previous
//
#include <hip/hip_runtime.h>
#include <hip/hip_bf16.h>
#include <math.h>

typedef __hip_bfloat16 bf16;
typedef __attribute__((ext_vector_type(8))) short short8v;   // 8 bf16 (4 VGPRs)
typedef __attribute__((ext_vector_type(4))) float float4v;   // 4 fp32 acc
#define MFMA16 __builtin_amdgcn_mfma_f32_16x16x32_bf16

__device__ __forceinline__ float us2f(unsigned short u) {
  union { unsigned u; float f; } c; c.u = ((unsigned)u) << 16; return c.f;
}
__device__ __forceinline__ unsigned short f2us(float f) {
  return __bfloat16_as_ushort(__float2bfloat16(f));
}

// fp32 x . fp32 w, K % 8 == 0, 16B-aligned
__device__ __forceinline__ float dot_ff(const float* __restrict__ x,
                                        const float* __restrict__ w, int K) {
  const float4* xp = reinterpret_cast<const float4*>(x);
  const float4* wp = reinterpret_cast<const float4*>(w);
  float acc = 0.f;
  const int n = K >> 2;
  for (int i = 0; i < n; ++i) {
    float4 a = xp[i], b = wp[i];
    acc += a.x*b.x + a.y*b.y + a.z*b.z + a.w*b.w;
  }
  return acc;
}

__device__ __forceinline__ float sigm(float x) { return 1.f / (1.f + expf(-x)); }

// ---------------------------------------------------------------------------
__global__ void k_canary(float* __restrict__ out) {
  out[blockIdx.x * 256 + threadIdx.x] = 100.0f;
}

// ---------------------------------------------------------------------------
// One-shot: convert MFMA-consumed weights to bf16 in ws.
// ---------------------------------------------------------------------------
__global__ __launch_bounds__(256) void k_cvt(
    const float* __restrict__ a_in_w, const float* __restrict__ t_in_w,
    const float* __restrict__ t_out_w, const float* __restrict__ t_ff1w,
    const float* __restrict__ t_ff2w,
    unsigned short* __restrict__ awb, unsigned short* __restrict__ twb,
    unsigned short* __restrict__ pwb, unsigned short* __restrict__ f1wb,
    unsigned short* __restrict__ f2wb)
{
  int i = blockIdx.x * 256 + threadIdx.x;
  if (i < 49152)  awb[i] = f2us(a_in_w[i]);
  if (i < 786432) twb[i] = f2us(t_in_w[i]);
  if (i < 262144) pwb[i] = f2us(t_out_w[i]);
  if (i < 524288) f1wb[i] = f2us(t_ff1w[i]);
  if (i < 524288) f2wb[i] = f2us(t_ff2w[i]);
}

// ---------------------------------------------------------------------------
// R11 GRU weight prep: row-major bf16 copies. whhb [dir][768][256],
// wihb [dir][768][128] (for gi GEMM).
// ---------------------------------------------------------------------------
__global__ __launch_bounds__(256) void k_gru_wb(
    const float* __restrict__ wih_f, const float* __restrict__ whh_f,
    const float* __restrict__ wih_b, const float* __restrict__ whh_b,
    unsigned short* __restrict__ whhb, unsigned short* __restrict__ wihb)
{
  int i = blockIdx.x * 256 + threadIdx.x;   // < 393216
  if (i >= 393216) return;
  int dir = i / 196608, r = i % 196608;
  whhb[i] = f2us((dir ? whh_b : whh_f)[r]);
  if (r < 98304) wihb[dir * 98304 + r] = f2us((dir ? wih_b : wih_f)[r]);
}

// ---------------------------------------------------------------------------
// Stage 1: embed + per-order MHA + token-mean + folded out-proj (MFMA QKV).
// ---------------------------------------------------------------------------
__global__ __launch_bounds__(256, 3) void k_order_attn(
    const int* __restrict__ oh, const float* __restrict__ emb,
    const unsigned short* __restrict__ awb, const float* __restrict__ in_b,
    const float* __restrict__ out_w, const float* __restrict__ out_b,
    float* __restrict__ order_emb)
{
  const int bo = blockIdx.x;            // 0..8191
  const int tid = threadIdx.x;
  __shared__ alignas(16) unsigned short xs[32 * 136];       // x bf16 (A operand)
  __shared__ alignas(16) unsigned short qkb[2 * 32 * 130];  // q,k bf16; o fp32 overlays
  __shared__ unsigned short vb[32 * 130];                   // v bf16
  __shared__ float scb[4096];                               // scores fp32
  __shared__ float om[128];
  __shared__ int ids[32];
  unsigned short* qb = qkb;
  unsigned short* kb = qkb + 32 * 130;

  if (tid < 32) ids[tid] = oh[bo * 32 + tid];
  __syncthreads();
  for (int i = tid; i < 32 * 128; i += 256) {
    int t = i >> 7, d = i & 127;
    xs[t * 136 + d] = f2us(emb[(size_t)ids[t] * 128 + d]);
  }
  __syncthreads();
  {
    const int lane = tid & 63, wave = tid >> 6;
    const int l15 = lane & 15, quad = lane >> 4;
    short8v af[2][4];
#pragma unroll
    for (int mt = 0; mt < 2; ++mt)
#pragma unroll
      for (int kc = 0; kc < 4; ++kc)
        af[mt][kc] = *reinterpret_cast<const short8v*>(
            xs + (mt * 16 + l15) * 136 + kc * 32 + quad * 8);
    for (int ni = 0; ni < 6; ++ni) {
      const int j = (wave + ni * 4) * 16 + l15;
      const unsigned short* wrow = awb + (size_t)j * 128;
      float4v acc0 = {0.f, 0.f, 0.f, 0.f}, acc1 = {0.f, 0.f, 0.f, 0.f};
#pragma unroll
      for (int kc = 0; kc < 4; ++kc) {
        short8v bfr = *reinterpret_cast<const short8v*>(wrow + kc * 32 + quad * 8);
        acc0 = MFMA16(af[0][kc], bfr, acc0, 0, 0, 0);
        acc1 = MFMA16(af[1][kc], bfr, acc1, 0, 0, 0);
      }
      const float bj = in_b[j];
      const int jj = j & 127;
      unsigned short* dst = (j < 128) ? qb : (j < 256) ? kb : vb;
#pragma unroll
      for (int r = 0; r < 4; ++r) {
        int t0 = quad * 4 + r;
        dst[t0 * 130 + jj] = f2us(acc0[r] + bj);
        dst[(t0 + 16) * 130 + jj] = f2us(acc1[r] + bj);
      }
    }
  }
  __syncthreads();
  float* sc = scb;  // sc[ki*128 + h*32 + qi]
  const float scale1 = 0.17677669529663687f; // 1/sqrt(32)
  for (int i = tid; i < 4096; i += 256) {
    int qi = i & 31, kh = i >> 5, ki = kh & 31, h = kh >> 5;
    const unsigned short* qp = qb + qi * 130 + h * 32;
    const unsigned short* kp = kb + ki * 130 + h * 32;
    float a0 = 0.f, a1 = 0.f;
#pragma unroll
    for (int c = 0; c < 32; c += 2) {
      a0 += us2f(qp[c]) * us2f(kp[c]);
      a1 += us2f(qp[c + 1]) * us2f(kp[c + 1]);
    }
    sc[ki * 128 + h * 32 + qi] = (a0 + a1) * scale1;
  }
  __syncthreads();
  if (tid < 128) {
    const int r = tid;
    float m = sc[r];
#pragma unroll
    for (int c = 1; c < 32; ++c) m = fmaxf(m, sc[c * 128 + r]);
    float s = 0.f;
#pragma unroll
    for (int c = 0; c < 32; ++c) { float e = expf(sc[c * 128 + r] - m); sc[c * 128 + r] = e; s += e; }
    float inv = 1.f / s;
#pragma unroll
    for (int c = 0; c < 32; ++c) sc[c * 128 + r] *= inv;
  }
  __syncthreads();
  float* o = reinterpret_cast<float*>(qkb);  // o[t*129+d] overlays dead q,k
  for (int i = tid; i < 4096; i += 256) {
    int t = i >> 7, d = i & 127, h = d >> 5;
    float a0 = 0.f, a1 = 0.f;
#pragma unroll
    for (int k = 0; k < 32; k += 2) {
      a0 += sc[k * 128 + h * 32 + t] * us2f(vb[k * 130 + d]);
      a1 += sc[(k + 1) * 128 + h * 32 + t] * us2f(vb[(k + 1) * 130 + d]);
    }
    o[t * 129 + d] = a0 + a1;
  }
  __syncthreads();
  if (tid < 128) {
    float acc = 0.f;
#pragma unroll
    for (int t = 0; t < 32; ++t) acc += o[t * 129 + tid];
    om[tid] = acc * (1.f / 32.f);
  }
  __syncthreads();
  if (tid < 128) {
    float acc = dot_ff(om, out_w + (size_t)tid * 128, 128) + out_b[tid];
    order_emb[(size_t)bo * 128 + tid] = acc;
  }
}

// ---------------------------------------------------------------------------
// gi GEMM (MFMA): gi[8192][1536] bf16 = oe @ wih^T (both dirs).
// ---------------------------------------------------------------------------
__global__ __launch_bounds__(256, 2) void k_gru_gi(
    const float* __restrict__ oe, const unsigned short* __restrict__ wihb,
    unsigned short* __restrict__ gi)
{
  const int row0 = blockIdx.x * 32, tid = threadIdx.x;
  __shared__ alignas(16) unsigned short xs[32 * 136];
  for (int i = tid; i < 32 * 128; i += 256) {
    int t = i >> 7, d = i & 127;
    xs[t * 136 + d] = f2us(oe[(size_t)(row0 + t) * 128 + d]);
  }
  __syncthreads();
  const int lane = tid & 63, wave = tid >> 6;
  const int l15 = lane & 15, quad = lane >> 4;
  short8v af[2][4];
#pragma unroll
  for (int mt = 0; mt < 2; ++mt)
#pragma unroll
    for (int kc = 0; kc < 4; ++kc)
      af[mt][kc] = *reinterpret_cast<const short8v*>(
          xs + (mt * 16 + l15) * 136 + kc * 32 + quad * 8);
  for (int ni = 0; ni < 24; ++ni) {
    int col = (wave + ni * 4) * 16 + l15;
    const unsigned short* wrow = wihb + (size_t)col * 128;
    float4v a0 = {0.f,0.f,0.f,0.f}, a1 = {0.f,0.f,0.f,0.f};
#pragma unroll
    for (int kc = 0; kc < 4; ++kc) {
      short8v bfr = *reinterpret_cast<const short8v*>(wrow + kc * 32 + quad * 8);
      a0 = MFMA16(af[0][kc], bfr, a0, 0, 0, 0);
      a1 = MFMA16(af[1][kc], bfr, a1, 0, 0, 0);
    }
#pragma unroll
    for (int r = 0; r < 4; ++r) {
      gi[(size_t)(row0 + quad * 4 + r) * 1536 + col] = f2us(a0[r]);
      gi[(size_t)(row0 + quad * 4 + r + 16) * 1536 + col] = f2us(a1[r]);
    }
  }
}

// ---------------------------------------------------------------------------
// R11 GRU recurrence via MFMA. 16 batches/block (one m-tile), grid (16,2),
// 512 threads (8 waves). whh register-resident: 6 n-tiles/wave x 8 k-chunks
// = 192 VGPRs of B-frags, loaded ONCE. h kept as bf16 in LDS (A operand,
// rewritten by the pointwise phase); matmul out pg fp32 in LDS.
// Per step: 48 MFMA/wave + pointwise; 2 barriers. LDS = 8448 + 49408 =
// 57,856 B (under the 64 KB static limit that killed round 1).
// ---------------------------------------------------------------------------
__global__ __launch_bounds__(512, 2) void k_gru_rec(
    const unsigned short* __restrict__ gi, const unsigned short* __restrict__ whhb,
    const float* __restrict__ bih_f, const float* __restrict__ bhh_f,
    const float* __restrict__ bih_b, const float* __restrict__ bhh_b,
    float* __restrict__ g)
{
  const int b0 = blockIdx.x * 16, dir = blockIdx.y;
  const int tid = threadIdx.x;           // 0..511
  const unsigned short* wb = whhb + (size_t)dir * 196608;   // [768][256] bf16
  const float* bih = dir ? bih_b : bih_f;
  const float* bhh = dir ? bhh_b : bhh_f;
  __shared__ alignas(16) unsigned short hb[16 * 264];   // h bf16 (A operand)
  __shared__ float pg[16 * 772];                        // gh fp32
  const int lane = tid & 63, wave = tid >> 6;
  const int l15 = lane & 15, quad = lane >> 4;
  const int j = tid & 255, mb = tid >> 8;               // pointwise: j fixed/thread
  const float bir = bih[j], biz = bih[256 + j], bin_ = bih[512 + j];
  const float bhr = bhh[j], bhz = bhh[256 + j], bhn  = bhh[512 + j];
  // preload whh B-frags (once)
  short8v wf[6][8];
  int cols[6];
#pragma unroll
  for (int ni = 0; ni < 6; ++ni) {
    cols[ni] = (wave + ni * 8) * 16 + l15;
#pragma unroll
    for (int kc = 0; kc < 8; ++kc)
      wf[ni][kc] = *reinterpret_cast<const short8v*>(
          wb + (size_t)cols[ni] * 256 + kc * 32 + quad * 8);
  }
  for (int i = tid; i < 16 * 264; i += 512) hb[i] = 0;
  __syncthreads();
  for (int s = 0; s < 32; ++s) {
    const int t = dir ? (31 - s) : s;
    float4v acc[6];
#pragma unroll
    for (int ni = 0; ni < 6; ++ni) acc[ni] = (float4v){0.f, 0.f, 0.f, 0.f};
#pragma unroll
    for (int kc = 0; kc < 8; ++kc) {
      short8v af = *reinterpret_cast<const short8v*>(hb + l15 * 264 + kc * 32 + quad * 8);
#pragma unroll
      for (int ni = 0; ni < 6; ++ni)
        acc[ni] = MFMA16(af, wf[ni][kc], acc[ni], 0, 0, 0);
    }
#pragma unroll
    for (int ni = 0; ni < 6; ++ni)
#pragma unroll
      for (int r = 0; r < 4; ++r)
        pg[(quad * 4 + r) * 772 + cols[ni]] = acc[ni][r];
    __syncthreads();
#pragma unroll
    for (int it = 0; it < 8; ++it) {
      const int m = mb + 2 * it;
      const size_t gbase = ((size_t)(b0 + m) * 32 + t) * 1536 + dir * 768;
      float gr = us2f(gi[gbase + j]);
      float gz = us2f(gi[gbase + 256 + j]);
      float gn = us2f(gi[gbase + 512 + j]);
      float hprev = us2f(hb[m * 264 + j]);
      float r = sigm(gr + bir + pg[m * 772 + j] + bhr);
      float z = sigm(gz + biz + pg[m * 772 + 256 + j] + bhz);
      float n = tanhf(gn + bin_ + r * (pg[m * 772 + 512 + j] + bhn));
      float nh = (1.f - z) * n + z * hprev;
      hb[m * 264 + j] = f2us(nh);
      g[((size_t)(b0 + m) * 32 + t) * 512 + dir * 256 + j] = nh;
    }
    __syncthreads();
  }
}

// ---------------------------------------------------------------------------
// Stage 3 fused attention, one block per (b, head). MFMA QKV (R8).
// ---------------------------------------------------------------------------
#define XS_STR 520

__global__ __launch_bounds__(256, 2) void k_mha2f(
    const float* __restrict__ g, const unsigned short* __restrict__ twb,
    const float* __restrict__ Bv, float* __restrict__ attn)
{
  const int b = blockIdx.x, h = blockIdx.y, tid = threadIdx.x;
  __shared__ alignas(16) unsigned short xs[32 * XS_STR];
  __shared__ unsigned short qs[32 * 130];
  __shared__ unsigned short ks[32 * 130];
  __shared__ unsigned short vs[32 * 130];
  for (int i = tid; i < 32 * 512; i += 256) {
    int t = i >> 9, c = i & 511;
    xs[t * XS_STR + c] = f2us(g[(size_t)b * 16384 + i]);
  }
  __syncthreads();
  {
    const int lane = tid & 63, wave = tid >> 6;
    const int l15 = lane & 15, quad = lane >> 4;
    int wrowi[6];
#pragma unroll
    for (int ni = 0; ni < 6; ++ni) {
      int idx = (wave + ni * 4) * 16 + l15;
      int m = idx >> 7, dd = idx & 127;
      wrowi[ni] = m * 512 + h * 128 + dd;
    }
    float4v acc[6][2];
#pragma unroll
    for (int ni = 0; ni < 6; ++ni)
#pragma unroll
      for (int mt = 0; mt < 2; ++mt) acc[ni][mt] = (float4v){0.f, 0.f, 0.f, 0.f};
    for (int kc4 = 0; kc4 < 4; ++kc4) {
      short8v af[2][4];
#pragma unroll
      for (int mt = 0; mt < 2; ++mt)
#pragma unroll
        for (int u = 0; u < 4; ++u)
          af[mt][u] = *reinterpret_cast<const short8v*>(
              xs + (mt * 16 + l15) * XS_STR + kc4 * 128 + u * 32 + quad * 8);
#pragma unroll
      for (int ni = 0; ni < 6; ++ni) {
        const unsigned short* wrow = twb + (size_t)wrowi[ni] * 512 + kc4 * 128;
#pragma unroll
        for (int u = 0; u < 4; ++u) {
          short8v bfr = *reinterpret_cast<const short8v*>(wrow + u * 32 + quad * 8);
          acc[ni][0] = MFMA16(af[0][u], bfr, acc[ni][0], 0, 0, 0);
          acc[ni][1] = MFMA16(af[1][u], bfr, acc[ni][1], 0, 0, 0);
        }
      }
    }
#pragma unroll
    for (int ni = 0; ni < 6; ++ni) {
      int idx = (wave + ni * 4) * 16 + l15;
      int m = idx >> 7, dd = idx & 127;
      float bj = Bv[wrowi[ni]];
      unsigned short* dst = (m == 0) ? qs : (m == 1) ? ks : vs;
#pragma unroll
      for (int r = 0; r < 4; ++r) {
        int t0 = quad * 4 + r;
        dst[t0 * 130 + dd] = f2us(acc[ni][0][r] + bj);
        dst[(t0 + 16) * 130 + dd] = f2us(acc[ni][1][r] + bj);
      }
    }
  }
  __syncthreads();
  float* sc = reinterpret_cast<float*>(xs);  // sc[qi*33 + ki] overlays dead xs
  const float scale2 = 0.08838834764831845f; // 1/sqrt(128)
  for (int i = tid; i < 1024; i += 256) {
    int qi = i >> 5, ki = i & 31;
    const unsigned short* qp = &qs[qi * 130];
    const unsigned short* kp = &ks[ki * 130];
    float a0 = 0.f, a1 = 0.f;
#pragma unroll
    for (int c = 0; c < 128; c += 2) {
      a0 += us2f(qp[c]) * us2f(kp[c]);
      a1 += us2f(qp[c + 1]) * us2f(kp[c + 1]);
    }
    sc[qi * 33 + ki] = (a0 + a1) * scale2;
  }
  __syncthreads();
  if (tid < 32) {
    float* row = &sc[tid * 33];
    float m = row[0];
#pragma unroll
    for (int c = 1; c < 32; ++c) m = fmaxf(m, row[c]);
    float s = 0.f;
#pragma unroll
    for (int c = 0; c < 32; ++c) { float e = expf(row[c] - m); row[c] = e; s += e; }
    float inv = 1.f / s;
#pragma unroll
    for (int c = 0; c < 32; ++c) row[c] *= inv;
  }
  __syncthreads();
  for (int i = tid; i < 4096; i += 256) {
    int t = i >> 7, d = i & 127;
    const float* prow = &sc[t * 33];
    float a0 = 0.f, a1 = 0.f;
#pragma unroll
    for (int k = 0; k < 32; k += 2) {
      a0 += prow[k] * us2f(vs[k * 130 + d]);
      a1 += prow[k + 1] * us2f(vs[(k + 1) * 130 + d]);
    }
    attn[((size_t)b * 32 + t) * 512 + h * 128 + d] = a0 + a1;
  }
}

// ---------------------------------------------------------------------------
// proj GEMM via MFMA (M=16/block, N=512, K=512) + bias + residual + LN.
// ---------------------------------------------------------------------------
__global__ __launch_bounds__(256, 2) void k_projln_mfma(
    const float* __restrict__ X, const unsigned short* __restrict__ Wb,
    const float* __restrict__ bias, const float* __restrict__ res,
    const float* __restrict__ gam, const float* __restrict__ bet,
    float* __restrict__ Y)
{
  const int row0 = blockIdx.x * 16, tid = threadIdx.x;
  __shared__ alignas(16) unsigned short xs[16 * 520];
  __shared__ float ys[16 * 516];
  for (int i = tid; i < 16 * 512; i += 256) {
    int t = i >> 9, c = i & 511;
    xs[t * 520 + c] = f2us(X[(size_t)(row0 + t) * 512 + c]);
  }
  __syncthreads();
  {
    const int lane = tid & 63, wave = tid >> 6;
    const int l15 = lane & 15, quad = lane >> 4;
    short8v af[16];
#pragma unroll
    for (int kc = 0; kc < 16; ++kc)
      af[kc] = *reinterpret_cast<const short8v*>(xs + l15 * 520 + kc * 32 + quad * 8);
    for (int ni = 0; ni < 8; ++ni) {
      int col = (wave + ni * 4) * 16 + l15;
      const unsigned short* wrow = Wb + (size_t)col * 512;
      float4v acc = {0.f,0.f,0.f,0.f};
#pragma unroll
      for (int kc = 0; kc < 16; ++kc) {
        short8v bfr = *reinterpret_cast<const short8v*>(wrow + kc * 32 + quad * 8);
        acc = MFMA16(af[kc], bfr, acc, 0, 0, 0);
      }
      float bj = bias[col];
#pragma unroll
      for (int r = 0; r < 4; ++r)
        ys[(quad * 4 + r) * 516 + col] = acc[r] + bj;
    }
  }
  __syncthreads();
  for (int i = tid; i < 16 * 512; i += 256) {
    int t = i >> 9, c = i & 511;
    ys[t * 516 + c] += res[(size_t)(row0 + t) * 512 + c];
  }
  __syncthreads();
  {
    int row = tid >> 4, l16 = tid & 15;
    const float* yr = ys + row * 516;
    float part = 0.f;
#pragma unroll
    for (int k = 0; k < 32; ++k) part += yr[l16 + 16 * k];
#pragma unroll
    for (int off = 8; off; off >>= 1) part += __shfl_xor(part, off, 16);
    float mean = part * (1.f / 512.f);
    float var = 0.f;
#pragma unroll
    for (int k = 0; k < 32; ++k) { float d = yr[l16 + 16 * k] - mean; var += d * d; }
#pragma unroll
    for (int off = 8; off; off >>= 1) var += __shfl_xor(var, off, 16);
    float rs = rsqrtf(var * (1.f / 512.f) + 1e-5f);
    for (int k = 0; k < 32; ++k) {
      int c = l16 + 16 * k;
      Y[(size_t)(row0 + row) * 512 + c] = (yr[c] - mean) * rs * gam[c] + bet[c];
    }
  }
}

// ---------------------------------------------------------------------------
// ff1 GEMM via MFMA (M=16/block, N=1024, K=512) + bias + relu -> bf16.
// ---------------------------------------------------------------------------
__global__ __launch_bounds__(256, 2) void k_ff1_mfma(
    const float* __restrict__ X, const unsigned short* __restrict__ Wb,
    const float* __restrict__ bias, unsigned short* __restrict__ Y)
{
  const int row0 = blockIdx.x * 16, tid = threadIdx.x;
  __shared__ alignas(16) unsigned short xs[16 * 520];
  for (int i = tid; i < 16 * 512; i += 256) {
    int t = i >> 9, c = i & 511;
    xs[t * 520 + c] = f2us(X[(size_t)(row0 + t) * 512 + c]);
  }
  __syncthreads();
  const int lane = tid & 63, wave = tid >> 6;
  const int l15 = lane & 15, quad = lane >> 4;
  short8v af[16];
#pragma unroll
  for (int kc = 0; kc < 16; ++kc)
    af[kc] = *reinterpret_cast<const short8v*>(xs + l15 * 520 + kc * 32 + quad * 8);
  for (int ni = 0; ni < 16; ++ni) {
    int col = (wave + ni * 4) * 16 + l15;
    const unsigned short* wrow = Wb + (size_t)col * 512;
    float4v acc = {0.f,0.f,0.f,0.f};
#pragma unroll
    for (int kc = 0; kc < 16; ++kc) {
      short8v bfr = *reinterpret_cast<const short8v*>(wrow + kc * 32 + quad * 8);
      acc = MFMA16(af[kc], bfr, acc, 0, 0, 0);
    }
    float bj = bias[col];
#pragma unroll
    for (int r = 0; r < 4; ++r)
      Y[(size_t)(row0 + quad * 4 + r) * 1024 + col] = f2us(fmaxf(acc[r] + bj, 0.f));
  }
}

// ---------------------------------------------------------------------------
// ff2 GEMM via MFMA (M=16/block, N=512, K=1024 in 2 chunks) + bias +
// residual + LN. Y fp32 overlays X bf16 in-place.
// ---------------------------------------------------------------------------
__global__ __launch_bounds__(256, 2) void k_ff2ln_mfma(
    const unsigned short* __restrict__ X, const unsigned short* __restrict__ Wb,
    const float* __restrict__ bias, const float* __restrict__ res,
    const float* __restrict__ gam, const float* __restrict__ bet,
    float* __restrict__ Y)
{
  const int row0 = blockIdx.x * 16, tid = threadIdx.x;
  __shared__ alignas(16) unsigned short xs[16 * 520];
  __shared__ float ys[16 * 516];
  const int lane = tid & 63, wave = tid >> 6;
  const int l15 = lane & 15, quad = lane >> 4;
  float4v acc[8];
#pragma unroll
  for (int ni = 0; ni < 8; ++ni) acc[ni] = (float4v){0.f,0.f,0.f,0.f};
  for (int half = 0; half < 2; ++half) {
    __syncthreads();
    for (int i = tid; i < 16 * 512; i += 256) {
      int t = i >> 9, c = i & 511;
      xs[t * 520 + c] = X[(size_t)(row0 + t) * 1024 + half * 512 + c];
    }
    __syncthreads();
    short8v af[16];
#pragma unroll
    for (int kc = 0; kc < 16; ++kc)
      af[kc] = *reinterpret_cast<const short8v*>(xs + l15 * 520 + kc * 32 + quad * 8);
#pragma unroll
    for (int ni = 0; ni < 8; ++ni) {
      int col = (wave + ni * 4) * 16 + l15;
      const unsigned short* wrow = Wb + (size_t)col * 1024 + half * 512;
#pragma unroll
      for (int kc = 0; kc < 16; ++kc) {
        short8v bfr = *reinterpret_cast<const short8v*>(wrow + kc * 32 + quad * 8);
        acc[ni] = MFMA16(af[kc], bfr, acc[ni], 0, 0, 0);
      }
    }
  }
  __syncthreads();
  for (int ni = 0; ni < 8; ++ni) {
    int col = (wave + ni * 4) * 16 + l15;
    float bj = bias[col];
#pragma unroll
    for (int r = 0; r < 4; ++r)
      ys[(quad * 4 + r) * 516 + col] = acc[ni][r] + bj;
  }
  __syncthreads();
  for (int i = tid; i < 16 * 512; i += 256) {
    int t = i >> 9, c = i & 511;
    ys[t * 516 + c] += res[(size_t)(row0 + t) * 512 + c];
  }
  __syncthreads();
  {
    int row = tid >> 4, l16 = tid & 15;
    const float* yr = ys + row * 516;
    float part = 0.f;
#pragma unroll
    for (int k = 0; k < 32; ++k) part += yr[l16 + 16 * k];
#pragma unroll
    for (int off = 8; off; off >>= 1) part += __shfl_xor(part, off, 16);
    float mean = part * (1.f / 512.f);
    float var = 0.f;
#pragma unroll
    for (int k = 0; k < 32; ++k) { float d = yr[l16 + 16 * k] - mean; var += d * d; }
#pragma unroll
    for (int off = 8; off; off >>= 1) var += __shfl_xor(var, off, 16);
    float rs = rsqrtf(var * (1.f / 512.f) + 1e-5f);
    for (int k = 0; k < 32; ++k) {
      int c = l16 + 16 * k;
      Y[(size_t)(row0 + row) * 512 + c] = (yr[c] - mean) * rs * gam[c] + bet[c];
    }
  }
}

// ---------------------------------------------------------------------------
// Final: mean-pool, temporal MLP, concat, classifier, LN, relu -> fp32
// ---------------------------------------------------------------------------
__global__ __launch_bounds__(256) void k_final(
    const float* __restrict__ g2,
    const float* __restrict__ db, const float* __restrict__ dsl,
    const float* __restrict__ te1_w, const float* __restrict__ te1_b,
    const float* __restrict__ l1g, const float* __restrict__ l1b,
    const float* __restrict__ te2_w, const float* __restrict__ te2_b,
    const float* __restrict__ l2g, const float* __restrict__ l2b,
    const float* __restrict__ c_w, const float* __restrict__ c_b,
    const float* __restrict__ clg, const float* __restrict__ clb,
    float* __restrict__ out)
{
  const int b = blockIdx.x, tid = threadIdx.x;
  __shared__ float cat[640];
  __shared__ float t1[64];
  __shared__ float t2[128];
  __shared__ float pre[256];
  __shared__ float red[256];
  __shared__ float st[2];
  for (int i = tid; i < 512; i += 256) {
    float acc = 0.f;
#pragma unroll
    for (int t = 0; t < 32; ++t) acc += g2[((size_t)b * 32 + t) * 512 + i];
    cat[i] = acc * (1.f / 32.f);
  }
  if (tid == 0) {
    float s = 0.f;
    for (int i = 0; i < 31; ++i) s += db[b * 31 + i];
    st[0] = s / 31.f;
    st[1] = dsl[b];
  }
  __syncthreads();
  const float f0 = st[0], f1v = st[1];
  if (tid < 64)
    t1[tid] = f0 * te1_w[tid * 2] + f1v * te1_w[tid * 2 + 1] + te1_b[tid];
  __syncthreads();
  if (tid == 0) {
    float m = 0.f; for (int i = 0; i < 64; ++i) m += t1[i]; m *= (1.f / 64.f);
    float v = 0.f; for (int i = 0; i < 64; ++i) { float d = t1[i] - m; v += d * d; }
    st[0] = m; st[1] = rsqrtf(v * (1.f / 64.f) + 1e-5f);
  }
  __syncthreads();
  if (tid < 64) {
    float v = (t1[tid] - st[0]) * st[1] * l1g[tid] + l1b[tid];
    t1[tid] = fmaxf(v, 0.f);
  }
  __syncthreads();
  if (tid < 128)
    t2[tid] = dot_ff(t1, te2_w + (size_t)tid * 64, 64) + te2_b[tid];
  __syncthreads();
  if (tid == 0) {
    float m = 0.f; for (int i = 0; i < 128; ++i) m += t2[i]; m *= (1.f / 128.f);
    float v = 0.f; for (int i = 0; i < 128; ++i) { float d = t2[i] - m; v += d * d; }
    st[0] = m; st[1] = rsqrtf(v * (1.f / 128.f) + 1e-5f);
  }
  __syncthreads();
  if (tid < 128) {
    float v = (t2[tid] - st[0]) * st[1] * l2g[tid] + l2b[tid];
    cat[512 + tid] = fmaxf(v, 0.f);
  }
  __syncthreads();
  pre[tid] = dot_ff(cat, c_w + (size_t)tid * 640, 640) + c_b[tid];
  red[tid] = pre[tid];
  __syncthreads();
  for (int s = 128; s > 0; s >>= 1) { if (tid < s) red[tid] += red[tid + s]; __syncthreads(); }
  const float m = red[0] * (1.f / 256.f);
  __syncthreads();
  const float d = pre[tid] - m;
  red[tid] = d * d;
  __syncthreads();
  for (int s = 128; s > 0; s >>= 1) { if (tid < s) red[tid] += red[tid + s]; __syncthreads(); }
  const float rs = rsqrtf(red[0] * (1.f / 256.f) + 1e-5f);
  float v = d * rs * clg[tid] + clb[tid];
  out[(size_t)b * 256 + tid] = fmaxf(v, 0.f);
}

// ---------------------------------------------------------------------------
extern "C" void kernel_launch(void* const* d_in, const int* in_sizes, int n_in,
                              void* d_out, int out_size, void* d_ws, size_t ws_size,
                              hipStream_t stream) {
  (void)in_sizes; (void)n_in; (void)out_size; (void)ws_size;
  const int*   oh     = (const int*)  d_in[0];
  const float* db     = (const float*)d_in[1];
  const float* dsl    = (const float*)d_in[2];
  const float* emb    = (const float*)d_in[3];
  const float* a_in_w = (const float*)d_in[4];
  const float* a_in_b = (const float*)d_in[5];
  const float* a_out_w= (const float*)d_in[6];
  const float* a_out_b= (const float*)d_in[7];
  const float* wih_f  = (const float*)d_in[8];
  const float* whh_f  = (const float*)d_in[9];
  const float* bih_f  = (const float*)d_in[10];
  const float* bhh_f  = (const float*)d_in[11];
  const float* wih_b  = (const float*)d_in[12];
  const float* whh_b  = (const float*)d_in[13];
  const float* bih_b  = (const float*)d_in[14];
  const float* bhh_b  = (const float*)d_in[15];
  const float* t_in_w = (const float*)d_in[16];
  const float* t_in_b = (const float*)d_in[17];
  const float* t_out_w= (const float*)d_in[18];
  const float* t_out_b= (const float*)d_in[19];
  const float* t_ln1g = (const float*)d_in[20];
  const float* t_ln1b = (const float*)d_in[21];
  const float* t_ff1w = (const float*)d_in[22];
  const float* t_ff1b = (const float*)d_in[23];
  const float* t_ff2w = (const float*)d_in[24];
  const float* t_ff2b = (const float*)d_in[25];
  const float* t_ln2g = (const float*)d_in[26];
  const float* t_ln2b = (const float*)d_in[27];
  const float* te1_w  = (const float*)d_in[28];
  const float* te1_b  = (const float*)d_in[29];
  const float* tl1g   = (const float*)d_in[30];
  const float* tl1b   = (const float*)d_in[31];
  const float* te2_w  = (const float*)d_in[32];
  const float* te2_b  = (const float*)d_in[33];
  const float* tl2g   = (const float*)d_in[34];
  const float* tl2b   = (const float*)d_in[35];
  const float* c_w    = (const float*)d_in[36];
  const float* c_b    = (const float*)d_in[37];
  const float* clng   = (const float*)d_in[38];
  const float* clnb   = (const float*)d_in[39];

  float* ws = (float*)d_ws;
  // Workspace (float slots), max index 17,391,616 (~69.6 MB):
  //   A [0,        1048576): oe [8192,128] fp32
  //   B [1048576,  5242880): g fp32 -> f1 bf16 (over dead g) -> g2 fp32
  //   C [5242880,  9437184): attn fp32; g1 = LN out in-place
  //   D [9437184,  9633792): whhb bf16 [2][768][256]
  //   D2[9633792,  9732096): wihb bf16 [2][768][128]
  //   E [10027008,10051584): awb bf16 [384*128]
  //   F [10051584,10444800): twb bf16 [1536*512]
  //   G [10444800,10575872): pwb bf16 [512*512]
  //   G2[10575872,10838016): f1wb bf16 [1024*512]
  //   G3[10838016,11100160): f2wb bf16 [512*1024]
  //   H [11100160,17391616): gi bf16 [8192*1536]
  float* oe   = ws;
  float* g    = ws + 1048576;
  float* attn = ws + 5242880;
  float* g1   = attn;                                   // in-place
  unsigned short* f1 = (unsigned short*)(ws + 1048576); // over dead g
  float* g2   = ws + 1048576;                           // in-place over f1
  unsigned short* whhb = (unsigned short*)(ws + 9437184);
  unsigned short* wihb = (unsigned short*)(ws + 9633792);
  unsigned short* awb  = (unsigned short*)(ws + 10027008);
  unsigned short* twb  = (unsigned short*)(ws + 10051584);
  unsigned short* pwb  = (unsigned short*)(ws + 10444800);
  unsigned short* f1wb = (unsigned short*)(ws + 10575872);
  unsigned short* f2wb = (unsigned short*)(ws + 10838016);
  unsigned short* gi   = (unsigned short*)(ws + 11100160);

  k_canary<<<256, 256, 0, stream>>>((float*)d_out);
  k_cvt<<<3072, 256, 0, stream>>>(a_in_w, t_in_w, t_out_w, t_ff1w, t_ff2w,
                                  awb, twb, pwb, f1wb, f2wb);
  k_gru_wb<<<1536, 256, 0, stream>>>(wih_f, whh_f, wih_b, whh_b, whhb, wihb);
  k_order_attn<<<8192, 256, 0, stream>>>(oh, emb, awb, a_in_b, a_out_w, a_out_b, oe);
  k_gru_gi<<<256, 256, 0, stream>>>(oe, wihb, gi);
  k_gru_rec<<<dim3(16, 2), 512, 0, stream>>>(gi, whhb, bih_f, bhh_f, bih_b, bhh_b, g);
  k_mha2f<<<dim3(256, 4), 256, 0, stream>>>(g, twb, t_in_b, attn);
  k_projln_mfma<<<512, 256, 0, stream>>>(attn, pwb, t_out_b, g, t_ln1g, t_ln1b, g1);
  k_ff1_mfma<<<512, 256, 0, stream>>>(g1, f1wb, t_ff1b, f1);
  k_ff2ln_mfma<<<512, 256, 0, stream>>>(f1, f2wb, t_ff2b, g1, t_ln2g, t_ln2b, g2);
  k_final<<<256, 256, 0, stream>>>(g2, db, dsl, te1_w, te1_b, tl1g, tl1b,
                                   te2_w, te2_b, tl2g, tl2b, c_w, c_b, clng, clnb,
                                   (float*)d_out);
}